// Round 13
// baseline (167.073 us; speedup 1.0000x reference)
//
#include <hip/hip_runtime.h>
#include <hip/hip_fp16.h>

// GCN 2-layer: out = A(relu(A x W1 + b1) W2) + b2, A = sym-normalized adj + self-loops.
// R13: revert to R11's 8-lane/4B padded gather (lanes-per-edge sweep done: it's the
// optimum). New: non-temporal col loads (col streams 12.8MB through L2 exactly once,
// evicting the 3.2MB x16 residency -> 26MB FETCH vs 3.2MB compulsory) + byte-offset
// col entries (src*32) for saddr-form addressing (one 32-bit add per trip).

#define B 256
#define NB_MAX 1024
#define BDIV 128          // nodes per bucket (pow2)
#define BSHIFT 7
#define CHUNK 8192        // edges per partition block
#define RI_MASK 0x7FFFFFu // rowinfo: start in low 23 bits, trips (deg_pad/8) in high 9

// ---------------- partition: per-block LDS histogram over buckets ----------------
__global__ __launch_bounds__(256) void k_phist(const int* __restrict__ dst,
                                               int* __restrict__ hists,
                                               int E, int NB, int NBLK) {
    __shared__ int h[NB_MAX];
    int tid = threadIdx.x, blk = blockIdx.x;
    for (int b = tid; b < NB; b += 256) h[b] = 0;
    __syncthreads();
    int start = blk * CHUNK;
    int end = min(start + CHUNK, E);
    for (int e = start + tid; e < end; e += 256)
        atomicAdd(&h[((unsigned)dst[e]) >> BSHIFT], 1);
    __syncthreads();
    for (int b = tid; b < NB; b += 256) hists[b * NBLK + blk] = h[b];
}

// per-bucket exclusive scan over NBLK block-counts (NBLK <= 512)
__global__ __launch_bounds__(512) void k_pscan1(int* __restrict__ hists,
                                                int* __restrict__ totals, int NBLK) {
    __shared__ int s[512];
    int b = blockIdx.x, tid = threadIdx.x;
    int v = (tid < NBLK) ? hists[b * NBLK + tid] : 0;
    s[tid] = v;
    __syncthreads();
    for (int off = 1; off < 512; off <<= 1) {
        int u = (tid >= off) ? s[tid - off] : 0;
        __syncthreads();
        s[tid] += u;
        __syncthreads();
    }
    if (tid < NBLK) hists[b * NBLK + tid] = s[tid] - v;  // exclusive within bucket
    if (tid == 511) totals[b] = s[511];
}

// scan bucket totals -> bucket bases (NB <= 1024); base[NB]=E
__global__ __launch_bounds__(1024) void k_pscan2(const int* __restrict__ totals,
                                                 int* __restrict__ base, int NB, int E) {
    __shared__ int s[1024];
    int tid = threadIdx.x;
    int v = (tid < NB) ? totals[tid] : 0;
    s[tid] = v;
    __syncthreads();
    for (int off = 1; off < 1024; off <<= 1) {
        int u = (tid >= off) ? s[tid - off] : 0;
        __syncthreads();
        s[tid] += u;
        __syncthreads();
    }
    if (tid < NB) base[tid] = s[tid] - v;
    if (tid == 1023) base[NB] = s[1023];
}

// move edges into bucket regions, LDS-staged for coalesced writes.
__global__ __launch_bounds__(256) void k_move(const int* __restrict__ src,
                                              const int* __restrict__ dst,
                                              const int* __restrict__ hists,
                                              const int* __restrict__ base,
                                              unsigned* __restrict__ packed,
                                              int E, int NB, int NBLK) {
    __shared__ unsigned stage[CHUNK];            // 32 KB
    __shared__ unsigned short stage_b[CHUNK];    // 16 KB
    __shared__ int lh[NB_MAX];
    __shared__ int lexc[NB_MAX];
    __shared__ int gb[NB_MAX];
    __shared__ int part[256];
    int tid = threadIdx.x, blk = blockIdx.x;
    int start = blk * CHUNK;
    int end = min(start + CHUNK, E);
    for (int b = tid; b < NB; b += 256) lh[b] = 0;
    __syncthreads();
    for (int e = start + tid; e < end; e += 256)
        atomicAdd(&lh[((unsigned)dst[e]) >> BSHIFT], 1);
    __syncthreads();
    int t4 = tid * 4;
    int a0 = 0, a1 = 0, a2 = 0, a3 = 0;
    if (t4 + 0 < NB) a0 = lh[t4 + 0];
    if (t4 + 1 < NB) a1 = lh[t4 + 1];
    if (t4 + 2 < NB) a2 = lh[t4 + 2];
    if (t4 + 3 < NB) a3 = lh[t4 + 3];
    int sum = a0 + a1 + a2 + a3;
    part[tid] = sum;
    __syncthreads();
    for (int off = 1; off < 256; off <<= 1) {
        int u = (tid >= off) ? part[tid - off] : 0;
        __syncthreads();
        part[tid] += u;
        __syncthreads();
    }
    int run = part[tid] - sum;
    if (t4 + 0 < NB) { lexc[t4 + 0] = run; run += a0; }
    if (t4 + 1 < NB) { lexc[t4 + 1] = run; run += a1; }
    if (t4 + 2 < NB) { lexc[t4 + 2] = run; run += a2; }
    if (t4 + 3 < NB) { lexc[t4 + 3] = run; run += a3; }
    __syncthreads();
    for (int b = tid; b < NB; b += 256) {
        lh[b] = lexc[b];
        gb[b] = base[b] + hists[b * NBLK + blk] - lexc[b];
    }
    __syncthreads();
    for (int e = start + tid; e < end; e += 256) {
        unsigned d = (unsigned)dst[e];
        int b = d >> BSHIFT;
        int r = atomicAdd(&lh[b], 1);
        stage[r] = (unsigned)src[e] | ((d & (BDIV - 1u)) << 20);
        stage_b[r] = (unsigned short)b;
    }
    __syncthreads();
    int cnt = end - start;
    for (int i = tid; i < cnt; i += 256)
        packed[gb[stage_b[i]] + i] = stage[i];
}

// per-bucket: LDS hist -> PADDED scan (mult of 8) -> rowinfo/dinv + place col + sentinels.
// col entries are BYTE OFFSETS into x16 (src*32). Sentinel = n*32 (zero row).
// col region for bucket b starts at base[b] + 1024*b.
__global__ __launch_bounds__(256) void k_bucket_csr(const unsigned* __restrict__ packed,
                                                    const int* __restrict__ base,
                                                    unsigned* __restrict__ rowinfo,
                                                    float* __restrict__ dinv,
                                                    unsigned* __restrict__ col, int n) {
    __shared__ int lcnt[BDIV];
    __shared__ int plexc[BDIV];
    int b = blockIdx.x, tid = threadIdx.x;
    if (tid < BDIV) lcnt[tid] = 0;
    __syncthreads();
    int s0 = base[b], s1 = base[b + 1];
    for (int i = s0 + tid; i < s1; i += 256)
        atomicAdd(&lcnt[packed[i] >> 20], 1);
    __syncthreads();
    int v = (tid < BDIV) ? lcnt[tid] : 0;
    int vp = (v + 7) & ~7;  // padded degree (mult of 8)
    if (tid < BDIV) plexc[tid] = vp;
    __syncthreads();
    for (int off = 1; off < BDIV; off <<= 1) {
        int u = (tid < BDIV && tid >= off) ? plexc[tid - off] : 0;
        __syncthreads();
        if (tid < BDIV) plexc[tid] += u;
        __syncthreads();
    }
    int cb = s0 + 1024 * b;  // padded col base for this bucket
    if (tid < BDIV) {
        plexc[tid] -= vp;  // exclusive padded offset
        int node = b * BDIV + tid;
        if (node < n) {
            rowinfo[node] = (unsigned)(cb + plexc[tid]) | ((unsigned)(vp >> 3) << 23);
            dinv[node] = rsqrtf((float)(v + 1));  // +1 self-loop
        }
        lcnt[tid] = 0;  // reuse as fill cursor
    }
    __syncthreads();
    for (int i = s0 + tid; i < s1; i += 256) {
        unsigned u = packed[i];
        int l = (int)(u >> 20);
        int pos = cb + plexc[l] + atomicAdd(&lcnt[l], 1);
        col[pos] = (u & 0xFFFFFu) * 32u;  // byte offset into x16
    }
    __syncthreads();
    if (tid < BDIV) {
        int st = cb + plexc[tid];
        unsigned sent = (unsigned)n * 32u;
        for (int k = v; k < vp; ++k) col[st + k] = sent;  // sentinel -> zero row
    }
}

// ---------------- x16 = fp16(x * dinv) + zero sentinel row / sentinel t ----------
__global__ void k_prep(const float* __restrict__ x, const float* __restrict__ dinv,
                       __half2* __restrict__ x16, float* __restrict__ t, int n8) {
    int g = blockIdx.x * blockDim.x + threadIdx.x;  // one half2 (2 feats)
    if (g < n8) {
        float d = dinv[g >> 3];
        float2 v = ((const float2*)x)[g];
        x16[g] = __float22half2_rn(make_float2(v.x * d, v.y * d));
    } else if (g < n8 + 8) {
        x16[g] = __float22half2_rn(make_float2(0.f, 0.f));  // sentinel row n
        if (g == n8) {  // sentinel t row n
            t[(n8 >> 3) * 2 + 0] = 0.f;
            t[(n8 >> 3) * 2 + 1] = 0.f;
        }
    }
}

// ---------------- layer 1: wave-per-row, branch-free padded gather + fused MLP ---
// lane = (h = lane&7 feat-pair, eg = lane>>3 edge-group). trips wave-uniform; loop
// branch-free; col loads NON-TEMPORAL (no L2 pollution of x16); col holds byte
// offsets -> addr = base + (colv + h*4), saddr form.
__global__ __launch_bounds__(256) void k_l1w(const __half2* __restrict__ x16,
                                             const unsigned* __restrict__ rowinfo,
                                             const unsigned* __restrict__ col,
                                             const float* __restrict__ dinv,
                                             const float* __restrict__ W1,
                                             const float* __restrict__ b1,
                                             const float* __restrict__ W2,
                                             float* __restrict__ t, int n) {
    __shared__ float sW1[512], sW2[64], sb1[32];
    int tid = threadIdx.x;
    for (int k = tid; k < 512; k += 256) sW1[k] = W1[k];
    if (tid < 64) sW2[tid] = W2[tid];
    if (tid < 32) sb1[tid] = b1[tid];
    __syncthreads();
    int lane = tid & 63;
    int r = blockIdx.x * 4 + (tid >> 6);
    if (r >= n) return;
    int h = lane & 7, eg = lane >> 3;
    unsigned h4 = (unsigned)h * 4u;
    const char* xb = (const char*)x16;
    float dr = dinv[r];
    unsigned ri = rowinfo[r];
    int j = (int)(ri & RI_MASK) + eg;
    int trips = (int)(ri >> 23);
    float s0 = 0.f, s1 = 0.f;
    if (eg == 0) {  // self-loop: x16[r] = x*dinv_r, *dr later -> x*dinv_r^2
        float2 f = __half22float2(x16[(size_t)r * 8 + h]);
        s0 = f.x; s1 = f.y;
    }
#pragma unroll 4
    for (int it = 0; it < trips; ++it, j += 8) {
        unsigned cv = __builtin_nontemporal_load(col + j);
        float2 f = __half22float2(*(const __half2*)(xb + cv + h4));
        s0 += f.x; s1 += f.y;
    }
    s0 += __shfl_xor(s0, 8);  s1 += __shfl_xor(s1, 8);
    s0 += __shfl_xor(s0, 16); s1 += __shfl_xor(s1, 16);
    s0 += __shfl_xor(s0, 32); s1 += __shfl_xor(s1, 32);
    s0 *= dr; s1 *= dr;  // agg[2h], agg[2h+1] in every lane
    int j32 = lane & 31;
    float hv = sb1[j32];
#pragma unroll
    for (int k = 0; k < 16; ++k) {
        float a = __shfl((k & 1) ? s1 : s0, k >> 1);
        hv = fmaf(a, sW1[k * 32 + j32], hv);
    }
    hv = fmaxf(hv, 0.f);
    float p = hv * sW2[j32 * 2 + (lane >> 5)];  // lanes<32 -> t0, lanes>=32 -> t1
#pragma unroll
    for (int off = 1; off <= 16; off <<= 1) p += __shfl_xor(p, off);
    if ((lane & 31) == 0) t[(size_t)r * 2 + (lane >> 5)] = p * dr;  // pre-scaled
}

// ---------------- layer 2: 8 lanes per node, branch-free, NT col loads ----------
__global__ __launch_bounds__(256) void k_l2w(const unsigned* __restrict__ rowinfo,
                                             const unsigned* __restrict__ col,
                                             const float* __restrict__ dinv,
                                             const float* __restrict__ ts,
                                             const float* __restrict__ b2,
                                             float* __restrict__ out, int n) {
    int g = blockIdx.x * 256 + threadIdx.x;
    int i = g >> 3, q = g & 7;
    if (i >= n) return;
    const char* tb = (const char*)ts;
    float di = dinv[i];
    unsigned ri = rowinfo[i];
    int j = (int)(ri & RI_MASK) + q;
    int trips = (int)(ri >> 23);
    float a0 = 0.f, a1 = 0.f;
    if (q == 0) {  // self: ts[i] = t*dinv_i; *di at end -> t*dinv_i^2
        float2 tv = *(const float2*)(ts + (size_t)i * 2);
        a0 = tv.x; a1 = tv.y;
    }
#pragma unroll 4
    for (int it = 0; it < trips; ++it, j += 8) {
        unsigned cv = __builtin_nontemporal_load(col + j);
        float2 tv = *(const float2*)(tb + (cv >> 2));  // t row = 8B = colv(32B)/4
        a0 += tv.x; a1 += tv.y;
    }
    a0 += __shfl_xor(a0, 1); a1 += __shfl_xor(a1, 1);
    a0 += __shfl_xor(a0, 2); a1 += __shfl_xor(a1, 2);
    a0 += __shfl_xor(a0, 4); a1 += __shfl_xor(a1, 4);
    if (q == 0) {
        out[(size_t)i * 2 + 0] = fmaf(a0, di, b2[0]);
        out[(size_t)i * 2 + 1] = fmaf(a1, di, b2[1]);
    }
}

// ---------------- fallback (global-atomic build, padded-8, byte-offset col) -----

__global__ void k_zero(int* __restrict__ cnt, int n) {
    int i = blockIdx.x * blockDim.x + threadIdx.x;
    if (i < n) cnt[i] = 0;
}
__global__ void k_hist_rank(const int* __restrict__ dst, int* __restrict__ cnt,
                            int* __restrict__ rank, int E) {
    int e = blockIdx.x * blockDim.x + threadIdx.x;
    if (e < E) rank[e] = atomicAdd(&cnt[dst[e]], 1);
}
__global__ __launch_bounds__(256) void k_blocksum(const int* __restrict__ cnt,
                                                  int* __restrict__ bsum, int n) {
    __shared__ int s[256];
    int tid = threadIdx.x;
    int bse = blockIdx.x * 1024 + tid * 4;
    int sum = 0;
#pragma unroll
    for (int q = 0; q < 4; ++q) {
        int i = bse + q;
        if (i < n) sum += (cnt[i] + 7) & ~7;  // padded-8
    }
    s[tid] = sum;
    __syncthreads();
    for (int off = 128; off > 0; off >>= 1) {
        if (tid < off) s[tid] += s[tid + off];
        __syncthreads();
    }
    if (tid == 0) bsum[blockIdx.x] = s[0];
}
__global__ __launch_bounds__(1024) void k_scan_bsums(const int* __restrict__ bsum,
                                                     int* __restrict__ boff, int nb) {
    __shared__ int s[1024];
    int tid = threadIdx.x;
    int v = (tid < nb) ? bsum[tid] : 0;
    s[tid] = v;
    __syncthreads();
    for (int off = 1; off < 1024; off <<= 1) {
        int u = (tid >= off) ? s[tid - off] : 0;
        __syncthreads();
        s[tid] += u;
        __syncthreads();
    }
    if (tid < nb) boff[tid] = s[tid] - v;
}
__global__ __launch_bounds__(256) void k_scan_apply(const int* __restrict__ cnt,
                                                    const int* __restrict__ boff,
                                                    unsigned* __restrict__ rowinfo,
                                                    float* __restrict__ dinv, int n) {
    __shared__ int s[256];
    int tid = threadIdx.x;
    int bse = blockIdx.x * 1024 + tid * 4;
    int c[4];
    int sum = 0;
#pragma unroll
    for (int q = 0; q < 4; ++q) {
        int i = bse + q;
        c[q] = (i < n) ? ((cnt[i] + 7) & ~7) : 0;
        sum += c[q];
    }
    s[tid] = sum;
    __syncthreads();
    for (int off = 1; off < 256; off <<= 1) {
        int u = (tid >= off) ? s[tid - off] : 0;
        __syncthreads();
        s[tid] += u;
        __syncthreads();
    }
    int run = boff[blockIdx.x] + s[tid] - sum;
#pragma unroll
    for (int q = 0; q < 4; ++q) {
        int i = bse + q;
        if (i < n) {
            rowinfo[i] = (unsigned)run | ((unsigned)(c[q] >> 3) << 23);
            run += c[q];
            dinv[i] = rsqrtf((float)(cnt[i] + 1));
        }
    }
}
__global__ void k_fill_rank(const int* __restrict__ src, const int* __restrict__ dst,
                            const unsigned* __restrict__ rowinfo,
                            const int* __restrict__ rank,
                            unsigned* __restrict__ col, int E) {
    int e = blockIdx.x * blockDim.x + threadIdx.x;
    if (e >= E) return;
    int d = dst[e];
    col[(rowinfo[d] & RI_MASK) + rank[e]] = (unsigned)src[e] * 32u;
}
__global__ void k_pad_sent(const unsigned* __restrict__ rowinfo,
                           const int* __restrict__ cnt,
                           unsigned* __restrict__ col, int n) {
    int i = blockIdx.x * blockDim.x + threadIdx.x;
    if (i >= n) return;
    int st = (int)(rowinfo[i] & RI_MASK);
    int v = cnt[i], vp = (v + 7) & ~7;
    unsigned sent = (unsigned)n * 32u;
    for (int k = v; k < vp; ++k) col[st + k] = sent;
}

static inline size_t align4(size_t v) { return (v + 3) & ~(size_t)3; }

extern "C" void kernel_launch(void* const* d_in, const int* in_sizes, int n_in,
                              void* d_out, int out_size, void* d_ws, size_t ws_size,
                              hipStream_t stream) {
    const float* x  = (const float*)d_in[0];
    const int*   ei = (const int*)d_in[1];
    const float* W1 = (const float*)d_in[2];
    const float* b1 = (const float*)d_in[3];
    const float* W2 = (const float*)d_in[4];
    const float* b2 = (const float*)d_in[5];
    float* out = (float*)d_out;

    const int n = in_sizes[0] / 16;
    const int E = in_sizes[1] / 2;
    const int* src = ei;
    const int* dst = ei + E;

    const int gn = (n + B - 1) / B;
    const int ge = (E + B - 1) / B;
    const int n8 = n * 8;

    const int NB   = (n + BDIV - 1) / BDIV;      // dst buckets
    const int NBLK = (E + CHUNK - 1) / CHUNK;    // partition blocks

    // ws layout (int units): hists[NB*NBLK] | totals[NB] | base[NB+1] |
    //   rowinfo[n] | dinv[n] | packed[E] | col[E + 1024*NB]
    // after k_bucket_csr, packed region reused: t[2(n+1)] at +0, x16 at align4(2n+2)
    size_t o_hists  = 0;
    size_t o_totals = align4(o_hists + (size_t)NB * NBLK);
    size_t o_base   = align4(o_totals + NB);
    size_t o_rowinf = align4(o_base + NB + 1);
    size_t o_dinv   = align4(o_rowinf + n);
    size_t o_packed = align4(o_dinv + n);
    size_t o_col    = align4(o_packed + E);
    size_t colsz    = (size_t)E + 1024 * (size_t)NB;
    size_t need_r5  = (o_col + colsz) * 4 + 64;
    size_t reuse_need = align4(2 * (size_t)n + 2) + 8 * ((size_t)n + 1);  // t + x16(8 ints/row)

    bool r5_ok = (NB <= NB_MAX) && (NBLK <= 512) && (n <= (1 << 20)) &&
                 ((size_t)E + 1024 * (size_t)NB < (RI_MASK + 1)) &&
                 ((size_t)n * 32 < 0x80000000u) &&
                 (reuse_need <= (size_t)E) && (ws_size >= need_r5);

    if (r5_ok) {
        int* ws = (int*)d_ws;
        int*      hists  = ws + o_hists;
        int*      totals = ws + o_totals;
        int*      base   = ws + o_base;
        unsigned* rowinf = (unsigned*)(ws + o_rowinf);
        float*    dinv   = (float*)(ws + o_dinv);
        unsigned* packed = (unsigned*)(ws + o_packed);
        unsigned* col    = (unsigned*)(ws + o_col);
        float*    t      = (float*)packed;                          // dead after CSR build
        __half2*  x16    = (__half2*)(packed + align4(2 * (size_t)n + 2));

        k_phist<<<NBLK, 256, 0, stream>>>(dst, hists, E, NB, NBLK);
        k_pscan1<<<NB, 512, 0, stream>>>(hists, totals, NBLK);
        k_pscan2<<<1, 1024, 0, stream>>>(totals, base, NB, E);
        k_move<<<NBLK, 256, 0, stream>>>(src, dst, hists, base, packed, E, NB, NBLK);
        k_bucket_csr<<<NB, 256, 0, stream>>>(packed, base, rowinf, dinv, col, n);
        k_prep<<<(n8 + 8 + 255) / 256, 256, 0, stream>>>(x, dinv, x16, t, n8);
        k_l1w<<<(n + 3) / 4, 256, 0, stream>>>(x16, rowinf, col, dinv, W1, b1, W2, t, n);
        k_l2w<<<(8 * n + 255) / 256, 256, 0, stream>>>(rowinf, col, dinv, t, b2, out, n);
        return;
    }

    // ---- fallback (global-atomic hist/fill), padded-8, byte-offset col ----
    const int nb = (n + 1023) / 1024;
    size_t f_cnt    = 0;
    size_t f_rowinf = align4(f_cnt + n);
    size_t f_col    = align4(f_rowinf + n);
    size_t f_dinv   = align4(f_col + E + 8 * (size_t)n);
    size_t f_bsum   = align4(f_dinv + n);
    size_t f_boff   = align4(f_bsum + nb);
    size_t f_rank   = align4(f_boff + nb);
    size_t reuse2   = align4(2 * (size_t)n + 2) + 8 * ((size_t)n + 1);
    size_t rmax = (size_t)E > reuse2 ? (size_t)E : reuse2;
    size_t need_rank = (f_rank + rmax) * 4 + 64;
    if (ws_size >= need_rank && nb <= 1024 && (size_t)n * 32 < 0x80000000u) {
        int*      ws     = (int*)d_ws;
        int*      cnt    = ws + f_cnt;
        unsigned* rowinf = (unsigned*)(ws + f_rowinf);
        unsigned* col    = (unsigned*)(ws + f_col);
        float*    dinv   = (float*)(ws + f_dinv);
        int*      bsum   = ws + f_bsum;
        int*      boff   = ws + f_boff;
        int*      rank   = ws + f_rank;                 // dead after k_fill_rank
        float*    t      = (float*)rank;
        __half2*  x16    = (__half2*)(rank + align4(2 * (size_t)n + 2));

        k_zero<<<gn, B, 0, stream>>>(cnt, n);
        k_hist_rank<<<ge, B, 0, stream>>>(dst, cnt, rank, E);
        k_blocksum<<<nb, 256, 0, stream>>>(cnt, bsum, n);
        k_scan_bsums<<<1, 1024, 0, stream>>>(bsum, boff, nb);
        k_scan_apply<<<nb, 256, 0, stream>>>(cnt, boff, rowinf, dinv, n);
        k_fill_rank<<<ge, B, 0, stream>>>(src, dst, rowinf, rank, col, E);
        k_pad_sent<<<gn, B, 0, stream>>>(rowinf, cnt, col, n);
        k_prep<<<(n8 + 8 + 255) / 256, 256, 0, stream>>>(x, dinv, x16, t, n8);
        k_l1w<<<(n + 3) / 4, 256, 0, stream>>>(x16, rowinf, col, dinv, W1, b1, W2, t, n);
        k_l2w<<<(8 * n + 255) / 256, 256, 0, stream>>>(rowinf, col, dinv, t, b2, out, n);
    }
}

// Round 14
// 149.160 us; speedup vs baseline: 1.1201x; 1.1201x over previous
//
#include <hip/hip_runtime.h>
#include <hip/hip_fp16.h>

// GCN 2-layer: out = A(relu(A x W1 + b1) W2) + b2, A = sym-normalized adj + self-loops.
// R14: revert to R11's proven gather kernels (8-lane/4B, pad-8, plain col loads —
// R13's NT/byte-offset both regressed). New: CHUNK 4096 (k_move LDS 61->37KB,
// 2->4 blocks/CU for the LDS-atomic scatter) with u16 hists (ws need unchanged),
// and late barrier in k_l1w (weight staging overlaps gather; no LDS use in loop).

#define B 256
#define NB_MAX 1024
#define BDIV 128          // nodes per bucket (pow2)
#define BSHIFT 7
#define CHUNK 4096        // edges per partition block (37KB LDS -> 4 blocks/CU)
#define RI_MASK 0x7FFFFFu // rowinfo: start in low 23 bits, trips (deg_pad/8) in high 9

// ---------------- partition: per-block LDS histogram over buckets ----------------
__global__ __launch_bounds__(256) void k_phist(const int* __restrict__ dst,
                                               unsigned short* __restrict__ hists,
                                               int E, int NB, int NBLK) {
    __shared__ int h[NB_MAX];
    int tid = threadIdx.x, blk = blockIdx.x;
    for (int b = tid; b < NB; b += 256) h[b] = 0;
    __syncthreads();
    int start = blk * CHUNK;
    int end = min(start + CHUNK, E);
    for (int e = start + tid; e < end; e += 256)
        atomicAdd(&h[((unsigned)dst[e]) >> BSHIFT], 1);
    __syncthreads();
    for (int b = tid; b < NB; b += 256) hists[b * NBLK + blk] = (unsigned short)h[b];
}

// per-bucket exclusive scan over NBLK block-counts (NBLK <= 1024), u16 in/out
__global__ __launch_bounds__(1024) void k_pscan1(unsigned short* __restrict__ hists,
                                                 int* __restrict__ totals, int NBLK) {
    __shared__ int s[1024];
    int b = blockIdx.x, tid = threadIdx.x;
    int v = (tid < NBLK) ? (int)hists[b * NBLK + tid] : 0;
    s[tid] = v;
    __syncthreads();
    for (int off = 1; off < 1024; off <<= 1) {
        int u = (tid >= off) ? s[tid - off] : 0;
        __syncthreads();
        s[tid] += u;
        __syncthreads();
    }
    if (tid < NBLK) hists[b * NBLK + tid] = (unsigned short)(s[tid] - v);
    if (tid == 1023) totals[b] = s[1023];
}

// scan bucket totals -> bucket bases (NB <= 1024); base[NB]=E
__global__ __launch_bounds__(1024) void k_pscan2(const int* __restrict__ totals,
                                                 int* __restrict__ base, int NB, int E) {
    __shared__ int s[1024];
    int tid = threadIdx.x;
    int v = (tid < NB) ? totals[tid] : 0;
    s[tid] = v;
    __syncthreads();
    for (int off = 1; off < 1024; off <<= 1) {
        int u = (tid >= off) ? s[tid - off] : 0;
        __syncthreads();
        s[tid] += u;
        __syncthreads();
    }
    if (tid < NB) base[tid] = s[tid] - v;
    if (tid == 1023) base[NB] = s[1023];
}

// move edges into bucket regions, LDS-staged for coalesced writes. 37KB LDS.
__global__ __launch_bounds__(256) void k_move(const int* __restrict__ src,
                                              const int* __restrict__ dst,
                                              const unsigned short* __restrict__ hists,
                                              const int* __restrict__ base,
                                              unsigned* __restrict__ packed,
                                              int E, int NB, int NBLK) {
    __shared__ unsigned stage[CHUNK];            // 16 KB
    __shared__ unsigned short stage_b[CHUNK];    // 8 KB
    __shared__ int lh[NB_MAX];                   // 4 KB
    __shared__ int lexc[NB_MAX];                 // 4 KB
    __shared__ int gb[NB_MAX];                   // 4 KB
    __shared__ int part[256];                    // 1 KB
    int tid = threadIdx.x, blk = blockIdx.x;
    int start = blk * CHUNK;
    int end = min(start + CHUNK, E);
    for (int b = tid; b < NB; b += 256) lh[b] = 0;
    __syncthreads();
    for (int e = start + tid; e < end; e += 256)
        atomicAdd(&lh[((unsigned)dst[e]) >> BSHIFT], 1);
    __syncthreads();
    int t4 = tid * 4;
    int a0 = 0, a1 = 0, a2 = 0, a3 = 0;
    if (t4 + 0 < NB) a0 = lh[t4 + 0];
    if (t4 + 1 < NB) a1 = lh[t4 + 1];
    if (t4 + 2 < NB) a2 = lh[t4 + 2];
    if (t4 + 3 < NB) a3 = lh[t4 + 3];
    int sum = a0 + a1 + a2 + a3;
    part[tid] = sum;
    __syncthreads();
    for (int off = 1; off < 256; off <<= 1) {
        int u = (tid >= off) ? part[tid - off] : 0;
        __syncthreads();
        part[tid] += u;
        __syncthreads();
    }
    int run = part[tid] - sum;
    if (t4 + 0 < NB) { lexc[t4 + 0] = run; run += a0; }
    if (t4 + 1 < NB) { lexc[t4 + 1] = run; run += a1; }
    if (t4 + 2 < NB) { lexc[t4 + 2] = run; run += a2; }
    if (t4 + 3 < NB) { lexc[t4 + 3] = run; run += a3; }
    __syncthreads();
    for (int b = tid; b < NB; b += 256) {
        lh[b] = lexc[b];
        gb[b] = base[b] + (int)hists[b * NBLK + blk] - lexc[b];
    }
    __syncthreads();
    for (int e = start + tid; e < end; e += 256) {
        unsigned d = (unsigned)dst[e];
        int b = d >> BSHIFT;
        int r = atomicAdd(&lh[b], 1);
        stage[r] = (unsigned)src[e] | ((d & (BDIV - 1u)) << 20);
        stage_b[r] = (unsigned short)b;
    }
    __syncthreads();
    int cnt = end - start;
    for (int i = tid; i < cnt; i += 256)
        packed[gb[stage_b[i]] + i] = stage[i];
}

// per-bucket: LDS hist -> PADDED scan (mult of 8) -> rowinfo/dinv + place col + sentinels.
// col region for bucket b starts at base[b] + 1024*b (1024 = worst-case pad per bucket).
__global__ __launch_bounds__(256) void k_bucket_csr(const unsigned* __restrict__ packed,
                                                    const int* __restrict__ base,
                                                    unsigned* __restrict__ rowinfo,
                                                    float* __restrict__ dinv,
                                                    int* __restrict__ col, int n) {
    __shared__ int lcnt[BDIV];
    __shared__ int plexc[BDIV];
    int b = blockIdx.x, tid = threadIdx.x;
    if (tid < BDIV) lcnt[tid] = 0;
    __syncthreads();
    int s0 = base[b], s1 = base[b + 1];
    for (int i = s0 + tid; i < s1; i += 256)
        atomicAdd(&lcnt[packed[i] >> 20], 1);
    __syncthreads();
    int v = (tid < BDIV) ? lcnt[tid] : 0;
    int vp = (v + 7) & ~7;  // padded degree (mult of 8)
    if (tid < BDIV) plexc[tid] = vp;
    __syncthreads();
    for (int off = 1; off < BDIV; off <<= 1) {
        int u = (tid < BDIV && tid >= off) ? plexc[tid - off] : 0;
        __syncthreads();
        if (tid < BDIV) plexc[tid] += u;
        __syncthreads();
    }
    int cb = s0 + 1024 * b;  // padded col base for this bucket
    if (tid < BDIV) {
        plexc[tid] -= vp;  // exclusive padded offset
        int node = b * BDIV + tid;
        if (node < n) {
            rowinfo[node] = (unsigned)(cb + plexc[tid]) | ((unsigned)(vp >> 3) << 23);
            dinv[node] = rsqrtf((float)(v + 1));  // +1 self-loop
        }
        lcnt[tid] = 0;  // reuse as fill cursor
    }
    __syncthreads();
    for (int i = s0 + tid; i < s1; i += 256) {
        unsigned u = packed[i];
        int l = (int)(u >> 20);
        int pos = cb + plexc[l] + atomicAdd(&lcnt[l], 1);
        col[pos] = (int)(u & 0xFFFFFu);
    }
    __syncthreads();
    if (tid < BDIV) {
        int st = cb + plexc[tid];
        for (int k = v; k < vp; ++k) col[st + k] = n;  // sentinel -> zero row
    }
}

// ---------------- x16 = fp16(x * dinv) + zero sentinel row / sentinel t ----------
__global__ void k_prep(const float* __restrict__ x, const float* __restrict__ dinv,
                       __half2* __restrict__ x16, float* __restrict__ t, int n8) {
    int g = blockIdx.x * blockDim.x + threadIdx.x;  // one half2 (2 feats)
    if (g < n8) {
        float d = dinv[g >> 3];
        float2 v = ((const float2*)x)[g];
        x16[g] = __float22half2_rn(make_float2(v.x * d, v.y * d));
    } else if (g < n8 + 8) {
        x16[g] = __float22half2_rn(make_float2(0.f, 0.f));  // sentinel row n
        if (g == n8) {  // sentinel t row n
            t[(n8 >> 3) * 2 + 0] = 0.f;
            t[(n8 >> 3) * 2 + 1] = 0.f;
        }
    }
}

// ---------------- layer 1: wave-per-row, branch-free padded gather + fused MLP ---
// lane = (h = lane&7 feat-pair, eg = lane>>3 edge-group). trips wave-uniform; loop
// branch-free. LATE BARRIER: gather phase touches no LDS, so weight staging
// overlaps it; r clamped (no early return) to keep the barrier convergent.
__global__ __launch_bounds__(256) void k_l1w(const __half2* __restrict__ x16,
                                             const unsigned* __restrict__ rowinfo,
                                             const int* __restrict__ col,
                                             const float* __restrict__ dinv,
                                             const float* __restrict__ W1,
                                             const float* __restrict__ b1,
                                             const float* __restrict__ W2,
                                             float* __restrict__ t, int n) {
    __shared__ float sW1[512], sW2[64], sb1[32];
    int tid = threadIdx.x;
    for (int k = tid; k < 512; k += 256) sW1[k] = W1[k];
    if (tid < 64) sW2[tid] = W2[tid];
    if (tid < 32) sb1[tid] = b1[tid];
    // no barrier yet: gather phase below uses no LDS
    int lane = tid & 63;
    int r0 = blockIdx.x * 4 + (tid >> 6);
    int r = min(r0, n - 1);  // clamp: all threads stay for the barrier
    int h = lane & 7, eg = lane >> 3;
    float dr = dinv[r];
    unsigned ri = rowinfo[r];
    int j = (int)(ri & RI_MASK) + eg;
    int trips = (int)(ri >> 23);
    float s0 = 0.f, s1 = 0.f;
    if (eg == 0) {  // self-loop: x16[r] = x*dinv_r, *dr later -> x*dinv_r^2
        float2 f = __half22float2(x16[(size_t)r * 8 + h]);
        s0 = f.x; s1 = f.y;
    }
#pragma unroll 4
    for (int it = 0; it < trips; ++it, j += 8) {
        int sc = col[j];
        float2 f = __half22float2(x16[(size_t)sc * 8 + h]);
        s0 += f.x; s1 += f.y;
    }
    s0 += __shfl_xor(s0, 8);  s1 += __shfl_xor(s1, 8);
    s0 += __shfl_xor(s0, 16); s1 += __shfl_xor(s1, 16);
    s0 += __shfl_xor(s0, 32); s1 += __shfl_xor(s1, 32);
    s0 *= dr; s1 *= dr;  // agg[2h], agg[2h+1] in every lane
    __syncthreads();     // weights ready; all threads reach this
    int j32 = lane & 31;
    float hv = sb1[j32];
#pragma unroll
    for (int k = 0; k < 16; ++k) {
        float a = __shfl((k & 1) ? s1 : s0, k >> 1);
        hv = fmaf(a, sW1[k * 32 + j32], hv);
    }
    hv = fmaxf(hv, 0.f);
    float p = hv * sW2[j32 * 2 + (lane >> 5)];  // lanes<32 -> t0, lanes>=32 -> t1
#pragma unroll
    for (int off = 1; off <= 16; off <<= 1) p += __shfl_xor(p, off);
    if ((lane & 31) == 0 && r0 < n) t[(size_t)r * 2 + (lane >> 5)] = p * dr;
}

// ---------------- layer 2: 8 lanes per node, branch-free padded loop ------------
__global__ __launch_bounds__(256) void k_l2w(const unsigned* __restrict__ rowinfo,
                                             const int* __restrict__ col,
                                             const float* __restrict__ dinv,
                                             const float* __restrict__ ts,
                                             const float* __restrict__ b2,
                                             float* __restrict__ out, int n) {
    int g = blockIdx.x * 256 + threadIdx.x;
    int i = g >> 3, q = g & 7;
    if (i >= n) return;
    float di = dinv[i];
    unsigned ri = rowinfo[i];
    int j = (int)(ri & RI_MASK) + q;
    int trips = (int)(ri >> 23);
    float a0 = 0.f, a1 = 0.f;
    if (q == 0) {  // self: ts[i] = t*dinv_i; *di at end -> t*dinv_i^2
        float2 tv = *(const float2*)(ts + (size_t)i * 2);
        a0 = tv.x; a1 = tv.y;
    }
#pragma unroll 4
    for (int it = 0; it < trips; ++it, j += 8) {
        int sc = col[j];
        float2 tv = *(const float2*)(ts + (size_t)sc * 2);
        a0 += tv.x; a1 += tv.y;
    }
    a0 += __shfl_xor(a0, 1); a1 += __shfl_xor(a1, 1);
    a0 += __shfl_xor(a0, 2); a1 += __shfl_xor(a1, 2);
    a0 += __shfl_xor(a0, 4); a1 += __shfl_xor(a1, 4);
    if (q == 0) {
        out[(size_t)i * 2 + 0] = fmaf(a0, di, b2[0]);
        out[(size_t)i * 2 + 1] = fmaf(a1, di, b2[1]);
    }
}

// ---------------- fallback (global-atomic build, padded-8) ----------------

__global__ void k_zero(int* __restrict__ cnt, int n) {
    int i = blockIdx.x * blockDim.x + threadIdx.x;
    if (i < n) cnt[i] = 0;
}
__global__ void k_hist_rank(const int* __restrict__ dst, int* __restrict__ cnt,
                            int* __restrict__ rank, int E) {
    int e = blockIdx.x * blockDim.x + threadIdx.x;
    if (e < E) rank[e] = atomicAdd(&cnt[dst[e]], 1);
}
__global__ __launch_bounds__(256) void k_blocksum(const int* __restrict__ cnt,
                                                  int* __restrict__ bsum, int n) {
    __shared__ int s[256];
    int tid = threadIdx.x;
    int bse = blockIdx.x * 1024 + tid * 4;
    int sum = 0;
#pragma unroll
    for (int q = 0; q < 4; ++q) {
        int i = bse + q;
        if (i < n) sum += (cnt[i] + 7) & ~7;  // padded-8
    }
    s[tid] = sum;
    __syncthreads();
    for (int off = 128; off > 0; off >>= 1) {
        if (tid < off) s[tid] += s[tid + off];
        __syncthreads();
    }
    if (tid == 0) bsum[blockIdx.x] = s[0];
}
__global__ __launch_bounds__(1024) void k_scan_bsums(const int* __restrict__ bsum,
                                                     int* __restrict__ boff, int nb) {
    __shared__ int s[1024];
    int tid = threadIdx.x;
    int v = (tid < nb) ? bsum[tid] : 0;
    s[tid] = v;
    __syncthreads();
    for (int off = 1; off < 1024; off <<= 1) {
        int u = (tid >= off) ? s[tid - off] : 0;
        __syncthreads();
        s[tid] += u;
        __syncthreads();
    }
    if (tid < nb) boff[tid] = s[tid] - v;
}
__global__ __launch_bounds__(256) void k_scan_apply(const int* __restrict__ cnt,
                                                    const int* __restrict__ boff,
                                                    unsigned* __restrict__ rowinfo,
                                                    float* __restrict__ dinv, int n) {
    __shared__ int s[256];
    int tid = threadIdx.x;
    int bse = blockIdx.x * 1024 + tid * 4;
    int c[4];
    int sum = 0;
#pragma unroll
    for (int q = 0; q < 4; ++q) {
        int i = bse + q;
        c[q] = (i < n) ? ((cnt[i] + 7) & ~7) : 0;
        sum += c[q];
    }
    s[tid] = sum;
    __syncthreads();
    for (int off = 1; off < 256; off <<= 1) {
        int u = (tid >= off) ? s[tid - off] : 0;
        __syncthreads();
        s[tid] += u;
        __syncthreads();
    }
    int run = boff[blockIdx.x] + s[tid] - sum;
#pragma unroll
    for (int q = 0; q < 4; ++q) {
        int i = bse + q;
        if (i < n) {
            rowinfo[i] = (unsigned)run | ((unsigned)(c[q] >> 3) << 23);
            run += c[q];
            dinv[i] = rsqrtf((float)(cnt[i] + 1));
        }
    }
}
__global__ void k_fill_rank(const int* __restrict__ src, const int* __restrict__ dst,
                            const unsigned* __restrict__ rowinfo,
                            const int* __restrict__ rank,
                            int* __restrict__ col, int E) {
    int e = blockIdx.x * blockDim.x + threadIdx.x;
    if (e >= E) return;
    int d = dst[e];
    col[(rowinfo[d] & RI_MASK) + rank[e]] = src[e];
}
__global__ void k_pad_sent(const unsigned* __restrict__ rowinfo,
                           const int* __restrict__ cnt,
                           int* __restrict__ col, int n) {
    int i = blockIdx.x * blockDim.x + threadIdx.x;
    if (i >= n) return;
    int st = (int)(rowinfo[i] & RI_MASK);
    int v = cnt[i], vp = (v + 7) & ~7;
    for (int k = v; k < vp; ++k) col[st + k] = n;
}

static inline size_t align4(size_t v) { return (v + 3) & ~(size_t)3; }

extern "C" void kernel_launch(void* const* d_in, const int* in_sizes, int n_in,
                              void* d_out, int out_size, void* d_ws, size_t ws_size,
                              hipStream_t stream) {
    const float* x  = (const float*)d_in[0];
    const int*   ei = (const int*)d_in[1];
    const float* W1 = (const float*)d_in[2];
    const float* b1 = (const float*)d_in[3];
    const float* W2 = (const float*)d_in[4];
    const float* b2 = (const float*)d_in[5];
    float* out = (float*)d_out;

    const int n = in_sizes[0] / 16;
    const int E = in_sizes[1] / 2;
    const int* src = ei;
    const int* dst = ei + E;

    const int gn = (n + B - 1) / B;
    const int ge = (E + B - 1) / B;
    const int n8 = n * 8;

    const int NB   = (n + BDIV - 1) / BDIV;      // dst buckets
    const int NBLK = (E + CHUNK - 1) / CHUNK;    // partition blocks

    // ws layout (int units): hists_u16[NB*NBLK] | totals[NB] | base[NB+1] |
    //   rowinfo[n] | dinv[n] | packed[E] | col[E + 1024*NB]
    // after k_bucket_csr, packed region reused: t[2(n+1)] at +0, x16 at align4(2n+2)
    size_t o_hists  = 0;
    size_t o_totals = align4(o_hists + ((size_t)NB * NBLK + 1) / 2);  // u16 array
    size_t o_base   = align4(o_totals + NB);
    size_t o_rowinf = align4(o_base + NB + 1);
    size_t o_dinv   = align4(o_rowinf + n);
    size_t o_packed = align4(o_dinv + n);
    size_t o_col    = align4(o_packed + E);
    size_t colsz    = (size_t)E + 1024 * (size_t)NB;
    size_t need_r5  = (o_col + colsz) * 4 + 64;
    size_t reuse_need = align4(2 * (size_t)n + 2) + (8 * (size_t)n + 8);  // t + x16

    bool r5_ok = (NB <= NB_MAX) && (NBLK <= 1024) && (n <= (1 << 20)) &&
                 ((size_t)E + 1024 * (size_t)NB < (RI_MASK + 1)) &&
                 (reuse_need <= (size_t)E) && (ws_size >= need_r5);

    if (r5_ok) {
        int* ws = (int*)d_ws;
        unsigned short* hists = (unsigned short*)(ws + o_hists);
        int*      totals = ws + o_totals;
        int*      base   = ws + o_base;
        unsigned* rowinf = (unsigned*)(ws + o_rowinf);
        float*    dinv   = (float*)(ws + o_dinv);
        unsigned* packed = (unsigned*)(ws + o_packed);
        int*      col    = ws + o_col;
        float*    t      = (float*)packed;                          // dead after CSR build
        __half2*  x16    = (__half2*)(packed + align4(2 * (size_t)n + 2));

        k_phist<<<NBLK, 256, 0, stream>>>(dst, hists, E, NB, NBLK);
        k_pscan1<<<NB, 1024, 0, stream>>>(hists, totals, NBLK);
        k_pscan2<<<1, 1024, 0, stream>>>(totals, base, NB, E);
        k_move<<<NBLK, 256, 0, stream>>>(src, dst, hists, base, packed, E, NB, NBLK);
        k_bucket_csr<<<NB, 256, 0, stream>>>(packed, base, rowinf, dinv, col, n);
        k_prep<<<(n8 + 8 + 255) / 256, 256, 0, stream>>>(x, dinv, x16, t, n8);
        k_l1w<<<(n + 3) / 4, 256, 0, stream>>>(x16, rowinf, col, dinv, W1, b1, W2, t, n);
        k_l2w<<<(8 * n + 255) / 256, 256, 0, stream>>>(rowinf, col, dinv, t, b2, out, n);
        return;
    }

    // ---- fallback (global-atomic hist/fill), padded-8 rowinfo format ----
    const int nb = (n + 1023) / 1024;
    size_t f_cnt    = 0;
    size_t f_rowinf = align4(f_cnt + n);
    size_t f_col    = align4(f_rowinf + n);
    size_t f_dinv   = align4(f_col + E + 8 * (size_t)n);
    size_t f_bsum   = align4(f_dinv + n);
    size_t f_boff   = align4(f_bsum + nb);
    size_t f_rank   = align4(f_boff + nb);
    size_t reuse2   = align4(2 * (size_t)n + 2) + (8 * (size_t)n + 8);
    size_t rmax = (size_t)E > reuse2 ? (size_t)E : reuse2;
    size_t need_rank = (f_rank + rmax) * 4 + 64;
    if (ws_size >= need_rank && nb <= 1024) {
        int*      ws     = (int*)d_ws;
        int*      cnt    = ws + f_cnt;
        unsigned* rowinf = (unsigned*)(ws + f_rowinf);
        int*      col    = ws + f_col;
        float*    dinv   = (float*)(ws + f_dinv);
        int*      bsum   = ws + f_bsum;
        int*      boff   = ws + f_boff;
        int*      rank   = ws + f_rank;                 // dead after k_fill_rank
        float*    t      = (float*)rank;
        __half2*  x16    = (__half2*)(rank + align4(2 * (size_t)n + 2));

        k_zero<<<gn, B, 0, stream>>>(cnt, n);
        k_hist_rank<<<ge, B, 0, stream>>>(dst, cnt, rank, E);
        k_blocksum<<<nb, 256, 0, stream>>>(cnt, bsum, n);
        k_scan_bsums<<<1, 1024, 0, stream>>>(bsum, boff, nb);
        k_scan_apply<<<nb, 256, 0, stream>>>(cnt, boff, rowinf, dinv, n);
        k_fill_rank<<<ge, B, 0, stream>>>(src, dst, rowinf, rank, col, E);
        k_pad_sent<<<gn, B, 0, stream>>>(rowinf, cnt, col, n);
        k_prep<<<(n8 + 8 + 255) / 256, 256, 0, stream>>>(x, dinv, x16, t, n8);
        k_l1w<<<(n + 3) / 4, 256, 0, stream>>>(x16, rowinf, col, dinv, W1, b1, W2, t, n);
        k_l2w<<<(8 * n + 255) / 256, 256, 0, stream>>>(rowinf, col, dinv, t, b2, out, n);
    }
}

// Round 15
// 145.455 us; speedup vs baseline: 1.1486x; 1.0255x over previous
//
#include <hip/hip_runtime.h>
#include <hip/hip_fp16.h>

// GCN 2-layer: out = A(relu(A x W1 + b1) W2) + b2, A = sym-normalized adj + self-loops.
// R15: k_l1w reverted to exact R11 form (early barrier+return = proven 56.5us; R14's
// late-barrier clamp cost 3.5us). Keep CHUNK4096+u16 hists (k_move win). New:
// single-pass k_bucket_csr -- stage the bucket's packed entries in LDS on the hist
// read (cap 6144 = mean+32sigma; tail falls back to global) -> one less 12.8MB pass.

#define B 256
#define NB_MAX 1024
#define BDIV 128          // nodes per bucket (pow2)
#define BSHIFT 7
#define CHUNK 4096        // edges per partition block (37KB LDS -> 4 blocks/CU)
#define BCAP 6144         // bucket-stage cap (uniform-random buckets ~4090 +/- 64)
#define RI_MASK 0x7FFFFFu // rowinfo: start in low 23 bits, trips (deg_pad/8) in high 9

// ---------------- partition: per-block LDS histogram over buckets ----------------
__global__ __launch_bounds__(256) void k_phist(const int* __restrict__ dst,
                                               unsigned short* __restrict__ hists,
                                               int E, int NB, int NBLK) {
    __shared__ int h[NB_MAX];
    int tid = threadIdx.x, blk = blockIdx.x;
    for (int b = tid; b < NB; b += 256) h[b] = 0;
    __syncthreads();
    int start = blk * CHUNK;
    int end = min(start + CHUNK, E);
    for (int e = start + tid; e < end; e += 256)
        atomicAdd(&h[((unsigned)dst[e]) >> BSHIFT], 1);
    __syncthreads();
    for (int b = tid; b < NB; b += 256) hists[b * NBLK + blk] = (unsigned short)h[b];
}

// per-bucket exclusive scan over NBLK block-counts (NBLK <= 1024), u16 in/out
__global__ __launch_bounds__(1024) void k_pscan1(unsigned short* __restrict__ hists,
                                                 int* __restrict__ totals, int NBLK) {
    __shared__ int s[1024];
    int b = blockIdx.x, tid = threadIdx.x;
    int v = (tid < NBLK) ? (int)hists[b * NBLK + tid] : 0;
    s[tid] = v;
    __syncthreads();
    for (int off = 1; off < 1024; off <<= 1) {
        int u = (tid >= off) ? s[tid - off] : 0;
        __syncthreads();
        s[tid] += u;
        __syncthreads();
    }
    if (tid < NBLK) hists[b * NBLK + tid] = (unsigned short)(s[tid] - v);
    if (tid == 1023) totals[b] = s[1023];
}

// scan bucket totals -> bucket bases (NB <= 1024); base[NB]=E
__global__ __launch_bounds__(1024) void k_pscan2(const int* __restrict__ totals,
                                                 int* __restrict__ base, int NB, int E) {
    __shared__ int s[1024];
    int tid = threadIdx.x;
    int v = (tid < NB) ? totals[tid] : 0;
    s[tid] = v;
    __syncthreads();
    for (int off = 1; off < 1024; off <<= 1) {
        int u = (tid >= off) ? s[tid - off] : 0;
        __syncthreads();
        s[tid] += u;
        __syncthreads();
    }
    if (tid < NB) base[tid] = s[tid] - v;
    if (tid == 1023) base[NB] = s[1023];
}

// move edges into bucket regions, LDS-staged for coalesced writes. 37KB LDS.
__global__ __launch_bounds__(256) void k_move(const int* __restrict__ src,
                                              const int* __restrict__ dst,
                                              const unsigned short* __restrict__ hists,
                                              const int* __restrict__ base,
                                              unsigned* __restrict__ packed,
                                              int E, int NB, int NBLK) {
    __shared__ unsigned stage[CHUNK];            // 16 KB
    __shared__ unsigned short stage_b[CHUNK];    // 8 KB
    __shared__ int lh[NB_MAX];                   // 4 KB
    __shared__ int lexc[NB_MAX];                 // 4 KB
    __shared__ int gb[NB_MAX];                   // 4 KB
    __shared__ int part[256];                    // 1 KB
    int tid = threadIdx.x, blk = blockIdx.x;
    int start = blk * CHUNK;
    int end = min(start + CHUNK, E);
    for (int b = tid; b < NB; b += 256) lh[b] = 0;
    __syncthreads();
    for (int e = start + tid; e < end; e += 256)
        atomicAdd(&lh[((unsigned)dst[e]) >> BSHIFT], 1);
    __syncthreads();
    int t4 = tid * 4;
    int a0 = 0, a1 = 0, a2 = 0, a3 = 0;
    if (t4 + 0 < NB) a0 = lh[t4 + 0];
    if (t4 + 1 < NB) a1 = lh[t4 + 1];
    if (t4 + 2 < NB) a2 = lh[t4 + 2];
    if (t4 + 3 < NB) a3 = lh[t4 + 3];
    int sum = a0 + a1 + a2 + a3;
    part[tid] = sum;
    __syncthreads();
    for (int off = 1; off < 256; off <<= 1) {
        int u = (tid >= off) ? part[tid - off] : 0;
        __syncthreads();
        part[tid] += u;
        __syncthreads();
    }
    int run = part[tid] - sum;
    if (t4 + 0 < NB) { lexc[t4 + 0] = run; run += a0; }
    if (t4 + 1 < NB) { lexc[t4 + 1] = run; run += a1; }
    if (t4 + 2 < NB) { lexc[t4 + 2] = run; run += a2; }
    if (t4 + 3 < NB) { lexc[t4 + 3] = run; run += a3; }
    __syncthreads();
    for (int b = tid; b < NB; b += 256) {
        lh[b] = lexc[b];
        gb[b] = base[b] + (int)hists[b * NBLK + blk] - lexc[b];
    }
    __syncthreads();
    for (int e = start + tid; e < end; e += 256) {
        unsigned d = (unsigned)dst[e];
        int b = d >> BSHIFT;
        int r = atomicAdd(&lh[b], 1);
        stage[r] = (unsigned)src[e] | ((d & (BDIV - 1u)) << 20);
        stage_b[r] = (unsigned short)b;
    }
    __syncthreads();
    int cnt = end - start;
    for (int i = tid; i < cnt; i += 256)
        packed[gb[stage_b[i]] + i] = stage[i];
}

// per-bucket: SINGLE-PASS (LDS-staged packed) hist -> padded scan (mult of 8) ->
// rowinfo/dinv + place col + sentinels. Bucket region starts at base[b] + 1024*b.
__global__ __launch_bounds__(256) void k_bucket_csr(const unsigned* __restrict__ packed,
                                                    const int* __restrict__ base,
                                                    unsigned* __restrict__ rowinfo,
                                                    float* __restrict__ dinv,
                                                    int* __restrict__ col, int n) {
    __shared__ unsigned stg[BCAP];   // 24 KB: staged packed entries
    __shared__ int lcnt[BDIV];
    __shared__ int plexc[BDIV];
    int b = blockIdx.x, tid = threadIdx.x;
    if (tid < BDIV) lcnt[tid] = 0;
    __syncthreads();
    int s0 = base[b], s1 = base[b + 1];
    for (int i = s0 + tid; i < s1; i += 256) {
        unsigned u = packed[i];
        int k = i - s0;
        if (k < BCAP) stg[k] = u;    // stage while histogramming
        atomicAdd(&lcnt[u >> 20], 1);
    }
    __syncthreads();
    int v = (tid < BDIV) ? lcnt[tid] : 0;
    int vp = (v + 7) & ~7;  // padded degree (mult of 8)
    if (tid < BDIV) plexc[tid] = vp;
    __syncthreads();
    for (int off = 1; off < BDIV; off <<= 1) {
        int u = (tid < BDIV && tid >= off) ? plexc[tid - off] : 0;
        __syncthreads();
        if (tid < BDIV) plexc[tid] += u;
        __syncthreads();
    }
    int cb = s0 + 1024 * b;  // padded col base for this bucket
    if (tid < BDIV) {
        plexc[tid] -= vp;  // exclusive padded offset
        int node = b * BDIV + tid;
        if (node < n) {
            rowinfo[node] = (unsigned)(cb + plexc[tid]) | ((unsigned)(vp >> 3) << 23);
            dinv[node] = rsqrtf((float)(v + 1));  // +1 self-loop
        }
        lcnt[tid] = 0;  // reuse as fill cursor
    }
    __syncthreads();
    for (int i = s0 + tid; i < s1; i += 256) {
        int k = i - s0;
        unsigned u = (k < BCAP) ? stg[k] : packed[i];  // LDS hit for ~all entries
        int l = (int)(u >> 20);
        int pos = cb + plexc[l] + atomicAdd(&lcnt[l], 1);
        col[pos] = (int)(u & 0xFFFFFu);
    }
    __syncthreads();
    if (tid < BDIV) {
        int st = cb + plexc[tid];
        for (int k = v; k < vp; ++k) col[st + k] = n;  // sentinel -> zero row
    }
}

// ---------------- x16 = fp16(x * dinv) + zero sentinel row / sentinel t ----------
__global__ void k_prep(const float* __restrict__ x, const float* __restrict__ dinv,
                       __half2* __restrict__ x16, float* __restrict__ t, int n8) {
    int g = blockIdx.x * blockDim.x + threadIdx.x;  // one half2 (2 feats)
    if (g < n8) {
        float d = dinv[g >> 3];
        float2 v = ((const float2*)x)[g];
        x16[g] = __float22half2_rn(make_float2(v.x * d, v.y * d));
    } else if (g < n8 + 8) {
        x16[g] = __float22half2_rn(make_float2(0.f, 0.f));  // sentinel row n
        if (g == n8) {  // sentinel t row n
            t[(n8 >> 3) * 2 + 0] = 0.f;
            t[(n8 >> 3) * 2 + 1] = 0.f;
        }
    }
}

// ---------------- layer 1: wave-per-row, branch-free padded gather + fused MLP ---
// (exact R11 form: early barrier, early return -- proven 56.5us)
__global__ __launch_bounds__(256) void k_l1w(const __half2* __restrict__ x16,
                                             const unsigned* __restrict__ rowinfo,
                                             const int* __restrict__ col,
                                             const float* __restrict__ dinv,
                                             const float* __restrict__ W1,
                                             const float* __restrict__ b1,
                                             const float* __restrict__ W2,
                                             float* __restrict__ t, int n) {
    __shared__ float sW1[512], sW2[64], sb1[32];
    int tid = threadIdx.x;
    for (int k = tid; k < 512; k += 256) sW1[k] = W1[k];
    if (tid < 64) sW2[tid] = W2[tid];
    if (tid < 32) sb1[tid] = b1[tid];
    __syncthreads();
    int lane = tid & 63;
    int r = blockIdx.x * 4 + (tid >> 6);
    if (r >= n) return;
    int h = lane & 7, eg = lane >> 3;
    float dr = dinv[r];
    unsigned ri = rowinfo[r];
    int j = (int)(ri & RI_MASK) + eg;
    int trips = (int)(ri >> 23);
    float s0 = 0.f, s1 = 0.f;
    if (eg == 0) {  // self-loop: x16[r] = x*dinv_r, *dr later -> x*dinv_r^2
        float2 f = __half22float2(x16[(size_t)r * 8 + h]);
        s0 = f.x; s1 = f.y;
    }
#pragma unroll 4
    for (int it = 0; it < trips; ++it, j += 8) {
        int sc = col[j];
        float2 f = __half22float2(x16[(size_t)sc * 8 + h]);
        s0 += f.x; s1 += f.y;
    }
    s0 += __shfl_xor(s0, 8);  s1 += __shfl_xor(s1, 8);
    s0 += __shfl_xor(s0, 16); s1 += __shfl_xor(s1, 16);
    s0 += __shfl_xor(s0, 32); s1 += __shfl_xor(s1, 32);
    s0 *= dr; s1 *= dr;  // agg[2h], agg[2h+1] in every lane
    int j32 = lane & 31;
    float hv = sb1[j32];
#pragma unroll
    for (int k = 0; k < 16; ++k) {
        float a = __shfl((k & 1) ? s1 : s0, k >> 1);
        hv = fmaf(a, sW1[k * 32 + j32], hv);
    }
    hv = fmaxf(hv, 0.f);
    float p = hv * sW2[j32 * 2 + (lane >> 5)];  // lanes<32 -> t0, lanes>=32 -> t1
#pragma unroll
    for (int off = 1; off <= 16; off <<= 1) p += __shfl_xor(p, off);
    if ((lane & 31) == 0) t[(size_t)r * 2 + (lane >> 5)] = p * dr;  // pre-scaled
}

// ---------------- layer 2: 8 lanes per node, branch-free padded loop ------------
__global__ __launch_bounds__(256) void k_l2w(const unsigned* __restrict__ rowinfo,
                                             const int* __restrict__ col,
                                             const float* __restrict__ dinv,
                                             const float* __restrict__ ts,
                                             const float* __restrict__ b2,
                                             float* __restrict__ out, int n) {
    int g = blockIdx.x * 256 + threadIdx.x;
    int i = g >> 3, q = g & 7;
    if (i >= n) return;
    float di = dinv[i];
    unsigned ri = rowinfo[i];
    int j = (int)(ri & RI_MASK) + q;
    int trips = (int)(ri >> 23);
    float a0 = 0.f, a1 = 0.f;
    if (q == 0) {  // self: ts[i] = t*dinv_i; *di at end -> t*dinv_i^2
        float2 tv = *(const float2*)(ts + (size_t)i * 2);
        a0 = tv.x; a1 = tv.y;
    }
#pragma unroll 4
    for (int it = 0; it < trips; ++it, j += 8) {
        int sc = col[j];
        float2 tv = *(const float2*)(ts + (size_t)sc * 2);
        a0 += tv.x; a1 += tv.y;
    }
    a0 += __shfl_xor(a0, 1); a1 += __shfl_xor(a1, 1);
    a0 += __shfl_xor(a0, 2); a1 += __shfl_xor(a1, 2);
    a0 += __shfl_xor(a0, 4); a1 += __shfl_xor(a1, 4);
    if (q == 0) {
        out[(size_t)i * 2 + 0] = fmaf(a0, di, b2[0]);
        out[(size_t)i * 2 + 1] = fmaf(a1, di, b2[1]);
    }
}

// ---------------- fallback (global-atomic build, padded-8) ----------------

__global__ void k_zero(int* __restrict__ cnt, int n) {
    int i = blockIdx.x * blockDim.x + threadIdx.x;
    if (i < n) cnt[i] = 0;
}
__global__ void k_hist_rank(const int* __restrict__ dst, int* __restrict__ cnt,
                            int* __restrict__ rank, int E) {
    int e = blockIdx.x * blockDim.x + threadIdx.x;
    if (e < E) rank[e] = atomicAdd(&cnt[dst[e]], 1);
}
__global__ __launch_bounds__(256) void k_blocksum(const int* __restrict__ cnt,
                                                  int* __restrict__ bsum, int n) {
    __shared__ int s[256];
    int tid = threadIdx.x;
    int bse = blockIdx.x * 1024 + tid * 4;
    int sum = 0;
#pragma unroll
    for (int q = 0; q < 4; ++q) {
        int i = bse + q;
        if (i < n) sum += (cnt[i] + 7) & ~7;  // padded-8
    }
    s[tid] = sum;
    __syncthreads();
    for (int off = 128; off > 0; off >>= 1) {
        if (tid < off) s[tid] += s[tid + off];
        __syncthreads();
    }
    if (tid == 0) bsum[blockIdx.x] = s[0];
}
__global__ __launch_bounds__(1024) void k_scan_bsums(const int* __restrict__ bsum,
                                                     int* __restrict__ boff, int nb) {
    __shared__ int s[1024];
    int tid = threadIdx.x;
    int v = (tid < nb) ? bsum[tid] : 0;
    s[tid] = v;
    __syncthreads();
    for (int off = 1; off < 1024; off <<= 1) {
        int u = (tid >= off) ? s[tid - off] : 0;
        __syncthreads();
        s[tid] += u;
        __syncthreads();
    }
    if (tid < nb) boff[tid] = s[tid] - v;
}
__global__ __launch_bounds__(256) void k_scan_apply(const int* __restrict__ cnt,
                                                    const int* __restrict__ boff,
                                                    unsigned* __restrict__ rowinfo,
                                                    float* __restrict__ dinv, int n) {
    __shared__ int s[256];
    int tid = threadIdx.x;
    int bse = blockIdx.x * 1024 + tid * 4;
    int c[4];
    int sum = 0;
#pragma unroll
    for (int q = 0; q < 4; ++q) {
        int i = bse + q;
        c[q] = (i < n) ? ((cnt[i] + 7) & ~7) : 0;
        sum += c[q];
    }
    s[tid] = sum;
    __syncthreads();
    for (int off = 1; off < 256; off <<= 1) {
        int u = (tid >= off) ? s[tid - off] : 0;
        __syncthreads();
        s[tid] += u;
        __syncthreads();
    }
    int run = boff[blockIdx.x] + s[tid] - sum;
#pragma unroll
    for (int q = 0; q < 4; ++q) {
        int i = bse + q;
        if (i < n) {
            rowinfo[i] = (unsigned)run | ((unsigned)(c[q] >> 3) << 23);
            run += c[q];
            dinv[i] = rsqrtf((float)(cnt[i] + 1));
        }
    }
}
__global__ void k_fill_rank(const int* __restrict__ src, const int* __restrict__ dst,
                            const unsigned* __restrict__ rowinfo,
                            const int* __restrict__ rank,
                            int* __restrict__ col, int E) {
    int e = blockIdx.x * blockDim.x + threadIdx.x;
    if (e >= E) return;
    int d = dst[e];
    col[(rowinfo[d] & RI_MASK) + rank[e]] = src[e];
}
__global__ void k_pad_sent(const unsigned* __restrict__ rowinfo,
                           const int* __restrict__ cnt,
                           int* __restrict__ col, int n) {
    int i = blockIdx.x * blockDim.x + threadIdx.x;
    if (i >= n) return;
    int st = (int)(rowinfo[i] & RI_MASK);
    int v = cnt[i], vp = (v + 7) & ~7;
    for (int k = v; k < vp; ++k) col[st + k] = n;
}

static inline size_t align4(size_t v) { return (v + 3) & ~(size_t)3; }

extern "C" void kernel_launch(void* const* d_in, const int* in_sizes, int n_in,
                              void* d_out, int out_size, void* d_ws, size_t ws_size,
                              hipStream_t stream) {
    const float* x  = (const float*)d_in[0];
    const int*   ei = (const int*)d_in[1];
    const float* W1 = (const float*)d_in[2];
    const float* b1 = (const float*)d_in[3];
    const float* W2 = (const float*)d_in[4];
    const float* b2 = (const float*)d_in[5];
    float* out = (float*)d_out;

    const int n = in_sizes[0] / 16;
    const int E = in_sizes[1] / 2;
    const int* src = ei;
    const int* dst = ei + E;

    const int gn = (n + B - 1) / B;
    const int ge = (E + B - 1) / B;
    const int n8 = n * 8;

    const int NB   = (n + BDIV - 1) / BDIV;      // dst buckets
    const int NBLK = (E + CHUNK - 1) / CHUNK;    // partition blocks

    // ws layout (int units): hists_u16[NB*NBLK] | totals[NB] | base[NB+1] |
    //   rowinfo[n] | dinv[n] | packed[E] | col[E + 1024*NB]
    // after k_bucket_csr, packed region reused: t[2(n+1)] at +0, x16 at align4(2n+2)
    size_t o_hists  = 0;
    size_t o_totals = align4(o_hists + ((size_t)NB * NBLK + 1) / 2);  // u16 array
    size_t o_base   = align4(o_totals + NB);
    size_t o_rowinf = align4(o_base + NB + 1);
    size_t o_dinv   = align4(o_rowinf + n);
    size_t o_packed = align4(o_dinv + n);
    size_t o_col    = align4(o_packed + E);
    size_t colsz    = (size_t)E + 1024 * (size_t)NB;
    size_t need_r5  = (o_col + colsz) * 4 + 64;
    size_t reuse_need = align4(2 * (size_t)n + 2) + (8 * (size_t)n + 8);  // t + x16

    bool r5_ok = (NB <= NB_MAX) && (NBLK <= 1024) && (n <= (1 << 20)) &&
                 ((size_t)E + 1024 * (size_t)NB < (RI_MASK + 1)) &&
                 (reuse_need <= (size_t)E) && (ws_size >= need_r5);

    if (r5_ok) {
        int* ws = (int*)d_ws;
        unsigned short* hists = (unsigned short*)(ws + o_hists);
        int*      totals = ws + o_totals;
        int*      base   = ws + o_base;
        unsigned* rowinf = (unsigned*)(ws + o_rowinf);
        float*    dinv   = (float*)(ws + o_dinv);
        unsigned* packed = (unsigned*)(ws + o_packed);
        int*      col    = ws + o_col;
        float*    t      = (float*)packed;                          // dead after CSR build
        __half2*  x16    = (__half2*)(packed + align4(2 * (size_t)n + 2));

        k_phist<<<NBLK, 256, 0, stream>>>(dst, hists, E, NB, NBLK);
        k_pscan1<<<NB, 1024, 0, stream>>>(hists, totals, NBLK);
        k_pscan2<<<1, 1024, 0, stream>>>(totals, base, NB, E);
        k_move<<<NBLK, 256, 0, stream>>>(src, dst, hists, base, packed, E, NB, NBLK);
        k_bucket_csr<<<NB, 256, 0, stream>>>(packed, base, rowinf, dinv, col, n);
        k_prep<<<(n8 + 8 + 255) / 256, 256, 0, stream>>>(x, dinv, x16, t, n8);
        k_l1w<<<(n + 3) / 4, 256, 0, stream>>>(x16, rowinf, col, dinv, W1, b1, W2, t, n);
        k_l2w<<<(8 * n + 255) / 256, 256, 0, stream>>>(rowinf, col, dinv, t, b2, out, n);
        return;
    }

    // ---- fallback (global-atomic hist/fill), padded-8 rowinfo format ----
    const int nb = (n + 1023) / 1024;
    size_t f_cnt    = 0;
    size_t f_rowinf = align4(f_cnt + n);
    size_t f_col    = align4(f_rowinf + n);
    size_t f_dinv   = align4(f_col + E + 8 * (size_t)n);
    size_t f_bsum   = align4(f_dinv + n);
    size_t f_boff   = align4(f_bsum + nb);
    size_t f_rank   = align4(f_boff + nb);
    size_t reuse2   = align4(2 * (size_t)n + 2) + (8 * (size_t)n + 8);
    size_t rmax = (size_t)E > reuse2 ? (size_t)E : reuse2;
    size_t need_rank = (f_rank + rmax) * 4 + 64;
    if (ws_size >= need_rank && nb <= 1024) {
        int*      ws     = (int*)d_ws;
        int*      cnt    = ws + f_cnt;
        unsigned* rowinf = (unsigned*)(ws + f_rowinf);
        int*      col    = ws + f_col;
        float*    dinv   = (float*)(ws + f_dinv);
        int*      bsum   = ws + f_bsum;
        int*      boff   = ws + f_boff;
        int*      rank   = ws + f_rank;                 // dead after k_fill_rank
        float*    t      = (float*)rank;
        __half2*  x16    = (__half2*)(rank + align4(2 * (size_t)n + 2));

        k_zero<<<gn, B, 0, stream>>>(cnt, n);
        k_hist_rank<<<ge, B, 0, stream>>>(dst, cnt, rank, E);
        k_blocksum<<<nb, 256, 0, stream>>>(cnt, bsum, n);
        k_scan_bsums<<<1, 1024, 0, stream>>>(bsum, boff, nb);
        k_scan_apply<<<nb, 256, 0, stream>>>(cnt, boff, rowinf, dinv, n);
        k_fill_rank<<<ge, B, 0, stream>>>(src, dst, rowinf, rank, col, E);
        k_pad_sent<<<gn, B, 0, stream>>>(rowinf, cnt, col, n);
        k_prep<<<(n8 + 8 + 255) / 256, 256, 0, stream>>>(x, dinv, x16, t, n8);
        k_l1w<<<(n + 3) / 4, 256, 0, stream>>>(x16, rowinf, col, dinv, W1, b1, W2, t, n);
        k_l2w<<<(8 * n + 255) / 256, 256, 0, stream>>>(rowinf, col, dinv, t, b2, out, n);
    }
}

// Round 16
// 132.506 us; speedup vs baseline: 1.2609x; 1.0977x over previous
//
#include <hip/hip_runtime.h>
#include <hip/hip_fp16.h>

// GCN 2-layer: out = A(relu(A x W1 + b1) W2) + b2, A = sym-normalized adj + self-loops.
// R16: (1) split k_l1w's serial shuffle-MLP epilogue (27 chained cross-lane ops/row)
// into a node-parallel k_mlp; k_l1w ends at fold + agg store (no LDS/barrier).
// (2) drop the 1-block k_pscan2 bubble: k_move/k_bucket_csr scan totals in LDS.

#define B 256
#define NB_MAX 1024
#define BDIV 128          // nodes per bucket (pow2)
#define BSHIFT 7
#define CHUNK 4096        // edges per partition block
#define BCAP 6144         // bucket-stage cap (uniform-random buckets ~4090 +/- 64)
#define RI_MASK 0x7FFFFFu // rowinfo: start in low 23 bits, trips (deg_pad/8) in high 9

// ---------------- partition: per-block LDS histogram over buckets ----------------
__global__ __launch_bounds__(256) void k_phist(const int* __restrict__ dst,
                                               unsigned short* __restrict__ hists,
                                               int E, int NB, int NBLK) {
    __shared__ int h[NB_MAX];
    int tid = threadIdx.x, blk = blockIdx.x;
    for (int b = tid; b < NB; b += 256) h[b] = 0;
    __syncthreads();
    int start = blk * CHUNK;
    int end = min(start + CHUNK, E);
    for (int e = start + tid; e < end; e += 256)
        atomicAdd(&h[((unsigned)dst[e]) >> BSHIFT], 1);
    __syncthreads();
    for (int b = tid; b < NB; b += 256) hists[b * NBLK + blk] = (unsigned short)h[b];
}

// per-bucket exclusive scan over NBLK block-counts (NBLK <= 1024), u16 in/out
__global__ __launch_bounds__(1024) void k_pscan1(unsigned short* __restrict__ hists,
                                                 int* __restrict__ totals, int NBLK) {
    __shared__ int s[1024];
    int b = blockIdx.x, tid = threadIdx.x;
    int v = (tid < NBLK) ? (int)hists[b * NBLK + tid] : 0;
    s[tid] = v;
    __syncthreads();
    for (int off = 1; off < 1024; off <<= 1) {
        int u = (tid >= off) ? s[tid - off] : 0;
        __syncthreads();
        s[tid] += u;
        __syncthreads();
    }
    if (tid < NBLK) hists[b * NBLK + tid] = (unsigned short)(s[tid] - v);
    if (tid == 1023) totals[b] = s[1023];
}

// move edges into bucket regions, LDS-staged for coalesced writes. 37KB LDS.
// Computes bucket bases from totals in-LDS (no pscan2 kernel).
__global__ __launch_bounds__(256) void k_move(const int* __restrict__ src,
                                              const int* __restrict__ dst,
                                              const unsigned short* __restrict__ hists,
                                              const int* __restrict__ totals,
                                              unsigned* __restrict__ packed,
                                              int E, int NB, int NBLK) {
    __shared__ unsigned stage[CHUNK];            // 16 KB
    __shared__ unsigned short stage_b[CHUNK];    // 8 KB
    __shared__ int lh[NB_MAX];                   // 4 KB
    __shared__ int lexc[NB_MAX];                 // 4 KB
    __shared__ int gb[NB_MAX];                   // 4 KB (holds base, then write-base)
    __shared__ int part[256];                    // 1 KB
    int tid = threadIdx.x, blk = blockIdx.x;
    int t4 = tid * 4;
    // --- base scan: exclusive prefix of totals -> gb ---
    {
        int a0 = (t4 + 0 < NB) ? totals[t4 + 0] : 0;
        int a1 = (t4 + 1 < NB) ? totals[t4 + 1] : 0;
        int a2 = (t4 + 2 < NB) ? totals[t4 + 2] : 0;
        int a3 = (t4 + 3 < NB) ? totals[t4 + 3] : 0;
        int sum = a0 + a1 + a2 + a3;
        part[tid] = sum;
        __syncthreads();
        for (int off = 1; off < 256; off <<= 1) {
            int u = (tid >= off) ? part[tid - off] : 0;
            __syncthreads();
            part[tid] += u;
            __syncthreads();
        }
        int run = part[tid] - sum;
        if (t4 + 0 < NB) { gb[t4 + 0] = run; run += a0; }
        if (t4 + 1 < NB) { gb[t4 + 1] = run; run += a1; }
        if (t4 + 2 < NB) { gb[t4 + 2] = run; run += a2; }
        if (t4 + 3 < NB) { gb[t4 + 3] = run; run += a3; }
    }
    for (int b = tid; b < NB; b += 256) lh[b] = 0;
    __syncthreads();
    int start = blk * CHUNK;
    int end = min(start + CHUNK, E);
    for (int e = start + tid; e < end; e += 256)
        atomicAdd(&lh[((unsigned)dst[e]) >> BSHIFT], 1);
    __syncthreads();
    {
        int a0 = 0, a1 = 0, a2 = 0, a3 = 0;
        if (t4 + 0 < NB) a0 = lh[t4 + 0];
        if (t4 + 1 < NB) a1 = lh[t4 + 1];
        if (t4 + 2 < NB) a2 = lh[t4 + 2];
        if (t4 + 3 < NB) a3 = lh[t4 + 3];
        int sum = a0 + a1 + a2 + a3;
        part[tid] = sum;
        __syncthreads();
        for (int off = 1; off < 256; off <<= 1) {
            int u = (tid >= off) ? part[tid - off] : 0;
            __syncthreads();
            part[tid] += u;
            __syncthreads();
        }
        int run = part[tid] - sum;
        if (t4 + 0 < NB) { lexc[t4 + 0] = run; run += a0; }
        if (t4 + 1 < NB) { lexc[t4 + 1] = run; run += a1; }
        if (t4 + 2 < NB) { lexc[t4 + 2] = run; run += a2; }
        if (t4 + 3 < NB) { lexc[t4 + 3] = run; run += a3; }
    }
    __syncthreads();
    for (int b = tid; b < NB; b += 256) {
        gb[b] = gb[b] + (int)hists[b * NBLK + blk] - lexc[b];
        lh[b] = lexc[b];
    }
    __syncthreads();
    for (int e = start + tid; e < end; e += 256) {
        unsigned d = (unsigned)dst[e];
        int b = d >> BSHIFT;
        int r = atomicAdd(&lh[b], 1);
        stage[r] = (unsigned)src[e] | ((d & (BDIV - 1u)) << 20);
        stage_b[r] = (unsigned short)b;
    }
    __syncthreads();
    int cnt = end - start;
    for (int i = tid; i < cnt; i += 256)
        packed[gb[stage_b[i]] + i] = stage[i];
}

// per-bucket: SINGLE-PASS (LDS-staged packed) hist -> padded scan (mult of 8) ->
// rowinfo/dinv + place col + sentinels. Computes own base from totals in-LDS.
__global__ __launch_bounds__(256) void k_bucket_csr(const unsigned* __restrict__ packed,
                                                    const int* __restrict__ totals,
                                                    unsigned* __restrict__ rowinfo,
                                                    float* __restrict__ dinv,
                                                    int* __restrict__ col, int n, int NB) {
    __shared__ unsigned stg[BCAP];   // 24 KB: staged packed entries
    __shared__ int part[256];
    __shared__ int lcnt[BDIV];
    __shared__ int plexc[BDIV];
    __shared__ int sbase[2];
    int b = blockIdx.x, tid = threadIdx.x;
    int t4 = tid * 4;
    // --- base scan: need exclusive prefix at b (and totals[b] for s1) ---
    {
        int a0 = (t4 + 0 < NB) ? totals[t4 + 0] : 0;
        int a1 = (t4 + 1 < NB) ? totals[t4 + 1] : 0;
        int a2 = (t4 + 2 < NB) ? totals[t4 + 2] : 0;
        int a3 = (t4 + 3 < NB) ? totals[t4 + 3] : 0;
        int sum = a0 + a1 + a2 + a3;
        part[tid] = sum;
        __syncthreads();
        for (int off = 1; off < 256; off <<= 1) {
            int u = (tid >= off) ? part[tid - off] : 0;
            __syncthreads();
            part[tid] += u;
            __syncthreads();
        }
        int run = part[tid] - sum;
        int a[4] = {a0, a1, a2, a3};
#pragma unroll
        for (int q = 0; q < 4; ++q) {
            if (t4 + q == b) { sbase[0] = run; sbase[1] = run + a[q]; }
            run += a[q];
        }
    }
    if (tid < BDIV) lcnt[tid] = 0;
    __syncthreads();
    int s0 = sbase[0], s1 = sbase[1];
    for (int i = s0 + tid; i < s1; i += 256) {
        unsigned u = packed[i];
        int k = i - s0;
        if (k < BCAP) stg[k] = u;    // stage while histogramming
        atomicAdd(&lcnt[u >> 20], 1);
    }
    __syncthreads();
    int v = (tid < BDIV) ? lcnt[tid] : 0;
    int vp = (v + 7) & ~7;  // padded degree (mult of 8)
    if (tid < BDIV) plexc[tid] = vp;
    __syncthreads();
    for (int off = 1; off < BDIV; off <<= 1) {
        int u = (tid < BDIV && tid >= off) ? plexc[tid - off] : 0;
        __syncthreads();
        if (tid < BDIV) plexc[tid] += u;
        __syncthreads();
    }
    int cb = s0 + 1024 * b;  // padded col base for this bucket
    if (tid < BDIV) {
        plexc[tid] -= vp;  // exclusive padded offset
        int node = b * BDIV + tid;
        if (node < n) {
            rowinfo[node] = (unsigned)(cb + plexc[tid]) | ((unsigned)(vp >> 3) << 23);
            dinv[node] = rsqrtf((float)(v + 1));  // +1 self-loop
        }
        lcnt[tid] = 0;  // reuse as fill cursor
    }
    __syncthreads();
    for (int i = s0 + tid; i < s1; i += 256) {
        int k = i - s0;
        unsigned u = (k < BCAP) ? stg[k] : packed[i];  // LDS hit for ~all entries
        int l = (int)(u >> 20);
        int pos = cb + plexc[l] + atomicAdd(&lcnt[l], 1);
        col[pos] = (int)(u & 0xFFFFFu);
    }
    __syncthreads();
    if (tid < BDIV) {
        int st = cb + plexc[tid];
        for (int k = v; k < vp; ++k) col[st + k] = n;  // sentinel -> zero row
    }
}

// ---------------- x16 = fp16(x * dinv) + zero sentinel row / sentinel t ----------
__global__ void k_prep(const float* __restrict__ x, const float* __restrict__ dinv,
                       __half2* __restrict__ x16, float* __restrict__ t, int n8) {
    int g = blockIdx.x * blockDim.x + threadIdx.x;  // one half2 (2 feats)
    if (g < n8) {
        float d = dinv[g >> 3];
        float2 v = ((const float2*)x)[g];
        x16[g] = __float22half2_rn(make_float2(v.x * d, v.y * d));
    } else if (g < n8 + 8) {
        x16[g] = __float22half2_rn(make_float2(0.f, 0.f));  // sentinel row n
        if (g == n8) {  // sentinel t row n
            t[(n8 >> 3) * 2 + 0] = 0.f;
            t[(n8 >> 3) * 2 + 1] = 0.f;
        }
    }
}

// ---------------- layer 1: wave-per-row branch-free gather -> agg store ----------
// lane = (h = lane&7 feat-pair, eg = lane>>3 edge-group). No LDS, no barrier:
// epilogue is fold (6 shfl) + one float2 store by lanes eg==0. MLP moved to k_mlp.
__global__ __launch_bounds__(256) void k_l1w(const __half2* __restrict__ x16,
                                             const unsigned* __restrict__ rowinfo,
                                             const int* __restrict__ col,
                                             const float* __restrict__ dinv,
                                             float* __restrict__ agg, int n) {
    int tid = threadIdx.x;
    int lane = tid & 63;
    int r = blockIdx.x * 4 + (tid >> 6);
    if (r >= n) return;
    int h = lane & 7, eg = lane >> 3;
    float dr = dinv[r];
    unsigned ri = rowinfo[r];
    int j = (int)(ri & RI_MASK) + eg;
    int trips = (int)(ri >> 23);
    float s0 = 0.f, s1 = 0.f;
    if (eg == 0) {  // self-loop: x16[r] = x*dinv_r, *dr later -> x*dinv_r^2
        float2 f = __half22float2(x16[(size_t)r * 8 + h]);
        s0 = f.x; s1 = f.y;
    }
#pragma unroll 4
    for (int it = 0; it < trips; ++it, j += 8) {
        int sc = col[j];
        float2 f = __half22float2(x16[(size_t)sc * 8 + h]);
        s0 += f.x; s1 += f.y;
    }
    s0 += __shfl_xor(s0, 8);  s1 += __shfl_xor(s1, 8);
    s0 += __shfl_xor(s0, 16); s1 += __shfl_xor(s1, 16);
    s0 += __shfl_xor(s0, 32); s1 += __shfl_xor(s1, 32);
    if (eg == 0)
        *(float2*)(agg + (size_t)r * 16 + 2 * h) = make_float2(s0 * dr, s1 * dr);
}

// ---------------- node-parallel fused MLP: t = (relu(agg W1 + b1) W2) * dinv -----
__global__ __launch_bounds__(256) void k_mlp(const float* __restrict__ agg,
                                             const float* __restrict__ dinv,
                                             const float* __restrict__ W1,
                                             const float* __restrict__ b1,
                                             const float* __restrict__ W2,
                                             float* __restrict__ t, int n) {
    __shared__ float sW1[512], sW2[64], sb1[32];
    int tid = threadIdx.x;
    for (int k = tid; k < 512; k += 256) sW1[k] = W1[k];
    if (tid < 64) sW2[tid] = W2[tid];
    if (tid < 32) sb1[tid] = b1[tid];
    __syncthreads();
    int i = blockIdx.x * 256 + tid;
    if (i >= n) return;
    float a[16];
    const float4* av = (const float4*)(agg + (size_t)i * 16);
#pragma unroll
    for (int q = 0; q < 4; ++q) {
        float4 v = av[q];
        a[4 * q + 0] = v.x; a[4 * q + 1] = v.y;
        a[4 * q + 2] = v.z; a[4 * q + 3] = v.w;
    }
    float di = dinv[i];
    float t0 = 0.f, t1 = 0.f;
#pragma unroll
    for (int j = 0; j < 32; ++j) {
        float acc = sb1[j];
#pragma unroll
        for (int k = 0; k < 16; ++k) acc = fmaf(a[k], sW1[k * 32 + j], acc);
        float hh = fmaxf(acc, 0.f);
        t0 = fmaf(hh, sW2[j * 2 + 0], t0);
        t1 = fmaf(hh, sW2[j * 2 + 1], t1);
    }
    t[(size_t)i * 2 + 0] = t0 * di;  // pre-scaled for layer-2
    t[(size_t)i * 2 + 1] = t1 * di;
}

// ---------------- layer 2: 8 lanes per node, branch-free padded loop ------------
__global__ __launch_bounds__(256) void k_l2w(const unsigned* __restrict__ rowinfo,
                                             const int* __restrict__ col,
                                             const float* __restrict__ dinv,
                                             const float* __restrict__ ts,
                                             const float* __restrict__ b2,
                                             float* __restrict__ out, int n) {
    int g = blockIdx.x * 256 + threadIdx.x;
    int i = g >> 3, q = g & 7;
    if (i >= n) return;
    float di = dinv[i];
    unsigned ri = rowinfo[i];
    int j = (int)(ri & RI_MASK) + q;
    int trips = (int)(ri >> 23);
    float a0 = 0.f, a1 = 0.f;
    if (q == 0) {  // self: ts[i] = t*dinv_i; *di at end -> t*dinv_i^2
        float2 tv = *(const float2*)(ts + (size_t)i * 2);
        a0 = tv.x; a1 = tv.y;
    }
#pragma unroll 4
    for (int it = 0; it < trips; ++it, j += 8) {
        int sc = col[j];
        float2 tv = *(const float2*)(ts + (size_t)sc * 2);
        a0 += tv.x; a1 += tv.y;
    }
    a0 += __shfl_xor(a0, 1); a1 += __shfl_xor(a1, 1);
    a0 += __shfl_xor(a0, 2); a1 += __shfl_xor(a1, 2);
    a0 += __shfl_xor(a0, 4); a1 += __shfl_xor(a1, 4);
    if (q == 0) {
        out[(size_t)i * 2 + 0] = fmaf(a0, di, b2[0]);
        out[(size_t)i * 2 + 1] = fmaf(a1, di, b2[1]);
    }
}

// ---------------- fallback (global-atomic build, padded-8) ----------------

__global__ void k_zero(int* __restrict__ cnt, int n) {
    int i = blockIdx.x * blockDim.x + threadIdx.x;
    if (i < n) cnt[i] = 0;
}
__global__ void k_hist_rank(const int* __restrict__ dst, int* __restrict__ cnt,
                            int* __restrict__ rank, int E) {
    int e = blockIdx.x * blockDim.x + threadIdx.x;
    if (e < E) rank[e] = atomicAdd(&cnt[dst[e]], 1);
}
__global__ __launch_bounds__(256) void k_blocksum(const int* __restrict__ cnt,
                                                  int* __restrict__ bsum, int n) {
    __shared__ int s[256];
    int tid = threadIdx.x;
    int bse = blockIdx.x * 1024 + tid * 4;
    int sum = 0;
#pragma unroll
    for (int q = 0; q < 4; ++q) {
        int i = bse + q;
        if (i < n) sum += (cnt[i] + 7) & ~7;  // padded-8
    }
    s[tid] = sum;
    __syncthreads();
    for (int off = 128; off > 0; off >>= 1) {
        if (tid < off) s[tid] += s[tid + off];
        __syncthreads();
    }
    if (tid == 0) bsum[blockIdx.x] = s[0];
}
__global__ __launch_bounds__(1024) void k_scan_bsums(const int* __restrict__ bsum,
                                                     int* __restrict__ boff, int nb) {
    __shared__ int s[1024];
    int tid = threadIdx.x;
    int v = (tid < nb) ? bsum[tid] : 0;
    s[tid] = v;
    __syncthreads();
    for (int off = 1; off < 1024; off <<= 1) {
        int u = (tid >= off) ? s[tid - off] : 0;
        __syncthreads();
        s[tid] += u;
        __syncthreads();
    }
    if (tid < nb) boff[tid] = s[tid] - v;
}
__global__ __launch_bounds__(256) void k_scan_apply(const int* __restrict__ cnt,
                                                    const int* __restrict__ boff,
                                                    unsigned* __restrict__ rowinfo,
                                                    float* __restrict__ dinv, int n) {
    __shared__ int s[256];
    int tid = threadIdx.x;
    int bse = blockIdx.x * 1024 + tid * 4;
    int c[4];
    int sum = 0;
#pragma unroll
    for (int q = 0; q < 4; ++q) {
        int i = bse + q;
        c[q] = (i < n) ? ((cnt[i] + 7) & ~7) : 0;
        sum += c[q];
    }
    s[tid] = sum;
    __syncthreads();
    for (int off = 1; off < 256; off <<= 1) {
        int u = (tid >= off) ? s[tid - off] : 0;
        __syncthreads();
        s[tid] += u;
        __syncthreads();
    }
    int run = boff[blockIdx.x] + s[tid] - sum;
#pragma unroll
    for (int q = 0; q < 4; ++q) {
        int i = bse + q;
        if (i < n) {
            rowinfo[i] = (unsigned)run | ((unsigned)(c[q] >> 3) << 23);
            run += c[q];
            dinv[i] = rsqrtf((float)(cnt[i] + 1));
        }
    }
}
__global__ void k_fill_rank(const int* __restrict__ src, const int* __restrict__ dst,
                            const unsigned* __restrict__ rowinfo,
                            const int* __restrict__ rank,
                            int* __restrict__ col, int E) {
    int e = blockIdx.x * blockDim.x + threadIdx.x;
    if (e >= E) return;
    int d = dst[e];
    col[(rowinfo[d] & RI_MASK) + rank[e]] = src[e];
}
__global__ void k_pad_sent(const unsigned* __restrict__ rowinfo,
                           const int* __restrict__ cnt,
                           int* __restrict__ col, int n) {
    int i = blockIdx.x * blockDim.x + threadIdx.x;
    if (i >= n) return;
    int st = (int)(rowinfo[i] & RI_MASK);
    int v = cnt[i], vp = (v + 7) & ~7;
    for (int k = v; k < vp; ++k) col[st + k] = n;
}

static inline size_t align4(size_t v) { return (v + 3) & ~(size_t)3; }

extern "C" void kernel_launch(void* const* d_in, const int* in_sizes, int n_in,
                              void* d_out, int out_size, void* d_ws, size_t ws_size,
                              hipStream_t stream) {
    const float* x  = (const float*)d_in[0];
    const int*   ei = (const int*)d_in[1];
    const float* W1 = (const float*)d_in[2];
    const float* b1 = (const float*)d_in[3];
    const float* W2 = (const float*)d_in[4];
    const float* b2 = (const float*)d_in[5];
    float* out = (float*)d_out;

    const int n = in_sizes[0] / 16;
    const int E = in_sizes[1] / 2;
    const int* src = ei;
    const int* dst = ei + E;

    const int gn = (n + B - 1) / B;
    const int ge = (E + B - 1) / B;
    const int n8 = n * 8;

    const int NB   = (n + BDIV - 1) / BDIV;      // dst buckets
    const int NBLK = (E + CHUNK - 1) / CHUNK;    // partition blocks

    // ws layout (int units): hists_u16[NB*NBLK] | totals[NB] | rowinfo[n] | dinv[n] |
    //   packed[E] | col[E + 1024*NB]
    // after k_bucket_csr, packed reused: t[2n+2] | x16[8n+8] | agg[16n]  (26n+ <= E)
    size_t o_hists  = 0;
    size_t o_totals = align4(o_hists + ((size_t)NB * NBLK + 1) / 2);  // u16 array
    size_t o_rowinf = align4(o_totals + NB);
    size_t o_dinv   = align4(o_rowinf + n);
    size_t o_packed = align4(o_dinv + n);
    size_t o_col    = align4(o_packed + E);
    size_t colsz    = (size_t)E + 1024 * (size_t)NB;
    size_t need_r5  = (o_col + colsz) * 4 + 64;
    size_t u_t   = 0;
    size_t u_x16 = align4(2 * (size_t)n + 2);
    size_t u_agg = align4(u_x16 + 8 * (size_t)n + 8);
    size_t reuse_need = u_agg + 16 * (size_t)n;

    bool r5_ok = (NB <= NB_MAX) && (NBLK <= 1024) && (n <= (1 << 20)) &&
                 ((size_t)E + 1024 * (size_t)NB < (RI_MASK + 1)) &&
                 (reuse_need <= (size_t)E) && (ws_size >= need_r5);

    if (r5_ok) {
        int* ws = (int*)d_ws;
        unsigned short* hists = (unsigned short*)(ws + o_hists);
        int*      totals = ws + o_totals;
        unsigned* rowinf = (unsigned*)(ws + o_rowinf);
        float*    dinv   = (float*)(ws + o_dinv);
        unsigned* packed = (unsigned*)(ws + o_packed);
        int*      col    = ws + o_col;
        float*    t      = (float*)(packed + u_t);    // dead after CSR build
        __half2*  x16    = (__half2*)(packed + u_x16);
        float*    agg    = (float*)(packed + u_agg);

        k_phist<<<NBLK, 256, 0, stream>>>(dst, hists, E, NB, NBLK);
        k_pscan1<<<NB, 1024, 0, stream>>>(hists, totals, NBLK);
        k_move<<<NBLK, 256, 0, stream>>>(src, dst, hists, totals, packed, E, NB, NBLK);
        k_bucket_csr<<<NB, 256, 0, stream>>>(packed, totals, rowinf, dinv, col, n, NB);
        k_prep<<<(n8 + 8 + 255) / 256, 256, 0, stream>>>(x, dinv, x16, t, n8);
        k_l1w<<<(n + 3) / 4, 256, 0, stream>>>(x16, rowinf, col, dinv, agg, n);
        k_mlp<<<gn, 256, 0, stream>>>(agg, dinv, W1, b1, W2, t, n);
        k_l2w<<<(8 * n + 255) / 256, 256, 0, stream>>>(rowinf, col, dinv, t, b2, out, n);
        return;
    }

    // ---- fallback (global-atomic hist/fill), padded-8 rowinfo format ----
    const int nb = (n + 1023) / 1024;
    size_t f_cnt    = 0;
    size_t f_rowinf = align4(f_cnt + n);
    size_t f_col    = align4(f_rowinf + n);
    size_t f_dinv   = align4(f_col + E + 8 * (size_t)n);
    size_t f_bsum   = align4(f_dinv + n);
    size_t f_boff   = align4(f_bsum + nb);
    size_t f_rank   = align4(f_boff + nb);
    size_t reuse2   = align4(2 * (size_t)n + 2) + align4(8 * (size_t)n + 8) + 16 * (size_t)n;
    size_t rmax = (size_t)E > reuse2 ? (size_t)E : reuse2;
    size_t need_rank = (f_rank + rmax) * 4 + 64;
    if (ws_size >= need_rank && nb <= 1024) {
        int*      ws     = (int*)d_ws;
        int*      cnt    = ws + f_cnt;
        unsigned* rowinf = (unsigned*)(ws + f_rowinf);
        int*      col    = ws + f_col;
        float*    dinv   = (float*)(ws + f_dinv);
        int*      bsum   = ws + f_bsum;
        int*      boff   = ws + f_boff;
        int*      rank   = ws + f_rank;                 // dead after k_fill_rank
        float*    t      = (float*)rank;
        __half2*  x16    = (__half2*)(rank + align4(2 * (size_t)n + 2));
        float*    agg    = (float*)(rank + align4(2 * (size_t)n + 2) + align4(8 * (size_t)n + 8));

        k_zero<<<gn, B, 0, stream>>>(cnt, n);
        k_hist_rank<<<ge, B, 0, stream>>>(dst, cnt, rank, E);
        k_blocksum<<<nb, 256, 0, stream>>>(cnt, bsum, n);
        k_scan_bsums<<<1, 1024, 0, stream>>>(bsum, boff, nb);
        k_scan_apply<<<nb, 256, 0, stream>>>(cnt, boff, rowinf, dinv, n);
        k_fill_rank<<<ge, B, 0, stream>>>(src, dst, rowinf, rank, col, E);
        k_pad_sent<<<gn, B, 0, stream>>>(rowinf, cnt, col, n);
        k_prep<<<(n8 + 8 + 255) / 256, 256, 0, stream>>>(x, dinv, x16, t, n8);
        k_l1w<<<(n + 3) / 4, 256, 0, stream>>>(x16, rowinf, col, dinv, agg, n);
        k_mlp<<<gn, 256, 0, stream>>>(agg, dinv, W1, b1, W2, t, n);
        k_l2w<<<(8 * n + 255) / 256, 256, 0, stream>>>(rowinf, col, dinv, t, b2, out, n);
    }
}

// Round 17
// 130.135 us; speedup vs baseline: 1.2839x; 1.0182x over previous
//
#include <hip/hip_runtime.h>
#include <hip/hip_fp16.h>

// GCN 2-layer: out = A(relu(A x W1 + b1) W2) + b2, A = sym-normalized adj + self-loops.
// R17: k_move was 42us (top kernel): re-histogrammed its chunk (2nd 12.8MB dst pass +
// 4096 LDS atomics) and ran 2x16-barrier scans at 20% occupancy. Fix: hists transposed
// to [blk][b] (phist writes + k_move reads coalesced); k_move derives chunk counts from
// pscan1 prefix rows (hist phase deleted); base+local scans fused into one dual-payload
// scan (half the barriers).

#define B 256
#define NB_MAX 1024
#define BDIV 128          // nodes per bucket (pow2)
#define BSHIFT 7
#define CHUNK 4096        // edges per partition block
#define BCAP 6144         // bucket-stage cap (uniform-random buckets ~4090 +/- 64)
#define RI_MASK 0x7FFFFFu // rowinfo: start in low 23 bits, trips (deg_pad/8) in high 9

// ---------------- partition: per-block LDS histogram; hists layout [blk][b] ------
__global__ __launch_bounds__(256) void k_phist(const int* __restrict__ dst,
                                               unsigned short* __restrict__ hists,
                                               int E, int NB, int NBLK) {
    __shared__ int h[NB_MAX];
    int tid = threadIdx.x, blk = blockIdx.x;
    for (int b = tid; b < NB; b += 256) h[b] = 0;
    __syncthreads();
    int start = blk * CHUNK;
    int end = min(start + CHUNK, E);
    for (int e = start + tid; e < end; e += 256)
        atomicAdd(&h[((unsigned)dst[e]) >> BSHIFT], 1);
    __syncthreads();
    for (int b = tid; b < NB; b += 256)
        hists[(size_t)blk * NB + b] = (unsigned short)h[b];  // coalesced
}

// per-bucket exclusive scan over NBLK chunk-counts (transposed layout), u16 in/out
__global__ __launch_bounds__(1024) void k_pscan1(unsigned short* __restrict__ hists,
                                                 int* __restrict__ totals,
                                                 int NB, int NBLK) {
    __shared__ int s[1024];
    int b = blockIdx.x, tid = threadIdx.x;
    int v = (tid < NBLK) ? (int)hists[(size_t)tid * NB + b] : 0;
    s[tid] = v;
    __syncthreads();
    for (int off = 1; off < 1024; off <<= 1) {
        int u = (tid >= off) ? s[tid - off] : 0;
        __syncthreads();
        s[tid] += u;
        __syncthreads();
    }
    if (tid < NBLK) hists[(size_t)tid * NB + b] = (unsigned short)(s[tid] - v);
    if (tid == 1023) totals[b] = s[1023];
}

// move edges into bucket regions, LDS-staged for coalesced writes. 38KB LDS.
// Chunk counts derived from prefix rows (no hist phase); fused dual scan.
__global__ __launch_bounds__(256) void k_move(const int* __restrict__ src,
                                              const int* __restrict__ dst,
                                              const unsigned short* __restrict__ hists,
                                              const int* __restrict__ totals,
                                              unsigned* __restrict__ packed,
                                              int E, int NB, int NBLK) {
    __shared__ unsigned stage[CHUNK];            // 16 KB
    __shared__ unsigned short stage_b[CHUNK];    // 8 KB
    __shared__ int lh[NB_MAX];                   // 4 KB (fill cursors)
    __shared__ int lexc[NB_MAX];                 // 4 KB
    __shared__ int gb[NB_MAX];                   // 4 KB (write base per bucket)
    __shared__ int partA[256];                   // 1 KB
    __shared__ int partB[256];                   // 1 KB
    int tid = threadIdx.x, blk = blockIdx.x;
    int t4 = tid * 4;
    bool last = (blk == NBLK - 1);
    // --- fused dual scan: A = totals (bucket bases), B = this chunk's counts ---
    int a[4], c[4], myoff[4];
    int sumA = 0, sumB = 0;
#pragma unroll
    for (int q = 0; q < 4; ++q) {
        int b = t4 + q;
        int tA = 0, mo = 0, cc = 0;
        if (b < NB) {
            tA = totals[b];
            mo = (int)hists[(size_t)blk * NB + b];
            int nxt = last ? tA : (int)hists[(size_t)(blk + 1) * NB + b];
            cc = nxt - mo;
        }
        a[q] = tA; myoff[q] = mo; c[q] = cc;
        sumA += tA; sumB += cc;
    }
    partA[tid] = sumA;
    partB[tid] = sumB;
    __syncthreads();
    for (int off = 1; off < 256; off <<= 1) {
        int uA = (tid >= off) ? partA[tid - off] : 0;
        int uB = (tid >= off) ? partB[tid - off] : 0;
        __syncthreads();
        partA[tid] += uA;
        partB[tid] += uB;
        __syncthreads();
    }
    int runA = partA[tid] - sumA;  // exclusive bucket base
    int runB = partB[tid] - sumB;  // exclusive local offset
#pragma unroll
    for (int q = 0; q < 4; ++q) {
        int b = t4 + q;
        if (b < NB) {
            gb[b] = runA + myoff[q] - runB;  // global write base minus local start
            lexc[b] = runB;
            lh[b] = runB;                    // cursor
        }
        runA += a[q];
        runB += c[q];
    }
    __syncthreads();
    int start = blk * CHUNK;
    int end = min(start + CHUNK, E);
    for (int e = start + tid; e < end; e += 256) {
        unsigned d = (unsigned)dst[e];
        int b = d >> BSHIFT;
        int r = atomicAdd(&lh[b], 1);
        stage[r] = (unsigned)src[e] | ((d & (BDIV - 1u)) << 20);
        stage_b[r] = (unsigned short)b;
    }
    __syncthreads();
    int cnt = end - start;
    for (int i = tid; i < cnt; i += 256)
        packed[gb[stage_b[i]] + i] = stage[i];
}

// per-bucket: SINGLE-PASS (LDS-staged packed) hist -> padded scan (mult of 8) ->
// rowinfo/dinv + place col + sentinels. Computes own base from totals in-LDS.
__global__ __launch_bounds__(256) void k_bucket_csr(const unsigned* __restrict__ packed,
                                                    const int* __restrict__ totals,
                                                    unsigned* __restrict__ rowinfo,
                                                    float* __restrict__ dinv,
                                                    int* __restrict__ col, int n, int NB) {
    __shared__ unsigned stg[BCAP];   // 24 KB: staged packed entries
    __shared__ int part[256];
    __shared__ int lcnt[BDIV];
    __shared__ int plexc[BDIV];
    __shared__ int sbase[2];
    int b = blockIdx.x, tid = threadIdx.x;
    int t4 = tid * 4;
    // --- base scan: exclusive prefix of totals at b ---
    {
        int a0 = (t4 + 0 < NB) ? totals[t4 + 0] : 0;
        int a1 = (t4 + 1 < NB) ? totals[t4 + 1] : 0;
        int a2 = (t4 + 2 < NB) ? totals[t4 + 2] : 0;
        int a3 = (t4 + 3 < NB) ? totals[t4 + 3] : 0;
        int sum = a0 + a1 + a2 + a3;
        part[tid] = sum;
        __syncthreads();
        for (int off = 1; off < 256; off <<= 1) {
            int u = (tid >= off) ? part[tid - off] : 0;
            __syncthreads();
            part[tid] += u;
            __syncthreads();
        }
        int run = part[tid] - sum;
        int a[4] = {a0, a1, a2, a3};
#pragma unroll
        for (int q = 0; q < 4; ++q) {
            if (t4 + q == b) { sbase[0] = run; sbase[1] = run + a[q]; }
            run += a[q];
        }
    }
    if (tid < BDIV) lcnt[tid] = 0;
    __syncthreads();
    int s0 = sbase[0], s1 = sbase[1];
    for (int i = s0 + tid; i < s1; i += 256) {
        unsigned u = packed[i];
        int k = i - s0;
        if (k < BCAP) stg[k] = u;    // stage while histogramming
        atomicAdd(&lcnt[u >> 20], 1);
    }
    __syncthreads();
    int v = (tid < BDIV) ? lcnt[tid] : 0;
    int vp = (v + 7) & ~7;  // padded degree (mult of 8)
    if (tid < BDIV) plexc[tid] = vp;
    __syncthreads();
    for (int off = 1; off < BDIV; off <<= 1) {
        int u = (tid < BDIV && tid >= off) ? plexc[tid - off] : 0;
        __syncthreads();
        if (tid < BDIV) plexc[tid] += u;
        __syncthreads();
    }
    int cb = s0 + 1024 * b;  // padded col base for this bucket
    if (tid < BDIV) {
        plexc[tid] -= vp;  // exclusive padded offset
        int node = b * BDIV + tid;
        if (node < n) {
            rowinfo[node] = (unsigned)(cb + plexc[tid]) | ((unsigned)(vp >> 3) << 23);
            dinv[node] = rsqrtf((float)(v + 1));  // +1 self-loop
        }
        lcnt[tid] = 0;  // reuse as fill cursor
    }
    __syncthreads();
    for (int i = s0 + tid; i < s1; i += 256) {
        int k = i - s0;
        unsigned u = (k < BCAP) ? stg[k] : packed[i];  // LDS hit for ~all entries
        int l = (int)(u >> 20);
        int pos = cb + plexc[l] + atomicAdd(&lcnt[l], 1);
        col[pos] = (int)(u & 0xFFFFFu);
    }
    __syncthreads();
    if (tid < BDIV) {
        int st = cb + plexc[tid];
        for (int k = v; k < vp; ++k) col[st + k] = n;  // sentinel -> zero row
    }
}

// ---------------- x16 = fp16(x * dinv) + zero sentinel row / sentinel t ----------
__global__ void k_prep(const float* __restrict__ x, const float* __restrict__ dinv,
                       __half2* __restrict__ x16, float* __restrict__ t, int n8) {
    int g = blockIdx.x * blockDim.x + threadIdx.x;  // one half2 (2 feats)
    if (g < n8) {
        float d = dinv[g >> 3];
        float2 v = ((const float2*)x)[g];
        x16[g] = __float22half2_rn(make_float2(v.x * d, v.y * d));
    } else if (g < n8 + 8) {
        x16[g] = __float22half2_rn(make_float2(0.f, 0.f));  // sentinel row n
        if (g == n8) {  // sentinel t row n
            t[(n8 >> 3) * 2 + 0] = 0.f;
            t[(n8 >> 3) * 2 + 1] = 0.f;
        }
    }
}

// ---------------- layer 1: wave-per-row branch-free gather -> agg store ----------
__global__ __launch_bounds__(256) void k_l1w(const __half2* __restrict__ x16,
                                             const unsigned* __restrict__ rowinfo,
                                             const int* __restrict__ col,
                                             const float* __restrict__ dinv,
                                             float* __restrict__ agg, int n) {
    int tid = threadIdx.x;
    int lane = tid & 63;
    int r = blockIdx.x * 4 + (tid >> 6);
    if (r >= n) return;
    int h = lane & 7, eg = lane >> 3;
    float dr = dinv[r];
    unsigned ri = rowinfo[r];
    int j = (int)(ri & RI_MASK) + eg;
    int trips = (int)(ri >> 23);
    float s0 = 0.f, s1 = 0.f;
    if (eg == 0) {  // self-loop: x16[r] = x*dinv_r, *dr later -> x*dinv_r^2
        float2 f = __half22float2(x16[(size_t)r * 8 + h]);
        s0 = f.x; s1 = f.y;
    }
#pragma unroll 4
    for (int it = 0; it < trips; ++it, j += 8) {
        int sc = col[j];
        float2 f = __half22float2(x16[(size_t)sc * 8 + h]);
        s0 += f.x; s1 += f.y;
    }
    s0 += __shfl_xor(s0, 8);  s1 += __shfl_xor(s1, 8);
    s0 += __shfl_xor(s0, 16); s1 += __shfl_xor(s1, 16);
    s0 += __shfl_xor(s0, 32); s1 += __shfl_xor(s1, 32);
    if (eg == 0)
        *(float2*)(agg + (size_t)r * 16 + 2 * h) = make_float2(s0 * dr, s1 * dr);
}

// ---------------- node-parallel fused MLP: t = (relu(agg W1 + b1) W2) * dinv -----
__global__ __launch_bounds__(256) void k_mlp(const float* __restrict__ agg,
                                             const float* __restrict__ dinv,
                                             const float* __restrict__ W1,
                                             const float* __restrict__ b1,
                                             const float* __restrict__ W2,
                                             float* __restrict__ t, int n) {
    __shared__ float sW1[512], sW2[64], sb1[32];
    int tid = threadIdx.x;
    for (int k = tid; k < 512; k += 256) sW1[k] = W1[k];
    if (tid < 64) sW2[tid] = W2[tid];
    if (tid < 32) sb1[tid] = b1[tid];
    __syncthreads();
    int i = blockIdx.x * 256 + tid;
    if (i >= n) return;
    float a[16];
    const float4* av = (const float4*)(agg + (size_t)i * 16);
#pragma unroll
    for (int q = 0; q < 4; ++q) {
        float4 v = av[q];
        a[4 * q + 0] = v.x; a[4 * q + 1] = v.y;
        a[4 * q + 2] = v.z; a[4 * q + 3] = v.w;
    }
    float di = dinv[i];
    float t0 = 0.f, t1 = 0.f;
#pragma unroll
    for (int j = 0; j < 32; ++j) {
        float acc = sb1[j];
#pragma unroll
        for (int k = 0; k < 16; ++k) acc = fmaf(a[k], sW1[k * 32 + j], acc);
        float hh = fmaxf(acc, 0.f);
        t0 = fmaf(hh, sW2[j * 2 + 0], t0);
        t1 = fmaf(hh, sW2[j * 2 + 1], t1);
    }
    t[(size_t)i * 2 + 0] = t0 * di;  // pre-scaled for layer-2
    t[(size_t)i * 2 + 1] = t1 * di;
}

// ---------------- layer 2: 8 lanes per node, branch-free padded loop ------------
__global__ __launch_bounds__(256) void k_l2w(const unsigned* __restrict__ rowinfo,
                                             const int* __restrict__ col,
                                             const float* __restrict__ dinv,
                                             const float* __restrict__ ts,
                                             const float* __restrict__ b2,
                                             float* __restrict__ out, int n) {
    int g = blockIdx.x * 256 + threadIdx.x;
    int i = g >> 3, q = g & 7;
    if (i >= n) return;
    float di = dinv[i];
    unsigned ri = rowinfo[i];
    int j = (int)(ri & RI_MASK) + q;
    int trips = (int)(ri >> 23);
    float a0 = 0.f, a1 = 0.f;
    if (q == 0) {  // self: ts[i] = t*dinv_i; *di at end -> t*dinv_i^2
        float2 tv = *(const float2*)(ts + (size_t)i * 2);
        a0 = tv.x; a1 = tv.y;
    }
#pragma unroll 4
    for (int it = 0; it < trips; ++it, j += 8) {
        int sc = col[j];
        float2 tv = *(const float2*)(ts + (size_t)sc * 2);
        a0 += tv.x; a1 += tv.y;
    }
    a0 += __shfl_xor(a0, 1); a1 += __shfl_xor(a1, 1);
    a0 += __shfl_xor(a0, 2); a1 += __shfl_xor(a1, 2);
    a0 += __shfl_xor(a0, 4); a1 += __shfl_xor(a1, 4);
    if (q == 0) {
        out[(size_t)i * 2 + 0] = fmaf(a0, di, b2[0]);
        out[(size_t)i * 2 + 1] = fmaf(a1, di, b2[1]);
    }
}

// ---------------- fallback (global-atomic build, padded-8) ----------------

__global__ void k_zero(int* __restrict__ cnt, int n) {
    int i = blockIdx.x * blockDim.x + threadIdx.x;
    if (i < n) cnt[i] = 0;
}
__global__ void k_hist_rank(const int* __restrict__ dst, int* __restrict__ cnt,
                            int* __restrict__ rank, int E) {
    int e = blockIdx.x * blockDim.x + threadIdx.x;
    if (e < E) rank[e] = atomicAdd(&cnt[dst[e]], 1);
}
__global__ __launch_bounds__(256) void k_blocksum(const int* __restrict__ cnt,
                                                  int* __restrict__ bsum, int n) {
    __shared__ int s[256];
    int tid = threadIdx.x;
    int bse = blockIdx.x * 1024 + tid * 4;
    int sum = 0;
#pragma unroll
    for (int q = 0; q < 4; ++q) {
        int i = bse + q;
        if (i < n) sum += (cnt[i] + 7) & ~7;  // padded-8
    }
    s[tid] = sum;
    __syncthreads();
    for (int off = 128; off > 0; off >>= 1) {
        if (tid < off) s[tid] += s[tid + off];
        __syncthreads();
    }
    if (tid == 0) bsum[blockIdx.x] = s[0];
}
__global__ __launch_bounds__(1024) void k_scan_bsums(const int* __restrict__ bsum,
                                                     int* __restrict__ boff, int nb) {
    __shared__ int s[1024];
    int tid = threadIdx.x;
    int v = (tid < nb) ? bsum[tid] : 0;
    s[tid] = v;
    __syncthreads();
    for (int off = 1; off < 1024; off <<= 1) {
        int u = (tid >= off) ? s[tid - off] : 0;
        __syncthreads();
        s[tid] += u;
        __syncthreads();
    }
    if (tid < nb) boff[tid] = s[tid] - v;
}
__global__ __launch_bounds__(256) void k_scan_apply(const int* __restrict__ cnt,
                                                    const int* __restrict__ boff,
                                                    unsigned* __restrict__ rowinfo,
                                                    float* __restrict__ dinv, int n) {
    __shared__ int s[256];
    int tid = threadIdx.x;
    int bse = blockIdx.x * 1024 + tid * 4;
    int c[4];
    int sum = 0;
#pragma unroll
    for (int q = 0; q < 4; ++q) {
        int i = bse + q;
        c[q] = (i < n) ? ((cnt[i] + 7) & ~7) : 0;
        sum += c[q];
    }
    s[tid] = sum;
    __syncthreads();
    for (int off = 1; off < 256; off <<= 1) {
        int u = (tid >= off) ? s[tid - off] : 0;
        __syncthreads();
        s[tid] += u;
        __syncthreads();
    }
    int run = boff[blockIdx.x] + s[tid] - sum;
#pragma unroll
    for (int q = 0; q < 4; ++q) {
        int i = bse + q;
        if (i < n) {
            rowinfo[i] = (unsigned)run | ((unsigned)(c[q] >> 3) << 23);
            run += c[q];
            dinv[i] = rsqrtf((float)(cnt[i] + 1));
        }
    }
}
__global__ void k_fill_rank(const int* __restrict__ src, const int* __restrict__ dst,
                            const unsigned* __restrict__ rowinfo,
                            const int* __restrict__ rank,
                            int* __restrict__ col, int E) {
    int e = blockIdx.x * blockDim.x + threadIdx.x;
    if (e >= E) return;
    int d = dst[e];
    col[(rowinfo[d] & RI_MASK) + rank[e]] = src[e];
}
__global__ void k_pad_sent(const unsigned* __restrict__ rowinfo,
                           const int* __restrict__ cnt,
                           int* __restrict__ col, int n) {
    int i = blockIdx.x * blockDim.x + threadIdx.x;
    if (i >= n) return;
    int st = (int)(rowinfo[i] & RI_MASK);
    int v = cnt[i], vp = (v + 7) & ~7;
    for (int k = v; k < vp; ++k) col[st + k] = n;
}

static inline size_t align4(size_t v) { return (v + 3) & ~(size_t)3; }

extern "C" void kernel_launch(void* const* d_in, const int* in_sizes, int n_in,
                              void* d_out, int out_size, void* d_ws, size_t ws_size,
                              hipStream_t stream) {
    const float* x  = (const float*)d_in[0];
    const int*   ei = (const int*)d_in[1];
    const float* W1 = (const float*)d_in[2];
    const float* b1 = (const float*)d_in[3];
    const float* W2 = (const float*)d_in[4];
    const float* b2 = (const float*)d_in[5];
    float* out = (float*)d_out;

    const int n = in_sizes[0] / 16;
    const int E = in_sizes[1] / 2;
    const int* src = ei;
    const int* dst = ei + E;

    const int gn = (n + B - 1) / B;
    const int ge = (E + B - 1) / B;
    const int n8 = n * 8;

    const int NB   = (n + BDIV - 1) / BDIV;      // dst buckets
    const int NBLK = (E + CHUNK - 1) / CHUNK;    // partition blocks

    // ws layout (int units): hists_u16[NBLK*NB] | totals[NB] | rowinfo[n] | dinv[n] |
    //   packed[E] | col[E + 1024*NB]
    // after k_bucket_csr, packed reused: t[2n+2] | x16[8n+8] | agg[16n]  (26n+ <= E)
    size_t o_hists  = 0;
    size_t o_totals = align4(o_hists + ((size_t)NB * NBLK + 1) / 2);  // u16 array
    size_t o_rowinf = align4(o_totals + NB);
    size_t o_dinv   = align4(o_rowinf + n);
    size_t o_packed = align4(o_dinv + n);
    size_t o_col    = align4(o_packed + E);
    size_t colsz    = (size_t)E + 1024 * (size_t)NB;
    size_t need_r5  = (o_col + colsz) * 4 + 64;
    size_t u_t   = 0;
    size_t u_x16 = align4(2 * (size_t)n + 2);
    size_t u_agg = align4(u_x16 + 8 * (size_t)n + 8);
    size_t reuse_need = u_agg + 16 * (size_t)n;

    bool r5_ok = (NB <= NB_MAX) && (NBLK <= 1024) && (n <= (1 << 20)) &&
                 ((size_t)E + 1024 * (size_t)NB < (RI_MASK + 1)) &&
                 (reuse_need <= (size_t)E) && (ws_size >= need_r5);

    if (r5_ok) {
        int* ws = (int*)d_ws;
        unsigned short* hists = (unsigned short*)(ws + o_hists);
        int*      totals = ws + o_totals;
        unsigned* rowinf = (unsigned*)(ws + o_rowinf);
        float*    dinv   = (float*)(ws + o_dinv);
        unsigned* packed = (unsigned*)(ws + o_packed);
        int*      col    = ws + o_col;
        float*    t      = (float*)(packed + u_t);    // dead after CSR build
        __half2*  x16    = (__half2*)(packed + u_x16);
        float*    agg    = (float*)(packed + u_agg);

        k_phist<<<NBLK, 256, 0, stream>>>(dst, hists, E, NB, NBLK);
        k_pscan1<<<NB, 1024, 0, stream>>>(hists, totals, NB, NBLK);
        k_move<<<NBLK, 256, 0, stream>>>(src, dst, hists, totals, packed, E, NB, NBLK);
        k_bucket_csr<<<NB, 256, 0, stream>>>(packed, totals, rowinf, dinv, col, n, NB);
        k_prep<<<(n8 + 8 + 255) / 256, 256, 0, stream>>>(x, dinv, x16, t, n8);
        k_l1w<<<(n + 3) / 4, 256, 0, stream>>>(x16, rowinf, col, dinv, agg, n);
        k_mlp<<<gn, 256, 0, stream>>>(agg, dinv, W1, b1, W2, t, n);
        k_l2w<<<(8 * n + 255) / 256, 256, 0, stream>>>(rowinf, col, dinv, t, b2, out, n);
        return;
    }

    // ---- fallback (global-atomic hist/fill), padded-8 rowinfo format ----
    const int nb = (n + 1023) / 1024;
    size_t f_cnt    = 0;
    size_t f_rowinf = align4(f_cnt + n);
    size_t f_col    = align4(f_rowinf + n);
    size_t f_dinv   = align4(f_col + E + 8 * (size_t)n);
    size_t f_bsum   = align4(f_dinv + n);
    size_t f_boff   = align4(f_bsum + nb);
    size_t f_rank   = align4(f_boff + nb);
    size_t reuse2   = align4(2 * (size_t)n + 2) + align4(8 * (size_t)n + 8) + 16 * (size_t)n;
    size_t rmax = (size_t)E > reuse2 ? (size_t)E : reuse2;
    size_t need_rank = (f_rank + rmax) * 4 + 64;
    if (ws_size >= need_rank && nb <= 1024) {
        int*      ws     = (int*)d_ws;
        int*      cnt    = ws + f_cnt;
        unsigned* rowinf = (unsigned*)(ws + f_rowinf);
        int*      col    = ws + f_col;
        float*    dinv   = (float*)(ws + f_dinv);
        int*      bsum   = ws + f_bsum;
        int*      boff   = ws + f_boff;
        int*      rank   = ws + f_rank;                 // dead after k_fill_rank
        float*    t      = (float*)rank;
        __half2*  x16    = (__half2*)(rank + align4(2 * (size_t)n + 2));
        float*    agg    = (float*)(rank + align4(2 * (size_t)n + 2) + align4(8 * (size_t)n + 8));

        k_zero<<<gn, B, 0, stream>>>(cnt, n);
        k_hist_rank<<<ge, B, 0, stream>>>(dst, cnt, rank, E);
        k_blocksum<<<nb, 256, 0, stream>>>(cnt, bsum, n);
        k_scan_bsums<<<1, 1024, 0, stream>>>(bsum, boff, nb);
        k_scan_apply<<<nb, 256, 0, stream>>>(cnt, boff, rowinf, dinv, n);
        k_fill_rank<<<ge, B, 0, stream>>>(src, dst, rowinf, rank, col, E);
        k_pad_sent<<<gn, B, 0, stream>>>(rowinf, cnt, col, n);
        k_prep<<<(n8 + 8 + 255) / 256, 256, 0, stream>>>(x, dinv, x16, t, n8);
        k_l1w<<<(n + 3) / 4, 256, 0, stream>>>(x16, rowinf, col, dinv, agg, n);
        k_mlp<<<gn, 256, 0, stream>>>(agg, dinv, W1, b1, W2, t, n);
        k_l2w<<<(8 * n + 255) / 256, 256, 0, stream>>>(rowinf, col, dinv, t, b2, out, n);
    }
}

// Round 18
// 123.634 us; speedup vs baseline: 1.3514x; 1.0526x over previous
//
#include <hip/hip_runtime.h>
#include <hip/hip_fp16.h>

// GCN 2-layer: out = A(relu(A x W1 + b1) W2) + b2, A = sym-normalized adj + self-loops.
// R18: vectorize the edge streams (int4 = 4 edges/load) in k_phist and k_move's
// staging pass -- 4x fewer VMEM issues + loop iterations on the 25.6MB of edge
// reads (G13). k_move drops the unused lexc LDS array (38->34KB).

#define B 256
#define NB_MAX 1024
#define BDIV 128          // nodes per bucket (pow2)
#define BSHIFT 7
#define CHUNK 4096        // edges per partition block
#define BCAP 6144         // bucket-stage cap (uniform-random buckets ~4090 +/- 64)
#define RI_MASK 0x7FFFFFu // rowinfo: start in low 23 bits, trips (deg_pad/8) in high 9

// ---------------- partition: per-block LDS histogram; hists layout [blk][b] ------
__global__ __launch_bounds__(256) void k_phist(const int* __restrict__ dst,
                                               unsigned short* __restrict__ hists,
                                               int E, int NB, int NBLK) {
    __shared__ int h[NB_MAX];
    int tid = threadIdx.x, blk = blockIdx.x;
    for (int b = tid; b < NB; b += 256) h[b] = 0;
    __syncthreads();
    int start = blk * CHUNK;
    int end = min(start + CHUNK, E);
    int nfull = (end - start) >> 2;
    const int4* d4 = (const int4*)(dst + start);
    for (int g = tid; g < nfull; g += 256) {
        int4 v = d4[g];
        atomicAdd(&h[((unsigned)v.x) >> BSHIFT], 1);
        atomicAdd(&h[((unsigned)v.y) >> BSHIFT], 1);
        atomicAdd(&h[((unsigned)v.z) >> BSHIFT], 1);
        atomicAdd(&h[((unsigned)v.w) >> BSHIFT], 1);
    }
    for (int e = start + (nfull << 2) + tid; e < end; e += 256)
        atomicAdd(&h[((unsigned)dst[e]) >> BSHIFT], 1);
    __syncthreads();
    for (int b = tid; b < NB; b += 256)
        hists[(size_t)blk * NB + b] = (unsigned short)h[b];  // coalesced
}

// per-bucket exclusive scan over NBLK chunk-counts (transposed layout), u16 in/out
__global__ __launch_bounds__(1024) void k_pscan1(unsigned short* __restrict__ hists,
                                                 int* __restrict__ totals,
                                                 int NB, int NBLK) {
    __shared__ int s[1024];
    int b = blockIdx.x, tid = threadIdx.x;
    int v = (tid < NBLK) ? (int)hists[(size_t)tid * NB + b] : 0;
    s[tid] = v;
    __syncthreads();
    for (int off = 1; off < 1024; off <<= 1) {
        int u = (tid >= off) ? s[tid - off] : 0;
        __syncthreads();
        s[tid] += u;
        __syncthreads();
    }
    if (tid < NBLK) hists[(size_t)tid * NB + b] = (unsigned short)(s[tid] - v);
    if (tid == 1023) totals[b] = s[1023];
}

// move edges into bucket regions, LDS-staged for coalesced writes. 34KB LDS.
__global__ __launch_bounds__(256) void k_move(const int* __restrict__ src,
                                              const int* __restrict__ dst,
                                              const unsigned short* __restrict__ hists,
                                              const int* __restrict__ totals,
                                              unsigned* __restrict__ packed,
                                              int E, int NB, int NBLK) {
    __shared__ unsigned stage[CHUNK];            // 16 KB
    __shared__ unsigned short stage_b[CHUNK];    // 8 KB
    __shared__ int lh[NB_MAX];                   // 4 KB (fill cursors)
    __shared__ int gb[NB_MAX];                   // 4 KB (write base per bucket)
    __shared__ int partA[256];                   // 1 KB
    __shared__ int partB[256];                   // 1 KB
    int tid = threadIdx.x, blk = blockIdx.x;
    int t4 = tid * 4;
    bool last = (blk == NBLK - 1);
    // --- fused dual scan: A = totals (bucket bases), B = this chunk's counts ---
    int a[4], c[4], myoff[4];
    int sumA = 0, sumB = 0;
#pragma unroll
    for (int q = 0; q < 4; ++q) {
        int b = t4 + q;
        int tA = 0, mo = 0, cc = 0;
        if (b < NB) {
            tA = totals[b];
            mo = (int)hists[(size_t)blk * NB + b];
            int nxt = last ? tA : (int)hists[(size_t)(blk + 1) * NB + b];
            cc = nxt - mo;
        }
        a[q] = tA; myoff[q] = mo; c[q] = cc;
        sumA += tA; sumB += cc;
    }
    partA[tid] = sumA;
    partB[tid] = sumB;
    __syncthreads();
    for (int off = 1; off < 256; off <<= 1) {
        int uA = (tid >= off) ? partA[tid - off] : 0;
        int uB = (tid >= off) ? partB[tid - off] : 0;
        __syncthreads();
        partA[tid] += uA;
        partB[tid] += uB;
        __syncthreads();
    }
    int runA = partA[tid] - sumA;  // exclusive bucket base
    int runB = partB[tid] - sumB;  // exclusive local offset
#pragma unroll
    for (int q = 0; q < 4; ++q) {
        int b = t4 + q;
        if (b < NB) {
            gb[b] = runA + myoff[q] - runB;  // global write base minus local start
            lh[b] = runB;                    // cursor
        }
        runA += a[q];
        runB += c[q];
    }
    __syncthreads();
    int start = blk * CHUNK;
    int end = min(start + CHUNK, E);
    int nfull = (end - start) >> 2;
    const int4* d4 = (const int4*)(dst + start);
    const int4* s4 = (const int4*)(src + start);
    for (int g = tid; g < nfull; g += 256) {
        int4 dv = d4[g];
        int4 sv = s4[g];
#pragma unroll
        for (int q = 0; q < 4; ++q) {
            unsigned d = (unsigned)((q == 0) ? dv.x : (q == 1) ? dv.y : (q == 2) ? dv.z : dv.w);
            unsigned s = (unsigned)((q == 0) ? sv.x : (q == 1) ? sv.y : (q == 2) ? sv.z : sv.w);
            int b = d >> BSHIFT;
            int r = atomicAdd(&lh[b], 1);
            stage[r] = s | ((d & (BDIV - 1u)) << 20);
            stage_b[r] = (unsigned short)b;
        }
    }
    for (int e = start + (nfull << 2) + tid; e < end; e += 256) {
        unsigned d = (unsigned)dst[e];
        int b = d >> BSHIFT;
        int r = atomicAdd(&lh[b], 1);
        stage[r] = (unsigned)src[e] | ((d & (BDIV - 1u)) << 20);
        stage_b[r] = (unsigned short)b;
    }
    __syncthreads();
    int cnt = end - start;
    for (int i = tid; i < cnt; i += 256)
        packed[gb[stage_b[i]] + i] = stage[i];
}

// per-bucket: SINGLE-PASS (LDS-staged packed) hist -> padded scan (mult of 8) ->
// rowinfo/dinv + place col + sentinels. Computes own base from totals in-LDS.
__global__ __launch_bounds__(256) void k_bucket_csr(const unsigned* __restrict__ packed,
                                                    const int* __restrict__ totals,
                                                    unsigned* __restrict__ rowinfo,
                                                    float* __restrict__ dinv,
                                                    int* __restrict__ col, int n, int NB) {
    __shared__ unsigned stg[BCAP];   // 24 KB: staged packed entries
    __shared__ int part[256];
    __shared__ int lcnt[BDIV];
    __shared__ int plexc[BDIV];
    __shared__ int sbase[2];
    int b = blockIdx.x, tid = threadIdx.x;
    int t4 = tid * 4;
    // --- base scan: exclusive prefix of totals at b ---
    {
        int a0 = (t4 + 0 < NB) ? totals[t4 + 0] : 0;
        int a1 = (t4 + 1 < NB) ? totals[t4 + 1] : 0;
        int a2 = (t4 + 2 < NB) ? totals[t4 + 2] : 0;
        int a3 = (t4 + 3 < NB) ? totals[t4 + 3] : 0;
        int sum = a0 + a1 + a2 + a3;
        part[tid] = sum;
        __syncthreads();
        for (int off = 1; off < 256; off <<= 1) {
            int u = (tid >= off) ? part[tid - off] : 0;
            __syncthreads();
            part[tid] += u;
            __syncthreads();
        }
        int run = part[tid] - sum;
        int a[4] = {a0, a1, a2, a3};
#pragma unroll
        for (int q = 0; q < 4; ++q) {
            if (t4 + q == b) { sbase[0] = run; sbase[1] = run + a[q]; }
            run += a[q];
        }
    }
    if (tid < BDIV) lcnt[tid] = 0;
    __syncthreads();
    int s0 = sbase[0], s1 = sbase[1];
    for (int i = s0 + tid; i < s1; i += 256) {
        unsigned u = packed[i];
        int k = i - s0;
        if (k < BCAP) stg[k] = u;    // stage while histogramming
        atomicAdd(&lcnt[u >> 20], 1);
    }
    __syncthreads();
    int v = (tid < BDIV) ? lcnt[tid] : 0;
    int vp = (v + 7) & ~7;  // padded degree (mult of 8)
    if (tid < BDIV) plexc[tid] = vp;
    __syncthreads();
    for (int off = 1; off < BDIV; off <<= 1) {
        int u = (tid < BDIV && tid >= off) ? plexc[tid - off] : 0;
        __syncthreads();
        if (tid < BDIV) plexc[tid] += u;
        __syncthreads();
    }
    int cb = s0 + 1024 * b;  // padded col base for this bucket
    if (tid < BDIV) {
        plexc[tid] -= vp;  // exclusive padded offset
        int node = b * BDIV + tid;
        if (node < n) {
            rowinfo[node] = (unsigned)(cb + plexc[tid]) | ((unsigned)(vp >> 3) << 23);
            dinv[node] = rsqrtf((float)(v + 1));  // +1 self-loop
        }
        lcnt[tid] = 0;  // reuse as fill cursor
    }
    __syncthreads();
    for (int i = s0 + tid; i < s1; i += 256) {
        int k = i - s0;
        unsigned u = (k < BCAP) ? stg[k] : packed[i];  // LDS hit for ~all entries
        int l = (int)(u >> 20);
        int pos = cb + plexc[l] + atomicAdd(&lcnt[l], 1);
        col[pos] = (int)(u & 0xFFFFFu);
    }
    __syncthreads();
    if (tid < BDIV) {
        int st = cb + plexc[tid];
        for (int k = v; k < vp; ++k) col[st + k] = n;  // sentinel -> zero row
    }
}

// ---------------- x16 = fp16(x * dinv) + zero sentinel row / sentinel t ----------
__global__ void k_prep(const float* __restrict__ x, const float* __restrict__ dinv,
                       __half2* __restrict__ x16, float* __restrict__ t, int n8) {
    int g = blockIdx.x * blockDim.x + threadIdx.x;  // one half2 (2 feats)
    if (g < n8) {
        float d = dinv[g >> 3];
        float2 v = ((const float2*)x)[g];
        x16[g] = __float22half2_rn(make_float2(v.x * d, v.y * d));
    } else if (g < n8 + 8) {
        x16[g] = __float22half2_rn(make_float2(0.f, 0.f));  // sentinel row n
        if (g == n8) {  // sentinel t row n
            t[(n8 >> 3) * 2 + 0] = 0.f;
            t[(n8 >> 3) * 2 + 1] = 0.f;
        }
    }
}

// ---------------- layer 1: wave-per-row branch-free gather -> agg store ----------
__global__ __launch_bounds__(256) void k_l1w(const __half2* __restrict__ x16,
                                             const unsigned* __restrict__ rowinfo,
                                             const int* __restrict__ col,
                                             const float* __restrict__ dinv,
                                             float* __restrict__ agg, int n) {
    int tid = threadIdx.x;
    int lane = tid & 63;
    int r = blockIdx.x * 4 + (tid >> 6);
    if (r >= n) return;
    int h = lane & 7, eg = lane >> 3;
    float dr = dinv[r];
    unsigned ri = rowinfo[r];
    int j = (int)(ri & RI_MASK) + eg;
    int trips = (int)(ri >> 23);
    float s0 = 0.f, s1 = 0.f;
    if (eg == 0) {  // self-loop: x16[r] = x*dinv_r, *dr later -> x*dinv_r^2
        float2 f = __half22float2(x16[(size_t)r * 8 + h]);
        s0 = f.x; s1 = f.y;
    }
#pragma unroll 4
    for (int it = 0; it < trips; ++it, j += 8) {
        int sc = col[j];
        float2 f = __half22float2(x16[(size_t)sc * 8 + h]);
        s0 += f.x; s1 += f.y;
    }
    s0 += __shfl_xor(s0, 8);  s1 += __shfl_xor(s1, 8);
    s0 += __shfl_xor(s0, 16); s1 += __shfl_xor(s1, 16);
    s0 += __shfl_xor(s0, 32); s1 += __shfl_xor(s1, 32);
    if (eg == 0)
        *(float2*)(agg + (size_t)r * 16 + 2 * h) = make_float2(s0 * dr, s1 * dr);
}

// ---------------- node-parallel fused MLP: t = (relu(agg W1 + b1) W2) * dinv -----
__global__ __launch_bounds__(256) void k_mlp(const float* __restrict__ agg,
                                             const float* __restrict__ dinv,
                                             const float* __restrict__ W1,
                                             const float* __restrict__ b1,
                                             const float* __restrict__ W2,
                                             float* __restrict__ t, int n) {
    __shared__ float sW1[512], sW2[64], sb1[32];
    int tid = threadIdx.x;
    for (int k = tid; k < 512; k += 256) sW1[k] = W1[k];
    if (tid < 64) sW2[tid] = W2[tid];
    if (tid < 32) sb1[tid] = b1[tid];
    __syncthreads();
    int i = blockIdx.x * 256 + tid;
    if (i >= n) return;
    float a[16];
    const float4* av = (const float4*)(agg + (size_t)i * 16);
#pragma unroll
    for (int q = 0; q < 4; ++q) {
        float4 v = av[q];
        a[4 * q + 0] = v.x; a[4 * q + 1] = v.y;
        a[4 * q + 2] = v.z; a[4 * q + 3] = v.w;
    }
    float di = dinv[i];
    float t0 = 0.f, t1 = 0.f;
#pragma unroll
    for (int j = 0; j < 32; ++j) {
        float acc = sb1[j];
#pragma unroll
        for (int k = 0; k < 16; ++k) acc = fmaf(a[k], sW1[k * 32 + j], acc);
        float hh = fmaxf(acc, 0.f);
        t0 = fmaf(hh, sW2[j * 2 + 0], t0);
        t1 = fmaf(hh, sW2[j * 2 + 1], t1);
    }
    t[(size_t)i * 2 + 0] = t0 * di;  // pre-scaled for layer-2
    t[(size_t)i * 2 + 1] = t1 * di;
}

// ---------------- layer 2: 8 lanes per node, branch-free padded loop ------------
__global__ __launch_bounds__(256) void k_l2w(const unsigned* __restrict__ rowinfo,
                                             const int* __restrict__ col,
                                             const float* __restrict__ dinv,
                                             const float* __restrict__ ts,
                                             const float* __restrict__ b2,
                                             float* __restrict__ out, int n) {
    int g = blockIdx.x * 256 + threadIdx.x;
    int i = g >> 3, q = g & 7;
    if (i >= n) return;
    float di = dinv[i];
    unsigned ri = rowinfo[i];
    int j = (int)(ri & RI_MASK) + q;
    int trips = (int)(ri >> 23);
    float a0 = 0.f, a1 = 0.f;
    if (q == 0) {  // self: ts[i] = t*dinv_i; *di at end -> t*dinv_i^2
        float2 tv = *(const float2*)(ts + (size_t)i * 2);
        a0 = tv.x; a1 = tv.y;
    }
#pragma unroll 4
    for (int it = 0; it < trips; ++it, j += 8) {
        int sc = col[j];
        float2 tv = *(const float2*)(ts + (size_t)sc * 2);
        a0 += tv.x; a1 += tv.y;
    }
    a0 += __shfl_xor(a0, 1); a1 += __shfl_xor(a1, 1);
    a0 += __shfl_xor(a0, 2); a1 += __shfl_xor(a1, 2);
    a0 += __shfl_xor(a0, 4); a1 += __shfl_xor(a1, 4);
    if (q == 0) {
        out[(size_t)i * 2 + 0] = fmaf(a0, di, b2[0]);
        out[(size_t)i * 2 + 1] = fmaf(a1, di, b2[1]);
    }
}

// ---------------- fallback (global-atomic build, padded-8) ----------------

__global__ void k_zero(int* __restrict__ cnt, int n) {
    int i = blockIdx.x * blockDim.x + threadIdx.x;
    if (i < n) cnt[i] = 0;
}
__global__ void k_hist_rank(const int* __restrict__ dst, int* __restrict__ cnt,
                            int* __restrict__ rank, int E) {
    int e = blockIdx.x * blockDim.x + threadIdx.x;
    if (e < E) rank[e] = atomicAdd(&cnt[dst[e]], 1);
}
__global__ __launch_bounds__(256) void k_blocksum(const int* __restrict__ cnt,
                                                  int* __restrict__ bsum, int n) {
    __shared__ int s[256];
    int tid = threadIdx.x;
    int bse = blockIdx.x * 1024 + tid * 4;
    int sum = 0;
#pragma unroll
    for (int q = 0; q < 4; ++q) {
        int i = bse + q;
        if (i < n) sum += (cnt[i] + 7) & ~7;  // padded-8
    }
    s[tid] = sum;
    __syncthreads();
    for (int off = 128; off > 0; off >>= 1) {
        if (tid < off) s[tid] += s[tid + off];
        __syncthreads();
    }
    if (tid == 0) bsum[blockIdx.x] = s[0];
}
__global__ __launch_bounds__(1024) void k_scan_bsums(const int* __restrict__ bsum,
                                                     int* __restrict__ boff, int nb) {
    __shared__ int s[1024];
    int tid = threadIdx.x;
    int v = (tid < nb) ? bsum[tid] : 0;
    s[tid] = v;
    __syncthreads();
    for (int off = 1; off < 1024; off <<= 1) {
        int u = (tid >= off) ? s[tid - off] : 0;
        __syncthreads();
        s[tid] += u;
        __syncthreads();
    }
    if (tid < nb) boff[tid] = s[tid] - v;
}
__global__ __launch_bounds__(256) void k_scan_apply(const int* __restrict__ cnt,
                                                    const int* __restrict__ boff,
                                                    unsigned* __restrict__ rowinfo,
                                                    float* __restrict__ dinv, int n) {
    __shared__ int s[256];
    int tid = threadIdx.x;
    int bse = blockIdx.x * 1024 + tid * 4;
    int c[4];
    int sum = 0;
#pragma unroll
    for (int q = 0; q < 4; ++q) {
        int i = bse + q;
        c[q] = (i < n) ? ((cnt[i] + 7) & ~7) : 0;
        sum += c[q];
    }
    s[tid] = sum;
    __syncthreads();
    for (int off = 1; off < 256; off <<= 1) {
        int u = (tid >= off) ? s[tid - off] : 0;
        __syncthreads();
        s[tid] += u;
        __syncthreads();
    }
    int run = boff[blockIdx.x] + s[tid] - sum;
#pragma unroll
    for (int q = 0; q < 4; ++q) {
        int i = bse + q;
        if (i < n) {
            rowinfo[i] = (unsigned)run | ((unsigned)(c[q] >> 3) << 23);
            run += c[q];
            dinv[i] = rsqrtf((float)(cnt[i] + 1));
        }
    }
}
__global__ void k_fill_rank(const int* __restrict__ src, const int* __restrict__ dst,
                            const unsigned* __restrict__ rowinfo,
                            const int* __restrict__ rank,
                            int* __restrict__ col, int E) {
    int e = blockIdx.x * blockDim.x + threadIdx.x;
    if (e >= E) return;
    int d = dst[e];
    col[(rowinfo[d] & RI_MASK) + rank[e]] = src[e];
}
__global__ void k_pad_sent(const unsigned* __restrict__ rowinfo,
                           const int* __restrict__ cnt,
                           int* __restrict__ col, int n) {
    int i = blockIdx.x * blockDim.x + threadIdx.x;
    if (i >= n) return;
    int st = (int)(rowinfo[i] & RI_MASK);
    int v = cnt[i], vp = (v + 7) & ~7;
    for (int k = v; k < vp; ++k) col[st + k] = n;
}

static inline size_t align4(size_t v) { return (v + 3) & ~(size_t)3; }

extern "C" void kernel_launch(void* const* d_in, const int* in_sizes, int n_in,
                              void* d_out, int out_size, void* d_ws, size_t ws_size,
                              hipStream_t stream) {
    const float* x  = (const float*)d_in[0];
    const int*   ei = (const int*)d_in[1];
    const float* W1 = (const float*)d_in[2];
    const float* b1 = (const float*)d_in[3];
    const float* W2 = (const float*)d_in[4];
    const float* b2 = (const float*)d_in[5];
    float* out = (float*)d_out;

    const int n = in_sizes[0] / 16;
    const int E = in_sizes[1] / 2;
    const int* src = ei;
    const int* dst = ei + E;

    const int gn = (n + B - 1) / B;
    const int ge = (E + B - 1) / B;
    const int n8 = n * 8;

    const int NB   = (n + BDIV - 1) / BDIV;      // dst buckets
    const int NBLK = (E + CHUNK - 1) / CHUNK;    // partition blocks

    // ws layout (int units): hists_u16[NBLK*NB] | totals[NB] | rowinfo[n] | dinv[n] |
    //   packed[E] | col[E + 1024*NB]
    // after k_bucket_csr, packed reused: t[2n+2] | x16[8n+8] | agg[16n]  (26n+ <= E)
    size_t o_hists  = 0;
    size_t o_totals = align4(o_hists + ((size_t)NB * NBLK + 1) / 2);  // u16 array
    size_t o_rowinf = align4(o_totals + NB);
    size_t o_dinv   = align4(o_rowinf + n);
    size_t o_packed = align4(o_dinv + n);
    size_t o_col    = align4(o_packed + E);
    size_t colsz    = (size_t)E + 1024 * (size_t)NB;
    size_t need_r5  = (o_col + colsz) * 4 + 64;
    size_t u_t   = 0;
    size_t u_x16 = align4(2 * (size_t)n + 2);
    size_t u_agg = align4(u_x16 + 8 * (size_t)n + 8);
    size_t reuse_need = u_agg + 16 * (size_t)n;

    bool r5_ok = (NB <= NB_MAX) && (NBLK <= 1024) && (n <= (1 << 20)) &&
                 ((size_t)E + 1024 * (size_t)NB < (RI_MASK + 1)) &&
                 (reuse_need <= (size_t)E) && (ws_size >= need_r5);

    if (r5_ok) {
        int* ws = (int*)d_ws;
        unsigned short* hists = (unsigned short*)(ws + o_hists);
        int*      totals = ws + o_totals;
        unsigned* rowinf = (unsigned*)(ws + o_rowinf);
        float*    dinv   = (float*)(ws + o_dinv);
        unsigned* packed = (unsigned*)(ws + o_packed);
        int*      col    = ws + o_col;
        float*    t      = (float*)(packed + u_t);    // dead after CSR build
        __half2*  x16    = (__half2*)(packed + u_x16);
        float*    agg    = (float*)(packed + u_agg);

        k_phist<<<NBLK, 256, 0, stream>>>(dst, hists, E, NB, NBLK);
        k_pscan1<<<NB, 1024, 0, stream>>>(hists, totals, NB, NBLK);
        k_move<<<NBLK, 256, 0, stream>>>(src, dst, hists, totals, packed, E, NB, NBLK);
        k_bucket_csr<<<NB, 256, 0, stream>>>(packed, totals, rowinf, dinv, col, n, NB);
        k_prep<<<(n8 + 8 + 255) / 256, 256, 0, stream>>>(x, dinv, x16, t, n8);
        k_l1w<<<(n + 3) / 4, 256, 0, stream>>>(x16, rowinf, col, dinv, agg, n);
        k_mlp<<<gn, 256, 0, stream>>>(agg, dinv, W1, b1, W2, t, n);
        k_l2w<<<(8 * n + 255) / 256, 256, 0, stream>>>(rowinf, col, dinv, t, b2, out, n);
        return;
    }

    // ---- fallback (global-atomic hist/fill), padded-8 rowinfo format ----
    const int nb = (n + 1023) / 1024;
    size_t f_cnt    = 0;
    size_t f_rowinf = align4(f_cnt + n);
    size_t f_col    = align4(f_rowinf + n);
    size_t f_dinv   = align4(f_col + E + 8 * (size_t)n);
    size_t f_bsum   = align4(f_dinv + n);
    size_t f_boff   = align4(f_bsum + nb);
    size_t f_rank   = align4(f_boff + nb);
    size_t reuse2   = align4(2 * (size_t)n + 2) + align4(8 * (size_t)n + 8) + 16 * (size_t)n;
    size_t rmax = (size_t)E > reuse2 ? (size_t)E : reuse2;
    size_t need_rank = (f_rank + rmax) * 4 + 64;
    if (ws_size >= need_rank && nb <= 1024) {
        int*      ws     = (int*)d_ws;
        int*      cnt    = ws + f_cnt;
        unsigned* rowinf = (unsigned*)(ws + f_rowinf);
        int*      col    = ws + f_col;
        float*    dinv   = (float*)(ws + f_dinv);
        int*      bsum   = ws + f_bsum;
        int*      boff   = ws + f_boff;
        int*      rank   = ws + f_rank;                 // dead after k_fill_rank
        float*    t      = (float*)rank;
        __half2*  x16    = (__half2*)(rank + align4(2 * (size_t)n + 2));
        float*    agg    = (float*)(rank + align4(2 * (size_t)n + 2) + align4(8 * (size_t)n + 8));

        k_zero<<<gn, B, 0, stream>>>(cnt, n);
        k_hist_rank<<<ge, B, 0, stream>>>(dst, cnt, rank, E);
        k_blocksum<<<nb, 256, 0, stream>>>(cnt, bsum, n);
        k_scan_bsums<<<1, 1024, 0, stream>>>(bsum, boff, nb);
        k_scan_apply<<<nb, 256, 0, stream>>>(cnt, boff, rowinf, dinv, n);
        k_fill_rank<<<ge, B, 0, stream>>>(src, dst, rowinf, rank, col, E);
        k_pad_sent<<<gn, B, 0, stream>>>(rowinf, cnt, col, n);
        k_prep<<<(n8 + 8 + 255) / 256, 256, 0, stream>>>(x, dinv, x16, t, n8);
        k_l1w<<<(n + 3) / 4, 256, 0, stream>>>(x16, rowinf, col, dinv, agg, n);
        k_mlp<<<gn, 256, 0, stream>>>(agg, dinv, W1, b1, W2, t, n);
        k_l2w<<<(8 * n + 255) / 256, 256, 0, stream>>>(rowinf, col, dinv, t, b2, out, n);
    }
}

// Round 19
// 121.724 us; speedup vs baseline: 1.3726x; 1.0157x over previous
//
#include <hip/hip_runtime.h>
#include <hip/hip_fp16.h>

// GCN 2-layer: out = A(relu(A x W1 + b1) W2) + b2, A = sym-normalized adj + self-loops.
// R19: fuse k_prep into k_bucket_csr (each bucket block converts its own 128 nodes to
// x16 = fp16(x*dinv) right after computing dinv; block 0 writes sentinels) -- one fewer
// launch + one fewer dinv pass. k_l2w unroll 8. Everything else frozen at R18.

#define B 256
#define NB_MAX 1024
#define BDIV 128          // nodes per bucket (pow2)
#define BSHIFT 7
#define CHUNK 4096        // edges per partition block
#define BCAP 6144         // bucket-stage cap (uniform-random buckets ~4090 +/- 64)
#define RI_MASK 0x7FFFFFu // rowinfo: start in low 23 bits, trips (deg_pad/8) in high 9

// ---------------- partition: per-block LDS histogram; hists layout [blk][b] ------
__global__ __launch_bounds__(256) void k_phist(const int* __restrict__ dst,
                                               unsigned short* __restrict__ hists,
                                               int E, int NB, int NBLK) {
    __shared__ int h[NB_MAX];
    int tid = threadIdx.x, blk = blockIdx.x;
    for (int b = tid; b < NB; b += 256) h[b] = 0;
    __syncthreads();
    int start = blk * CHUNK;
    int end = min(start + CHUNK, E);
    int nfull = (end - start) >> 2;
    const int4* d4 = (const int4*)(dst + start);
    for (int g = tid; g < nfull; g += 256) {
        int4 v = d4[g];
        atomicAdd(&h[((unsigned)v.x) >> BSHIFT], 1);
        atomicAdd(&h[((unsigned)v.y) >> BSHIFT], 1);
        atomicAdd(&h[((unsigned)v.z) >> BSHIFT], 1);
        atomicAdd(&h[((unsigned)v.w) >> BSHIFT], 1);
    }
    for (int e = start + (nfull << 2) + tid; e < end; e += 256)
        atomicAdd(&h[((unsigned)dst[e]) >> BSHIFT], 1);
    __syncthreads();
    for (int b = tid; b < NB; b += 256)
        hists[(size_t)blk * NB + b] = (unsigned short)h[b];  // coalesced
}

// per-bucket exclusive scan over NBLK chunk-counts (transposed layout), u16 in/out
__global__ __launch_bounds__(1024) void k_pscan1(unsigned short* __restrict__ hists,
                                                 int* __restrict__ totals,
                                                 int NB, int NBLK) {
    __shared__ int s[1024];
    int b = blockIdx.x, tid = threadIdx.x;
    int v = (tid < NBLK) ? (int)hists[(size_t)tid * NB + b] : 0;
    s[tid] = v;
    __syncthreads();
    for (int off = 1; off < 1024; off <<= 1) {
        int u = (tid >= off) ? s[tid - off] : 0;
        __syncthreads();
        s[tid] += u;
        __syncthreads();
    }
    if (tid < NBLK) hists[(size_t)tid * NB + b] = (unsigned short)(s[tid] - v);
    if (tid == 1023) totals[b] = s[1023];
}

// move edges into bucket regions, LDS-staged for coalesced writes. 34KB LDS.
__global__ __launch_bounds__(256) void k_move(const int* __restrict__ src,
                                              const int* __restrict__ dst,
                                              const unsigned short* __restrict__ hists,
                                              const int* __restrict__ totals,
                                              unsigned* __restrict__ packed,
                                              int E, int NB, int NBLK) {
    __shared__ unsigned stage[CHUNK];            // 16 KB
    __shared__ unsigned short stage_b[CHUNK];    // 8 KB
    __shared__ int lh[NB_MAX];                   // 4 KB (fill cursors)
    __shared__ int gb[NB_MAX];                   // 4 KB (write base per bucket)
    __shared__ int partA[256];                   // 1 KB
    __shared__ int partB[256];                   // 1 KB
    int tid = threadIdx.x, blk = blockIdx.x;
    int t4 = tid * 4;
    bool last = (blk == NBLK - 1);
    // --- fused dual scan: A = totals (bucket bases), B = this chunk's counts ---
    int a[4], c[4], myoff[4];
    int sumA = 0, sumB = 0;
#pragma unroll
    for (int q = 0; q < 4; ++q) {
        int b = t4 + q;
        int tA = 0, mo = 0, cc = 0;
        if (b < NB) {
            tA = totals[b];
            mo = (int)hists[(size_t)blk * NB + b];
            int nxt = last ? tA : (int)hists[(size_t)(blk + 1) * NB + b];
            cc = nxt - mo;
        }
        a[q] = tA; myoff[q] = mo; c[q] = cc;
        sumA += tA; sumB += cc;
    }
    partA[tid] = sumA;
    partB[tid] = sumB;
    __syncthreads();
    for (int off = 1; off < 256; off <<= 1) {
        int uA = (tid >= off) ? partA[tid - off] : 0;
        int uB = (tid >= off) ? partB[tid - off] : 0;
        __syncthreads();
        partA[tid] += uA;
        partB[tid] += uB;
        __syncthreads();
    }
    int runA = partA[tid] - sumA;  // exclusive bucket base
    int runB = partB[tid] - sumB;  // exclusive local offset
#pragma unroll
    for (int q = 0; q < 4; ++q) {
        int b = t4 + q;
        if (b < NB) {
            gb[b] = runA + myoff[q] - runB;  // global write base minus local start
            lh[b] = runB;                    // cursor
        }
        runA += a[q];
        runB += c[q];
    }
    __syncthreads();
    int start = blk * CHUNK;
    int end = min(start + CHUNK, E);
    int nfull = (end - start) >> 2;
    const int4* d4 = (const int4*)(dst + start);
    const int4* s4 = (const int4*)(src + start);
    for (int g = tid; g < nfull; g += 256) {
        int4 dv = d4[g];
        int4 sv = s4[g];
#pragma unroll
        for (int q = 0; q < 4; ++q) {
            unsigned d = (unsigned)((q == 0) ? dv.x : (q == 1) ? dv.y : (q == 2) ? dv.z : dv.w);
            unsigned s = (unsigned)((q == 0) ? sv.x : (q == 1) ? sv.y : (q == 2) ? sv.z : sv.w);
            int b = d >> BSHIFT;
            int r = atomicAdd(&lh[b], 1);
            stage[r] = s | ((d & (BDIV - 1u)) << 20);
            stage_b[r] = (unsigned short)b;
        }
    }
    for (int e = start + (nfull << 2) + tid; e < end; e += 256) {
        unsigned d = (unsigned)dst[e];
        int b = d >> BSHIFT;
        int r = atomicAdd(&lh[b], 1);
        stage[r] = (unsigned)src[e] | ((d & (BDIV - 1u)) << 20);
        stage_b[r] = (unsigned short)b;
    }
    __syncthreads();
    int cnt = end - start;
    for (int i = tid; i < cnt; i += 256)
        packed[gb[stage_b[i]] + i] = stage[i];
}

// per-bucket: SINGLE-PASS (LDS-staged packed) hist -> padded scan (mult of 8) ->
// rowinfo/dinv/x16 + place col + sentinels. Fused k_prep: this block converts its
// own 128 nodes' features to fp16(x*dinv); block 0 writes sentinel rows.
__global__ __launch_bounds__(256) void k_bucket_csr(const unsigned* __restrict__ packed,
                                                    const int* __restrict__ totals,
                                                    const float* __restrict__ x,
                                                    unsigned* __restrict__ rowinfo,
                                                    float* __restrict__ dinv,
                                                    __half2* __restrict__ x16,
                                                    float* __restrict__ t,
                                                    int* __restrict__ col, int n, int NB) {
    __shared__ unsigned stg[BCAP];   // 24 KB: staged packed entries
    __shared__ float sdinv[BDIV];
    __shared__ int part[256];
    __shared__ int lcnt[BDIV];
    __shared__ int plexc[BDIV];
    __shared__ int sbase[2];
    int b = blockIdx.x, tid = threadIdx.x;
    int t4 = tid * 4;
    // --- base scan: exclusive prefix of totals at b ---
    {
        int a0 = (t4 + 0 < NB) ? totals[t4 + 0] : 0;
        int a1 = (t4 + 1 < NB) ? totals[t4 + 1] : 0;
        int a2 = (t4 + 2 < NB) ? totals[t4 + 2] : 0;
        int a3 = (t4 + 3 < NB) ? totals[t4 + 3] : 0;
        int sum = a0 + a1 + a2 + a3;
        part[tid] = sum;
        __syncthreads();
        for (int off = 1; off < 256; off <<= 1) {
            int u = (tid >= off) ? part[tid - off] : 0;
            __syncthreads();
            part[tid] += u;
            __syncthreads();
        }
        int run = part[tid] - sum;
        int a[4] = {a0, a1, a2, a3};
#pragma unroll
        for (int q = 0; q < 4; ++q) {
            if (t4 + q == b) { sbase[0] = run; sbase[1] = run + a[q]; }
            run += a[q];
        }
    }
    if (tid < BDIV) lcnt[tid] = 0;
    __syncthreads();
    int s0 = sbase[0], s1 = sbase[1];
    for (int i = s0 + tid; i < s1; i += 256) {
        unsigned u = packed[i];
        int k = i - s0;
        if (k < BCAP) stg[k] = u;    // stage while histogramming
        atomicAdd(&lcnt[u >> 20], 1);
    }
    __syncthreads();
    int v = (tid < BDIV) ? lcnt[tid] : 0;
    int vp = (v + 7) & ~7;  // padded degree (mult of 8)
    if (tid < BDIV) plexc[tid] = vp;
    __syncthreads();
    for (int off = 1; off < BDIV; off <<= 1) {
        int u = (tid < BDIV && tid >= off) ? plexc[tid - off] : 0;
        __syncthreads();
        if (tid < BDIV) plexc[tid] += u;
        __syncthreads();
    }
    int cb = s0 + 1024 * b;  // padded col base for this bucket
    if (tid < BDIV) {
        plexc[tid] -= vp;  // exclusive padded offset
        int node = b * BDIV + tid;
        float dv = rsqrtf((float)(v + 1));
        sdinv[tid] = dv;
        if (node < n) {
            rowinfo[node] = (unsigned)(cb + plexc[tid]) | ((unsigned)(vp >> 3) << 23);
            dinv[node] = dv;  // +1 self-loop
        }
        lcnt[tid] = 0;  // reuse as fill cursor
    }
    __syncthreads();
    // fused k_prep: x16 rows for this bucket's nodes (2 threads/node, 8B each)
    {
        int node0 = b * BDIV;
        int nloc = min(BDIV, n - node0);
        for (int w = tid; w < nloc * 2; w += 256) {
            int l = w >> 1, half = w & 1;
            int node = node0 + l;
            float dv = sdinv[l];
            float4 xv = *(const float4*)(x + (size_t)node * 16 + half * 8);
            float4 xw = *(const float4*)(x + (size_t)node * 16 + half * 8 + 4);
            __half2 o0 = __float22half2_rn(make_float2(xv.x * dv, xv.y * dv));
            __half2 o1 = __float22half2_rn(make_float2(xv.z * dv, xv.w * dv));
            __half2 o2 = __float22half2_rn(make_float2(xw.x * dv, xw.y * dv));
            __half2 o3 = __float22half2_rn(make_float2(xw.z * dv, xw.w * dv));
            __half2* op = x16 + (size_t)node * 8 + half * 4;
            op[0] = o0; op[1] = o1; op[2] = o2; op[3] = o3;
        }
        if (b == 0 && tid < 8) {  // sentinel row n (zeros) + sentinel t
            x16[(size_t)n * 8 + tid] = __float22half2_rn(make_float2(0.f, 0.f));
            if (tid == 0) { t[(size_t)n * 2] = 0.f; t[(size_t)n * 2 + 1] = 0.f; }
        }
    }
    __syncthreads();
    for (int i = s0 + tid; i < s1; i += 256) {
        int k = i - s0;
        unsigned u = (k < BCAP) ? stg[k] : packed[i];  // LDS hit for ~all entries
        int l = (int)(u >> 20);
        int pos = cb + plexc[l] + atomicAdd(&lcnt[l], 1);
        col[pos] = (int)(u & 0xFFFFFu);
    }
    __syncthreads();
    if (tid < BDIV) {
        int st = cb + plexc[tid];
        for (int k = v; k < vp; ++k) col[st + k] = n;  // sentinel -> zero row
    }
}

// ---------------- layer 1: wave-per-row branch-free gather -> agg store ----------
__global__ __launch_bounds__(256) void k_l1w(const __half2* __restrict__ x16,
                                             const unsigned* __restrict__ rowinfo,
                                             const int* __restrict__ col,
                                             const float* __restrict__ dinv,
                                             float* __restrict__ agg, int n) {
    int tid = threadIdx.x;
    int lane = tid & 63;
    int r = blockIdx.x * 4 + (tid >> 6);
    if (r >= n) return;
    int h = lane & 7, eg = lane >> 3;
    float dr = dinv[r];
    unsigned ri = rowinfo[r];
    int j = (int)(ri & RI_MASK) + eg;
    int trips = (int)(ri >> 23);
    float s0 = 0.f, s1 = 0.f;
    if (eg == 0) {  // self-loop: x16[r] = x*dinv_r, *dr later -> x*dinv_r^2
        float2 f = __half22float2(x16[(size_t)r * 8 + h]);
        s0 = f.x; s1 = f.y;
    }
#pragma unroll 4
    for (int it = 0; it < trips; ++it, j += 8) {
        int sc = col[j];
        float2 f = __half22float2(x16[(size_t)sc * 8 + h]);
        s0 += f.x; s1 += f.y;
    }
    s0 += __shfl_xor(s0, 8);  s1 += __shfl_xor(s1, 8);
    s0 += __shfl_xor(s0, 16); s1 += __shfl_xor(s1, 16);
    s0 += __shfl_xor(s0, 32); s1 += __shfl_xor(s1, 32);
    if (eg == 0)
        *(float2*)(agg + (size_t)r * 16 + 2 * h) = make_float2(s0 * dr, s1 * dr);
}

// ---------------- node-parallel fused MLP: t = (relu(agg W1 + b1) W2) * dinv -----
__global__ __launch_bounds__(256) void k_mlp(const float* __restrict__ agg,
                                             const float* __restrict__ dinv,
                                             const float* __restrict__ W1,
                                             const float* __restrict__ b1,
                                             const float* __restrict__ W2,
                                             float* __restrict__ t, int n) {
    __shared__ float sW1[512], sW2[64], sb1[32];
    int tid = threadIdx.x;
    for (int k = tid; k < 512; k += 256) sW1[k] = W1[k];
    if (tid < 64) sW2[tid] = W2[tid];
    if (tid < 32) sb1[tid] = b1[tid];
    __syncthreads();
    int i = blockIdx.x * 256 + tid;
    if (i >= n) return;
    float a[16];
    const float4* av = (const float4*)(agg + (size_t)i * 16);
#pragma unroll
    for (int q = 0; q < 4; ++q) {
        float4 v = av[q];
        a[4 * q + 0] = v.x; a[4 * q + 1] = v.y;
        a[4 * q + 2] = v.z; a[4 * q + 3] = v.w;
    }
    float di = dinv[i];
    float t0 = 0.f, t1 = 0.f;
#pragma unroll
    for (int j = 0; j < 32; ++j) {
        float acc = sb1[j];
#pragma unroll
        for (int k = 0; k < 16; ++k) acc = fmaf(a[k], sW1[k * 32 + j], acc);
        float hh = fmaxf(acc, 0.f);
        t0 = fmaf(hh, sW2[j * 2 + 0], t0);
        t1 = fmaf(hh, sW2[j * 2 + 1], t1);
    }
    t[(size_t)i * 2 + 0] = t0 * di;  // pre-scaled for layer-2
    t[(size_t)i * 2 + 1] = t1 * di;
}

// ---------------- layer 2: 8 lanes per node, branch-free padded loop ------------
__global__ __launch_bounds__(256) void k_l2w(const unsigned* __restrict__ rowinfo,
                                             const int* __restrict__ col,
                                             const float* __restrict__ dinv,
                                             const float* __restrict__ ts,
                                             const float* __restrict__ b2,
                                             float* __restrict__ out, int n) {
    int g = blockIdx.x * 256 + threadIdx.x;
    int i = g >> 3, q = g & 7;
    if (i >= n) return;
    float di = dinv[i];
    unsigned ri = rowinfo[i];
    int j = (int)(ri & RI_MASK) + q;
    int trips = (int)(ri >> 23);
    float a0 = 0.f, a1 = 0.f;
    if (q == 0) {  // self: ts[i] = t*dinv_i; *di at end -> t*dinv_i^2
        float2 tv = *(const float2*)(ts + (size_t)i * 2);
        a0 = tv.x; a1 = tv.y;
    }
#pragma unroll 8
    for (int it = 0; it < trips; ++it, j += 8) {
        int sc = col[j];
        float2 tv = *(const float2*)(ts + (size_t)sc * 2);
        a0 += tv.x; a1 += tv.y;
    }
    a0 += __shfl_xor(a0, 1); a1 += __shfl_xor(a1, 1);
    a0 += __shfl_xor(a0, 2); a1 += __shfl_xor(a1, 2);
    a0 += __shfl_xor(a0, 4); a1 += __shfl_xor(a1, 4);
    if (q == 0) {
        out[(size_t)i * 2 + 0] = fmaf(a0, di, b2[0]);
        out[(size_t)i * 2 + 1] = fmaf(a1, di, b2[1]);
    }
}

// ---------------- fallback (global-atomic build, padded-8) ----------------

__global__ void k_zero(int* __restrict__ cnt, int n) {
    int i = blockIdx.x * blockDim.x + threadIdx.x;
    if (i < n) cnt[i] = 0;
}
__global__ void k_hist_rank(const int* __restrict__ dst, int* __restrict__ cnt,
                            int* __restrict__ rank, int E) {
    int e = blockIdx.x * blockDim.x + threadIdx.x;
    if (e < E) rank[e] = atomicAdd(&cnt[dst[e]], 1);
}
__global__ __launch_bounds__(256) void k_blocksum(const int* __restrict__ cnt,
                                                  int* __restrict__ bsum, int n) {
    __shared__ int s[256];
    int tid = threadIdx.x;
    int bse = blockIdx.x * 1024 + tid * 4;
    int sum = 0;
#pragma unroll
    for (int q = 0; q < 4; ++q) {
        int i = bse + q;
        if (i < n) sum += (cnt[i] + 7) & ~7;  // padded-8
    }
    s[tid] = sum;
    __syncthreads();
    for (int off = 128; off > 0; off >>= 1) {
        if (tid < off) s[tid] += s[tid + off];
        __syncthreads();
    }
    if (tid == 0) bsum[blockIdx.x] = s[0];
}
__global__ __launch_bounds__(1024) void k_scan_bsums(const int* __restrict__ bsum,
                                                     int* __restrict__ boff, int nb) {
    __shared__ int s[1024];
    int tid = threadIdx.x;
    int v = (tid < nb) ? bsum[tid] : 0;
    s[tid] = v;
    __syncthreads();
    for (int off = 1; off < 1024; off <<= 1) {
        int u = (tid >= off) ? s[tid - off] : 0;
        __syncthreads();
        s[tid] += u;
        __syncthreads();
    }
    if (tid < nb) boff[tid] = s[tid] - v;
}
__global__ __launch_bounds__(256) void k_scan_apply(const int* __restrict__ cnt,
                                                    const int* __restrict__ boff,
                                                    unsigned* __restrict__ rowinfo,
                                                    float* __restrict__ dinv, int n) {
    __shared__ int s[256];
    int tid = threadIdx.x;
    int bse = blockIdx.x * 1024 + tid * 4;
    int c[4];
    int sum = 0;
#pragma unroll
    for (int q = 0; q < 4; ++q) {
        int i = bse + q;
        c[q] = (i < n) ? ((cnt[i] + 7) & ~7) : 0;
        sum += c[q];
    }
    s[tid] = sum;
    __syncthreads();
    for (int off = 1; off < 256; off <<= 1) {
        int u = (tid >= off) ? s[tid - off] : 0;
        __syncthreads();
        s[tid] += u;
        __syncthreads();
    }
    int run = boff[blockIdx.x] + s[tid] - sum;
#pragma unroll
    for (int q = 0; q < 4; ++q) {
        int i = bse + q;
        if (i < n) {
            rowinfo[i] = (unsigned)run | ((unsigned)(c[q] >> 3) << 23);
            run += c[q];
            dinv[i] = rsqrtf((float)(cnt[i] + 1));
        }
    }
}
__global__ void k_fill_rank(const int* __restrict__ src, const int* __restrict__ dst,
                            const unsigned* __restrict__ rowinfo,
                            const int* __restrict__ rank,
                            int* __restrict__ col, int E) {
    int e = blockIdx.x * blockDim.x + threadIdx.x;
    if (e >= E) return;
    int d = dst[e];
    col[(rowinfo[d] & RI_MASK) + rank[e]] = src[e];
}
__global__ void k_pad_sent(const unsigned* __restrict__ rowinfo,
                           const int* __restrict__ cnt,
                           int* __restrict__ col, int n) {
    int i = blockIdx.x * blockDim.x + threadIdx.x;
    if (i >= n) return;
    int st = (int)(rowinfo[i] & RI_MASK);
    int v = cnt[i], vp = (v + 7) & ~7;
    for (int k = v; k < vp; ++k) col[st + k] = n;
}
__global__ void k_prep(const float* __restrict__ x, const float* __restrict__ dinv,
                       __half2* __restrict__ x16, float* __restrict__ t, int n8) {
    int g = blockIdx.x * blockDim.x + threadIdx.x;
    if (g < n8) {
        float d = dinv[g >> 3];
        float2 v = ((const float2*)x)[g];
        x16[g] = __float22half2_rn(make_float2(v.x * d, v.y * d));
    } else if (g < n8 + 8) {
        x16[g] = __float22half2_rn(make_float2(0.f, 0.f));
        if (g == n8) {
            t[(n8 >> 3) * 2 + 0] = 0.f;
            t[(n8 >> 3) * 2 + 1] = 0.f;
        }
    }
}

static inline size_t align4(size_t v) { return (v + 3) & ~(size_t)3; }

extern "C" void kernel_launch(void* const* d_in, const int* in_sizes, int n_in,
                              void* d_out, int out_size, void* d_ws, size_t ws_size,
                              hipStream_t stream) {
    const float* x  = (const float*)d_in[0];
    const int*   ei = (const int*)d_in[1];
    const float* W1 = (const float*)d_in[2];
    const float* b1 = (const float*)d_in[3];
    const float* W2 = (const float*)d_in[4];
    const float* b2 = (const float*)d_in[5];
    float* out = (float*)d_out;

    const int n = in_sizes[0] / 16;
    const int E = in_sizes[1] / 2;
    const int* src = ei;
    const int* dst = ei + E;

    const int gn = (n + B - 1) / B;
    const int ge = (E + B - 1) / B;
    const int n8 = n * 8;

    const int NB   = (n + BDIV - 1) / BDIV;      // dst buckets
    const int NBLK = (E + CHUNK - 1) / CHUNK;    // partition blocks

    // ws layout (int units): hists_u16[NBLK*NB] | totals[NB] | rowinfo[n] | dinv[n] |
    //   packed[E] | col[E + 1024*NB]
    // after k_bucket_csr, packed reused: t[2n+2] | x16[8n+8] | agg[16n]  (26n+ <= E)
    size_t o_hists  = 0;
    size_t o_totals = align4(o_hists + ((size_t)NB * NBLK + 1) / 2);  // u16 array
    size_t o_rowinf = align4(o_totals + NB);
    size_t o_dinv   = align4(o_rowinf + n);
    size_t o_packed = align4(o_dinv + n);
    size_t o_col    = align4(o_packed + E);
    size_t colsz    = (size_t)E + 1024 * (size_t)NB;
    size_t need_r5  = (o_col + colsz) * 4 + 64;
    size_t u_t   = 0;
    size_t u_x16 = align4(2 * (size_t)n + 2);
    size_t u_agg = align4(u_x16 + 8 * (size_t)n + 8);
    size_t reuse_need = u_agg + 16 * (size_t)n;

    bool r5_ok = (NB <= NB_MAX) && (NBLK <= 1024) && (n <= (1 << 20)) &&
                 ((size_t)E + 1024 * (size_t)NB < (RI_MASK + 1)) &&
                 (reuse_need <= (size_t)E) && (ws_size >= need_r5);

    if (r5_ok) {
        int* ws = (int*)d_ws;
        unsigned short* hists = (unsigned short*)(ws + o_hists);
        int*      totals = ws + o_totals;
        unsigned* rowinf = (unsigned*)(ws + o_rowinf);
        float*    dinv   = (float*)(ws + o_dinv);
        unsigned* packed = (unsigned*)(ws + o_packed);
        int*      col    = ws + o_col;
        float*    t      = (float*)(packed + u_t);    // packed dead after k_bucket_csr
        __half2*  x16    = (__half2*)(packed + u_x16);
        float*    agg    = (float*)(packed + u_agg);

        k_phist<<<NBLK, 256, 0, stream>>>(dst, hists, E, NB, NBLK);
        k_pscan1<<<NB, 1024, 0, stream>>>(hists, totals, NB, NBLK);
        k_move<<<NBLK, 256, 0, stream>>>(src, dst, hists, totals, packed, E, NB, NBLK);
        k_bucket_csr<<<NB, 256, 0, stream>>>(packed, totals, x, rowinf, dinv, x16, t,
                                             col, n, NB);
        k_l1w<<<(n + 3) / 4, 256, 0, stream>>>(x16, rowinf, col, dinv, agg, n);
        k_mlp<<<gn, 256, 0, stream>>>(agg, dinv, W1, b1, W2, t, n);
        k_l2w<<<(8 * n + 255) / 256, 256, 0, stream>>>(rowinf, col, dinv, t, b2, out, n);
        return;
    }

    // ---- fallback (global-atomic hist/fill), padded-8 rowinfo format ----
    const int nb = (n + 1023) / 1024;
    size_t f_cnt    = 0;
    size_t f_rowinf = align4(f_cnt + n);
    size_t f_col    = align4(f_rowinf + n);
    size_t f_dinv   = align4(f_col + E + 8 * (size_t)n);
    size_t f_bsum   = align4(f_dinv + n);
    size_t f_boff   = align4(f_bsum + nb);
    size_t f_rank   = align4(f_boff + nb);
    size_t reuse2   = align4(2 * (size_t)n + 2) + align4(8 * (size_t)n + 8) + 16 * (size_t)n;
    size_t rmax = (size_t)E > reuse2 ? (size_t)E : reuse2;
    size_t need_rank = (f_rank + rmax) * 4 + 64;
    if (ws_size >= need_rank && nb <= 1024) {
        int*      ws     = (int*)d_ws;
        int*      cnt    = ws + f_cnt;
        unsigned* rowinf = (unsigned*)(ws + f_rowinf);
        int*      col    = ws + f_col;
        float*    dinv   = (float*)(ws + f_dinv);
        int*      bsum   = ws + f_bsum;
        int*      boff   = ws + f_boff;
        int*      rank   = ws + f_rank;                 // dead after k_fill_rank
        float*    t      = (float*)rank;
        __half2*  x16    = (__half2*)(rank + align4(2 * (size_t)n + 2));
        float*    agg    = (float*)(rank + align4(2 * (size_t)n + 2) + align4(8 * (size_t)n + 8));

        k_zero<<<gn, B, 0, stream>>>(cnt, n);
        k_hist_rank<<<ge, B, 0, stream>>>(dst, cnt, rank, E);
        k_blocksum<<<nb, 256, 0, stream>>>(cnt, bsum, n);
        k_scan_bsums<<<1, 1024, 0, stream>>>(bsum, boff, nb);
        k_scan_apply<<<nb, 256, 0, stream>>>(cnt, boff, rowinf, dinv, n);
        k_fill_rank<<<ge, B, 0, stream>>>(src, dst, rowinf, rank, col, E);
        k_pad_sent<<<gn, B, 0, stream>>>(rowinf, cnt, col, n);
        k_prep<<<(n8 + 8 + 255) / 256, 256, 0, stream>>>(x, dinv, x16, t, n8);
        k_l1w<<<(n + 3) / 4, 256, 0, stream>>>(x16, rowinf, col, dinv, agg, n);
        k_mlp<<<gn, 256, 0, stream>>>(agg, dinv, W1, b1, W2, t, n);
        k_l2w<<<(8 * n + 255) / 256, 256, 0, stream>>>(rowinf, col, dinv, t, b2, out, n);
    }
}

// Round 21
// 121.319 us; speedup vs baseline: 1.3771x; 1.0033x over previous
//
#include <hip/hip_runtime.h>
#include <hip/hip_fp16.h>

// GCN 2-layer: out = A(relu(A x W1 + b1) W2) + b2, A = sym-normalized adj + self-loops.
// R21: R20's fp16-agg retry with the workspace layout FIXED. R20 under-allocated x16
// (wrote "8n+8 halfs = 4n+4 ints" but x16 is __half2[8n+8] = 8n+8 ints) so agg16
// overlapped x16's top half -> k_l1w clobbered live gather data (absmax 8.5e-2).
// Correct: u_agg = align4(u_x16 + 8n + 8); agg16 = 8n ints.

#define B 256
#define NB_MAX 1024
#define BDIV 128          // nodes per bucket (pow2)
#define BSHIFT 7
#define CHUNK 4096        // edges per partition block
#define BCAP 6144         // bucket-stage cap (uniform-random buckets ~4090 +/- 64)
#define RI_MASK 0x7FFFFFu // rowinfo: start in low 23 bits, trips (deg_pad/8) in high 9

// ---------------- partition: per-block LDS histogram; hists layout [blk][b] ------
__global__ __launch_bounds__(256) void k_phist(const int* __restrict__ dst,
                                               unsigned short* __restrict__ hists,
                                               int E, int NB, int NBLK) {
    __shared__ int h[NB_MAX];
    int tid = threadIdx.x, blk = blockIdx.x;
    for (int b = tid; b < NB; b += 256) h[b] = 0;
    __syncthreads();
    int start = blk * CHUNK;
    int end = min(start + CHUNK, E);
    int nfull = (end - start) >> 2;
    const int4* d4 = (const int4*)(dst + start);
    for (int g = tid; g < nfull; g += 256) {
        int4 v = d4[g];
        atomicAdd(&h[((unsigned)v.x) >> BSHIFT], 1);
        atomicAdd(&h[((unsigned)v.y) >> BSHIFT], 1);
        atomicAdd(&h[((unsigned)v.z) >> BSHIFT], 1);
        atomicAdd(&h[((unsigned)v.w) >> BSHIFT], 1);
    }
    for (int e = start + (nfull << 2) + tid; e < end; e += 256)
        atomicAdd(&h[((unsigned)dst[e]) >> BSHIFT], 1);
    __syncthreads();
    for (int b = tid; b < NB; b += 256)
        hists[(size_t)blk * NB + b] = (unsigned short)h[b];  // coalesced
}

// per-bucket exclusive scan over NBLK chunk-counts (transposed layout), u16 in/out
__global__ __launch_bounds__(1024) void k_pscan1(unsigned short* __restrict__ hists,
                                                 int* __restrict__ totals,
                                                 int NB, int NBLK) {
    __shared__ int s[1024];
    int b = blockIdx.x, tid = threadIdx.x;
    int v = (tid < NBLK) ? (int)hists[(size_t)tid * NB + b] : 0;
    s[tid] = v;
    __syncthreads();
    for (int off = 1; off < 1024; off <<= 1) {
        int u = (tid >= off) ? s[tid - off] : 0;
        __syncthreads();
        s[tid] += u;
        __syncthreads();
    }
    if (tid < NBLK) hists[(size_t)tid * NB + b] = (unsigned short)(s[tid] - v);
    if (tid == 1023) totals[b] = s[1023];
}

// move edges into bucket regions, LDS-staged for coalesced writes. 34KB LDS.
__global__ __launch_bounds__(256) void k_move(const int* __restrict__ src,
                                              const int* __restrict__ dst,
                                              const unsigned short* __restrict__ hists,
                                              const int* __restrict__ totals,
                                              unsigned* __restrict__ packed,
                                              int E, int NB, int NBLK) {
    __shared__ unsigned stage[CHUNK];            // 16 KB
    __shared__ unsigned short stage_b[CHUNK];    // 8 KB
    __shared__ int lh[NB_MAX];                   // 4 KB (fill cursors)
    __shared__ int gb[NB_MAX];                   // 4 KB (write base per bucket)
    __shared__ int partA[256];                   // 1 KB
    __shared__ int partB[256];                   // 1 KB
    int tid = threadIdx.x, blk = blockIdx.x;
    int t4 = tid * 4;
    bool last = (blk == NBLK - 1);
    // --- fused dual scan: A = totals (bucket bases), B = this chunk's counts ---
    int a[4], c[4], myoff[4];
    int sumA = 0, sumB = 0;
#pragma unroll
    for (int q = 0; q < 4; ++q) {
        int b = t4 + q;
        int tA = 0, mo = 0, cc = 0;
        if (b < NB) {
            tA = totals[b];
            mo = (int)hists[(size_t)blk * NB + b];
            int nxt = last ? tA : (int)hists[(size_t)(blk + 1) * NB + b];
            cc = nxt - mo;
        }
        a[q] = tA; myoff[q] = mo; c[q] = cc;
        sumA += tA; sumB += cc;
    }
    partA[tid] = sumA;
    partB[tid] = sumB;
    __syncthreads();
    for (int off = 1; off < 256; off <<= 1) {
        int uA = (tid >= off) ? partA[tid - off] : 0;
        int uB = (tid >= off) ? partB[tid - off] : 0;
        __syncthreads();
        partA[tid] += uA;
        partB[tid] += uB;
        __syncthreads();
    }
    int runA = partA[tid] - sumA;  // exclusive bucket base
    int runB = partB[tid] - sumB;  // exclusive local offset
#pragma unroll
    for (int q = 0; q < 4; ++q) {
        int b = t4 + q;
        if (b < NB) {
            gb[b] = runA + myoff[q] - runB;  // global write base minus local start
            lh[b] = runB;                    // cursor
        }
        runA += a[q];
        runB += c[q];
    }
    __syncthreads();
    int start = blk * CHUNK;
    int end = min(start + CHUNK, E);
    int nfull = (end - start) >> 2;
    const int4* d4 = (const int4*)(dst + start);
    const int4* s4 = (const int4*)(src + start);
    for (int g = tid; g < nfull; g += 256) {
        int4 dv = d4[g];
        int4 sv = s4[g];
#pragma unroll
        for (int q = 0; q < 4; ++q) {
            unsigned d = (unsigned)((q == 0) ? dv.x : (q == 1) ? dv.y : (q == 2) ? dv.z : dv.w);
            unsigned s = (unsigned)((q == 0) ? sv.x : (q == 1) ? sv.y : (q == 2) ? sv.z : sv.w);
            int b = d >> BSHIFT;
            int r = atomicAdd(&lh[b], 1);
            stage[r] = s | ((d & (BDIV - 1u)) << 20);
            stage_b[r] = (unsigned short)b;
        }
    }
    for (int e = start + (nfull << 2) + tid; e < end; e += 256) {
        unsigned d = (unsigned)dst[e];
        int b = d >> BSHIFT;
        int r = atomicAdd(&lh[b], 1);
        stage[r] = (unsigned)src[e] | ((d & (BDIV - 1u)) << 20);
        stage_b[r] = (unsigned short)b;
    }
    __syncthreads();
    int cnt = end - start;
    for (int i = tid; i < cnt; i += 256)
        packed[gb[stage_b[i]] + i] = stage[i];
}

// per-bucket: SINGLE-PASS (LDS-staged packed) hist -> padded scan (mult of 8) ->
// rowinfo/dinv/x16 + place col + sentinels. Fused prep: block converts its 128
// nodes' features to fp16(x*dinv); block 0 writes sentinel rows.
__global__ __launch_bounds__(256) void k_bucket_csr(const unsigned* __restrict__ packed,
                                                    const int* __restrict__ totals,
                                                    const float* __restrict__ x,
                                                    unsigned* __restrict__ rowinfo,
                                                    float* __restrict__ dinv,
                                                    __half2* __restrict__ x16,
                                                    float* __restrict__ t,
                                                    int* __restrict__ col, int n, int NB) {
    __shared__ unsigned stg[BCAP];   // 24 KB: staged packed entries
    __shared__ float sdinv[BDIV];
    __shared__ int part[256];
    __shared__ int lcnt[BDIV];
    __shared__ int plexc[BDIV];
    __shared__ int sbase[2];
    int b = blockIdx.x, tid = threadIdx.x;
    int t4 = tid * 4;
    // --- base scan: exclusive prefix of totals at b ---
    {
        int a0 = (t4 + 0 < NB) ? totals[t4 + 0] : 0;
        int a1 = (t4 + 1 < NB) ? totals[t4 + 1] : 0;
        int a2 = (t4 + 2 < NB) ? totals[t4 + 2] : 0;
        int a3 = (t4 + 3 < NB) ? totals[t4 + 3] : 0;
        int sum = a0 + a1 + a2 + a3;
        part[tid] = sum;
        __syncthreads();
        for (int off = 1; off < 256; off <<= 1) {
            int u = (tid >= off) ? part[tid - off] : 0;
            __syncthreads();
            part[tid] += u;
            __syncthreads();
        }
        int run = part[tid] - sum;
        int a[4] = {a0, a1, a2, a3};
#pragma unroll
        for (int q = 0; q < 4; ++q) {
            if (t4 + q == b) { sbase[0] = run; sbase[1] = run + a[q]; }
            run += a[q];
        }
    }
    if (tid < BDIV) lcnt[tid] = 0;
    __syncthreads();
    int s0 = sbase[0], s1 = sbase[1];
    for (int i = s0 + tid; i < s1; i += 256) {
        unsigned u = packed[i];
        int k = i - s0;
        if (k < BCAP) stg[k] = u;    // stage while histogramming
        atomicAdd(&lcnt[u >> 20], 1);
    }
    __syncthreads();
    int v = (tid < BDIV) ? lcnt[tid] : 0;
    int vp = (v + 7) & ~7;  // padded degree (mult of 8)
    if (tid < BDIV) plexc[tid] = vp;
    __syncthreads();
    for (int off = 1; off < BDIV; off <<= 1) {
        int u = (tid < BDIV && tid >= off) ? plexc[tid - off] : 0;
        __syncthreads();
        if (tid < BDIV) plexc[tid] += u;
        __syncthreads();
    }
    int cb = s0 + 1024 * b;  // padded col base for this bucket
    if (tid < BDIV) {
        plexc[tid] -= vp;  // exclusive padded offset
        int node = b * BDIV + tid;
        float dv = rsqrtf((float)(v + 1));
        sdinv[tid] = dv;
        if (node < n) {
            rowinfo[node] = (unsigned)(cb + plexc[tid]) | ((unsigned)(vp >> 3) << 23);
            dinv[node] = dv;  // +1 self-loop
        }
        lcnt[tid] = 0;  // reuse as fill cursor
    }
    __syncthreads();
    // fused prep: x16 rows for this bucket's nodes (2 threads/node, 16B each)
    {
        int node0 = b * BDIV;
        int nloc = min(BDIV, n - node0);
        for (int w = tid; w < nloc * 2; w += 256) {
            int l = w >> 1, half = w & 1;
            int node = node0 + l;
            float dv = sdinv[l];
            float4 xv = *(const float4*)(x + (size_t)node * 16 + half * 8);
            float4 xw = *(const float4*)(x + (size_t)node * 16 + half * 8 + 4);
            __half2 o0 = __float22half2_rn(make_float2(xv.x * dv, xv.y * dv));
            __half2 o1 = __float22half2_rn(make_float2(xv.z * dv, xv.w * dv));
            __half2 o2 = __float22half2_rn(make_float2(xw.x * dv, xw.y * dv));
            __half2 o3 = __float22half2_rn(make_float2(xw.z * dv, xw.w * dv));
            __half2* op = x16 + (size_t)node * 8 + half * 4;
            op[0] = o0; op[1] = o1; op[2] = o2; op[3] = o3;
        }
        if (b == 0 && tid < 8) {  // sentinel row n (zeros) + sentinel t
            x16[(size_t)n * 8 + tid] = __float22half2_rn(make_float2(0.f, 0.f));
            if (tid == 0) { t[(size_t)n * 2] = 0.f; t[(size_t)n * 2 + 1] = 0.f; }
        }
    }
    __syncthreads();
    for (int i = s0 + tid; i < s1; i += 256) {
        int k = i - s0;
        unsigned u = (k < BCAP) ? stg[k] : packed[i];  // LDS hit for ~all entries
        int l = (int)(u >> 20);
        int pos = cb + plexc[l] + atomicAdd(&lcnt[l], 1);
        col[pos] = (int)(u & 0xFFFFFu);
    }
    __syncthreads();
    if (tid < BDIV) {
        int st = cb + plexc[tid];
        for (int k = v; k < vp; ++k) col[st + k] = n;  // sentinel -> zero row
    }
}

// ---------------- layer 1: wave-per-row branch-free gather -> fp16 agg store -----
__global__ __launch_bounds__(256) void k_l1w(const __half2* __restrict__ x16,
                                             const unsigned* __restrict__ rowinfo,
                                             const int* __restrict__ col,
                                             const float* __restrict__ dinv,
                                             __half2* __restrict__ agg16, int n) {
    int tid = threadIdx.x;
    int lane = tid & 63;
    int r = blockIdx.x * 4 + (tid >> 6);
    if (r >= n) return;
    int h = lane & 7, eg = lane >> 3;
    float dr = dinv[r];
    unsigned ri = rowinfo[r];
    int j = (int)(ri & RI_MASK) + eg;
    int trips = (int)(ri >> 23);
    float s0 = 0.f, s1 = 0.f;
    if (eg == 0) {  // self-loop: x16[r] = x*dinv_r, *dr later -> x*dinv_r^2
        float2 f = __half22float2(x16[(size_t)r * 8 + h]);
        s0 = f.x; s1 = f.y;
    }
#pragma unroll 4
    for (int it = 0; it < trips; ++it, j += 8) {
        int sc = col[j];
        float2 f = __half22float2(x16[(size_t)sc * 8 + h]);
        s0 += f.x; s1 += f.y;
    }
    s0 += __shfl_xor(s0, 8);  s1 += __shfl_xor(s1, 8);
    s0 += __shfl_xor(s0, 16); s1 += __shfl_xor(s1, 16);
    s0 += __shfl_xor(s0, 32); s1 += __shfl_xor(s1, 32);
    if (eg == 0)
        agg16[(size_t)r * 8 + h] = __float22half2_rn(make_float2(s0 * dr, s1 * dr));
}

// ---------------- node-parallel fused MLP: t = (relu(agg W1 + b1) W2) * dinv -----
__global__ __launch_bounds__(256) void k_mlp(const __half2* __restrict__ agg16,
                                             const float* __restrict__ dinv,
                                             const float* __restrict__ W1,
                                             const float* __restrict__ b1,
                                             const float* __restrict__ W2,
                                             float* __restrict__ t, int n) {
    __shared__ float sW1[512], sW2[64], sb1[32];
    int tid = threadIdx.x;
    for (int k = tid; k < 512; k += 256) sW1[k] = W1[k];
    if (tid < 64) sW2[tid] = W2[tid];
    if (tid < 32) sb1[tid] = b1[tid];
    __syncthreads();
    int i = blockIdx.x * 256 + tid;
    if (i >= n) return;
    float a[16];
    const uint4* av = (const uint4*)(agg16 + (size_t)i * 8);  // 32B = 2 x uint4
#pragma unroll
    for (int q = 0; q < 2; ++q) {
        uint4 raw = av[q];
        const __half2* hp = (const __half2*)&raw;
#pragma unroll
        for (int p = 0; p < 4; ++p) {
            float2 f = __half22float2(hp[p]);
            a[q * 8 + 2 * p + 0] = f.x;
            a[q * 8 + 2 * p + 1] = f.y;
        }
    }
    float di = dinv[i];
    float t0 = 0.f, t1 = 0.f;
#pragma unroll
    for (int j = 0; j < 32; ++j) {
        float acc = sb1[j];
#pragma unroll
        for (int k = 0; k < 16; ++k) acc = fmaf(a[k], sW1[k * 32 + j], acc);
        float hh = fmaxf(acc, 0.f);
        t0 = fmaf(hh, sW2[j * 2 + 0], t0);
        t1 = fmaf(hh, sW2[j * 2 + 1], t1);
    }
    t[(size_t)i * 2 + 0] = t0 * di;  // pre-scaled for layer-2
    t[(size_t)i * 2 + 1] = t1 * di;
}

// ---------------- layer 2: 8 lanes per node, branch-free padded loop ------------
__global__ __launch_bounds__(256) void k_l2w(const unsigned* __restrict__ rowinfo,
                                             const int* __restrict__ col,
                                             const float* __restrict__ dinv,
                                             const float* __restrict__ ts,
                                             const float* __restrict__ b2,
                                             float* __restrict__ out, int n) {
    int g = blockIdx.x * 256 + threadIdx.x;
    int i = g >> 3, q = g & 7;
    if (i >= n) return;
    float di = dinv[i];
    unsigned ri = rowinfo[i];
    int j = (int)(ri & RI_MASK) + q;
    int trips = (int)(ri >> 23);
    float a0 = 0.f, a1 = 0.f;
    if (q == 0) {  // self: ts[i] = t*dinv_i; *di at end -> t*dinv_i^2
        float2 tv = *(const float2*)(ts + (size_t)i * 2);
        a0 = tv.x; a1 = tv.y;
    }
#pragma unroll 8
    for (int it = 0; it < trips; ++it, j += 8) {
        int sc = col[j];
        float2 tv = *(const float2*)(ts + (size_t)sc * 2);
        a0 += tv.x; a1 += tv.y;
    }
    a0 += __shfl_xor(a0, 1); a1 += __shfl_xor(a1, 1);
    a0 += __shfl_xor(a0, 2); a1 += __shfl_xor(a1, 2);
    a0 += __shfl_xor(a0, 4); a1 += __shfl_xor(a1, 4);
    if (q == 0) {
        out[(size_t)i * 2 + 0] = fmaf(a0, di, b2[0]);
        out[(size_t)i * 2 + 1] = fmaf(a1, di, b2[1]);
    }
}

// ---------------- fallback (global-atomic build, padded-8) ----------------

__global__ void k_zero(int* __restrict__ cnt, int n) {
    int i = blockIdx.x * blockDim.x + threadIdx.x;
    if (i < n) cnt[i] = 0;
}
__global__ void k_hist_rank(const int* __restrict__ dst, int* __restrict__ cnt,
                            int* __restrict__ rank, int E) {
    int e = blockIdx.x * blockDim.x + threadIdx.x;
    if (e < E) rank[e] = atomicAdd(&cnt[dst[e]], 1);
}
__global__ __launch_bounds__(256) void k_blocksum(const int* __restrict__ cnt,
                                                  int* __restrict__ bsum, int n) {
    __shared__ int s[256];
    int tid = threadIdx.x;
    int bse = blockIdx.x * 1024 + tid * 4;
    int sum = 0;
#pragma unroll
    for (int q = 0; q < 4; ++q) {
        int i = bse + q;
        if (i < n) sum += (cnt[i] + 7) & ~7;  // padded-8
    }
    s[tid] = sum;
    __syncthreads();
    for (int off = 128; off > 0; off >>= 1) {
        if (tid < off) s[tid] += s[tid + off];
        __syncthreads();
    }
    if (tid == 0) bsum[blockIdx.x] = s[0];
}
__global__ __launch_bounds__(1024) void k_scan_bsums(const int* __restrict__ bsum,
                                                     int* __restrict__ boff, int nb) {
    __shared__ int s[1024];
    int tid = threadIdx.x;
    int v = (tid < nb) ? bsum[tid] : 0;
    s[tid] = v;
    __syncthreads();
    for (int off = 1; off < 1024; off <<= 1) {
        int u = (tid >= off) ? s[tid - off] : 0;
        __syncthreads();
        s[tid] += u;
        __syncthreads();
    }
    if (tid < nb) boff[tid] = s[tid] - v;
}
__global__ __launch_bounds__(256) void k_scan_apply(const int* __restrict__ cnt,
                                                    const int* __restrict__ boff,
                                                    unsigned* __restrict__ rowinfo,
                                                    float* __restrict__ dinv, int n) {
    __shared__ int s[256];
    int tid = threadIdx.x;
    int bse = blockIdx.x * 1024 + tid * 4;
    int c[4];
    int sum = 0;
#pragma unroll
    for (int q = 0; q < 4; ++q) {
        int i = bse + q;
        c[q] = (i < n) ? ((cnt[i] + 7) & ~7) : 0;
        sum += c[q];
    }
    s[tid] = sum;
    __syncthreads();
    for (int off = 1; off < 256; off <<= 1) {
        int u = (tid >= off) ? s[tid - off] : 0;
        __syncthreads();
        s[tid] += u;
        __syncthreads();
    }
    int run = boff[blockIdx.x] + s[tid] - sum;
#pragma unroll
    for (int q = 0; q < 4; ++q) {
        int i = bse + q;
        if (i < n) {
            rowinfo[i] = (unsigned)run | ((unsigned)(c[q] >> 3) << 23);
            run += c[q];
            dinv[i] = rsqrtf((float)(cnt[i] + 1));
        }
    }
}
__global__ void k_fill_rank(const int* __restrict__ src, const int* __restrict__ dst,
                            const unsigned* __restrict__ rowinfo,
                            const int* __restrict__ rank,
                            int* __restrict__ col, int E) {
    int e = blockIdx.x * blockDim.x + threadIdx.x;
    if (e >= E) return;
    int d = dst[e];
    col[(rowinfo[d] & RI_MASK) + rank[e]] = src[e];
}
__global__ void k_pad_sent(const unsigned* __restrict__ rowinfo,
                           const int* __restrict__ cnt,
                           int* __restrict__ col, int n) {
    int i = blockIdx.x * blockDim.x + threadIdx.x;
    if (i >= n) return;
    int st = (int)(rowinfo[i] & RI_MASK);
    int v = cnt[i], vp = (v + 7) & ~7;
    for (int k = v; k < vp; ++k) col[st + k] = n;
}
__global__ void k_prep(const float* __restrict__ x, const float* __restrict__ dinv,
                       __half2* __restrict__ x16, float* __restrict__ t, int n8) {
    int g = blockIdx.x * blockDim.x + threadIdx.x;
    if (g < n8) {
        float d = dinv[g >> 3];
        float2 v = ((const float2*)x)[g];
        x16[g] = __float22half2_rn(make_float2(v.x * d, v.y * d));
    } else if (g < n8 + 8) {
        x16[g] = __float22half2_rn(make_float2(0.f, 0.f));
        if (g == n8) {
            t[(n8 >> 3) * 2 + 0] = 0.f;
            t[(n8 >> 3) * 2 + 1] = 0.f;
        }
    }
}

static inline size_t align4(size_t v) { return (v + 3) & ~(size_t)3; }

extern "C" void kernel_launch(void* const* d_in, const int* in_sizes, int n_in,
                              void* d_out, int out_size, void* d_ws, size_t ws_size,
                              hipStream_t stream) {
    const float* x  = (const float*)d_in[0];
    const int*   ei = (const int*)d_in[1];
    const float* W1 = (const float*)d_in[2];
    const float* b1 = (const float*)d_in[3];
    const float* W2 = (const float*)d_in[4];
    const float* b2 = (const float*)d_in[5];
    float* out = (float*)d_out;

    const int n = in_sizes[0] / 16;
    const int E = in_sizes[1] / 2;
    const int* src = ei;
    const int* dst = ei + E;

    const int gn = (n + B - 1) / B;
    const int ge = (E + B - 1) / B;
    const int n8 = n * 8;

    const int NB   = (n + BDIV - 1) / BDIV;      // dst buckets
    const int NBLK = (E + CHUNK - 1) / CHUNK;    // partition blocks

    // ws layout (int units): hists_u16[NBLK*NB] | totals[NB] | rowinfo[n] | dinv[n] |
    //   packed[E] | col[E + 1024*NB]
    // packed reuse (after k_bucket_csr): t[2n+2 ints] | x16[8n+8 ints] | agg16[8n ints]
    size_t o_hists  = 0;
    size_t o_totals = align4(o_hists + ((size_t)NB * NBLK + 1) / 2);  // u16 array
    size_t o_rowinf = align4(o_totals + NB);
    size_t o_dinv   = align4(o_rowinf + n);
    size_t o_packed = align4(o_dinv + n);
    size_t o_col    = align4(o_packed + E);
    size_t colsz    = (size_t)E + 1024 * (size_t)NB;
    size_t need_r5  = (o_col + colsz) * 4 + 64;
    size_t u_t    = 0;
    size_t u_x16  = align4(2 * (size_t)n + 2);
    size_t u_agg  = align4(u_x16 + 8 * (size_t)n + 8);   // x16 = (8n+8) half2 = 8n+8 ints
    size_t reuse_need = u_agg + 8 * (size_t)n;           // agg16 = 8n half2 = 8n ints

    bool r5_ok = (NB <= NB_MAX) && (NBLK <= 1024) && (n <= (1 << 20)) &&
                 ((size_t)E + 1024 * (size_t)NB < (RI_MASK + 1)) &&
                 (reuse_need <= (size_t)E) && (ws_size >= need_r5);

    if (r5_ok) {
        int* ws = (int*)d_ws;
        unsigned short* hists = (unsigned short*)(ws + o_hists);
        int*      totals = ws + o_totals;
        unsigned* rowinf = (unsigned*)(ws + o_rowinf);
        float*    dinv   = (float*)(ws + o_dinv);
        unsigned* packed = (unsigned*)(ws + o_packed);
        int*      col    = ws + o_col;
        float*    t      = (float*)(packed + u_t);    // packed dead after k_bucket_csr
        __half2*  x16    = (__half2*)(packed + u_x16);
        __half2*  agg16  = (__half2*)(packed + u_agg);

        k_phist<<<NBLK, 256, 0, stream>>>(dst, hists, E, NB, NBLK);
        k_pscan1<<<NB, 1024, 0, stream>>>(hists, totals, NB, NBLK);
        k_move<<<NBLK, 256, 0, stream>>>(src, dst, hists, totals, packed, E, NB, NBLK);
        k_bucket_csr<<<NB, 256, 0, stream>>>(packed, totals, x, rowinf, dinv, x16, t,
                                             col, n, NB);
        k_l1w<<<(n + 3) / 4, 256, 0, stream>>>(x16, rowinf, col, dinv, agg16, n);
        k_mlp<<<gn, 256, 0, stream>>>(agg16, dinv, W1, b1, W2, t, n);
        k_l2w<<<(8 * n + 255) / 256, 256, 0, stream>>>(rowinf, col, dinv, t, b2, out, n);
        return;
    }

    // ---- fallback (global-atomic hist/fill), padded-8 rowinfo format ----
    const int nb = (n + 1023) / 1024;
    size_t f_cnt    = 0;
    size_t f_rowinf = align4(f_cnt + n);
    size_t f_col    = align4(f_rowinf + n);
    size_t f_dinv   = align4(f_col + E + 8 * (size_t)n);
    size_t f_bsum   = align4(f_dinv + n);
    size_t f_boff   = align4(f_bsum + nb);
    size_t f_rank   = align4(f_boff + nb);
    size_t reuse2   = align4(2 * (size_t)n + 2) + align4(8 * (size_t)n + 8) + 8 * (size_t)n;
    size_t rmax = (size_t)E > reuse2 ? (size_t)E : reuse2;
    size_t need_rank = (f_rank + rmax) * 4 + 64;
    if (ws_size >= need_rank && nb <= 1024) {
        int*      ws     = (int*)d_ws;
        int*      cnt    = ws + f_cnt;
        unsigned* rowinf = (unsigned*)(ws + f_rowinf);
        int*      col    = ws + f_col;
        float*    dinv   = (float*)(ws + f_dinv);
        int*      bsum   = ws + f_bsum;
        int*      boff   = ws + f_boff;
        int*      rank   = ws + f_rank;                 // dead after k_fill_rank
        float*    t      = (float*)rank;
        __half2*  x16    = (__half2*)(rank + align4(2 * (size_t)n + 2));
        __half2*  agg16  = (__half2*)(rank + align4(2 * (size_t)n + 2) + align4(8 * (size_t)n + 8));

        k_zero<<<gn, B, 0, stream>>>(cnt, n);
        k_hist_rank<<<ge, B, 0, stream>>>(dst, cnt, rank, E);
        k_blocksum<<<nb, 256, 0, stream>>>(cnt, bsum, n);
        k_scan_bsums<<<1, 1024, 0, stream>>>(bsum, boff, nb);
        k_scan_apply<<<nb, 256, 0, stream>>>(cnt, boff, rowinf, dinv, n);
        k_fill_rank<<<ge, B, 0, stream>>>(src, dst, rowinf, rank, col, E);
        k_pad_sent<<<gn, B, 0, stream>>>(rowinf, cnt, col, n);
        k_prep<<<(n8 + 8 + 255) / 256, 256, 0, stream>>>(x, dinv, x16, t, n8);
        k_l1w<<<(n + 3) / 4, 256, 0, stream>>>(x16, rowinf, col, dinv, agg16, n);
        k_mlp<<<gn, 256, 0, stream>>>(agg16, dinv, W1, b1, W2, t, n);
        k_l2w<<<(8 * n + 255) / 256, 256, 0, stream>>>(rowinf, col, dinv, t, b2, out, n);
    }
}